// Round 4
// baseline (19578.091 us; speedup 1.0000x reference)
//
#include <hip/hip_runtime.h>
#include <cstdint>

// Model dims (fixed)
#define Bb 8
#define Ll 512
#define Cc 512
#define Hh 8
#define HD 64
#define Ff 2048
#define Ss 50
#define NROWS 4096   // B*L

__device__ __forceinline__ float wave_sum(float v){
  #pragma unroll
  for (int o=32;o>=1;o>>=1) v += __shfl_xor(v,o);
  return v;
}
__device__ __forceinline__ float wave_max(float v){
  #pragma unroll
  for (int o=32;o>=1;o>>=1) v = fmaxf(v,__shfl_xor(v,o));
  return v;
}

// ---------------- embed gather: x[(b*L+l)*C+c] = embed[tok][c] ----------------
__global__ __launch_bounds__(128) void embed_k(const int* __restrict__ tok,
    const float* __restrict__ emb, float* __restrict__ x){
  int n = blockIdx.x;
  int t = tok[n];
  ((float4*)(x + ((size_t)n<<9)))[threadIdx.x] =
      ((const float4*)(emb + ((size_t)t<<9)))[threadIdx.x];
}

// ---------------- x *= mask[row] (in-place) ----------------
__global__ __launch_bounds__(256) void maskmul_k(float* __restrict__ x,
    const float* __restrict__ mask){
  int i = blockIdx.x*256 + threadIdx.x;        // float4 index
  float m = mask[i >> 7];                      // row = (4*i)/512
  float4 v = ((float4*)x)[i];
  v.x*=m; v.y*=m; v.z*=m; v.w*=m;
  ((float4*)x)[i]=v;
}

// ---------------- depthwise conv K=5, edge-replicate pad, +bias, *mask --------
__global__ __launch_bounds__(128) void dwconv_k(const float* __restrict__ x,
    const float* __restrict__ w, const float* __restrict__ bias,
    const float* __restrict__ mask, float* __restrict__ h){
  int n = blockIdx.x; int b_ = n >> 9, l = n & 511;
  int c0 = threadIdx.x * 4;
  float acc0=bias[c0], acc1=bias[c0+1], acc2=bias[c0+2], acc3=bias[c0+3];
  #pragma unroll
  for (int k=0;k<5;k++){
    int ls = l + k - 2; ls = ls < 0 ? 0 : (ls > 511 ? 511 : ls);
    const float4 xv = *(const float4*)&x[((size_t)(b_*512 + ls) << 9) + c0];
    acc0 += w[(c0+0)*5+k]*xv.x;
    acc1 += w[(c0+1)*5+k]*xv.y;
    acc2 += w[(c0+2)*5+k]*xv.z;
    acc3 += w[(c0+3)*5+k]*xv.w;
  }
  float mm = mask[n];
  float4 o; o.x=acc0*mm; o.y=acc1*mm; o.z=acc2*mm; o.w=acc3*mm;
  *(float4*)&h[((size_t)n << 9) + c0] = o;
}

// ---------------- rowwise LayerNorm over C=512: one wave per row ----------------
__global__ __launch_bounds__(256) void ln_rows(const float* __restrict__ x,
    const float* __restrict__ g, const float* __restrict__ bt,
    float* __restrict__ y, int nrows){
  int wid = threadIdx.x >> 6, lane = threadIdx.x & 63;
  int row = blockIdx.x*4 + wid;
  if (row >= nrows) return;
  const float4* xr = (const float4*)(x + ((size_t)row<<9));
  float4 a = xr[lane*2], b = xr[lane*2+1];
  float s = a.x+a.y+a.z+a.w+b.x+b.y+b.z+b.w;
  s = wave_sum(s);
  float m = s * (1.f/512.f);
  float d0=a.x-m,d1=a.y-m,d2=a.z-m,d3=a.w-m,d4=b.x-m,d5=b.y-m,d6=b.z-m,d7=b.w-m;
  float sq = d0*d0+d1*d1+d2*d2+d3*d3+d4*d4+d5*d5+d6*d6+d7*d7;
  sq = wave_sum(sq);
  float var = sq * (1.f/512.f);
  float inv = 1.f/sqrtf(var + 1e-6f);
  const float4* gr = (const float4*)g; const float4* br = (const float4*)bt;
  float4 g0=gr[lane*2], g1=gr[lane*2+1], b0=br[lane*2], b1=br[lane*2+1];
  float4 o0, o1;
  o0.x=d0*inv*g0.x+b0.x; o0.y=d1*inv*g0.y+b0.y; o0.z=d2*inv*g0.z+b0.z; o0.w=d3*inv*g0.w+b0.w;
  o1.x=d4*inv*g1.x+b1.x; o1.y=d5*inv*g1.y+b1.y; o1.z=d6*inv*g1.z+b1.z; o1.w=d7*inv*g1.w+b1.w;
  float4* yr = (float4*)(y + ((size_t)row<<9));
  yr[lane*2]=o0; yr[lane*2+1]=o1;
}

// ---------------- GEMM: Y[n,o] = sum_k A[n,k]*W[o,k]  (+ fused epilogues) -------
#define EPI_BIAS 0
#define EPI_SCALE 1
#define EPI_GELU 2
#define EPI_RES 3
#define EPI_RELU_MASK 4
#define EPI_RES_MASK 5
#define EPI_RES_GAMMA_MASK 6
#define EPI_TANH 7

template<int EPI, bool AMASK>
__global__ __launch_bounds__(256) void gemm_nt(
    const float* __restrict__ A, const float* __restrict__ W,
    const float* __restrict__ bias, const float* __restrict__ res,
    const float* __restrict__ gamma, const float* __restrict__ rowmask,
    float* __restrict__ Y, int N, int K, int O, float scale)
{
  __shared__ float As[16][68];
  __shared__ float Bs[16][68];
  int t = threadIdx.x;
  int tx = t & 15, ty = t >> 4;
  int row0 = blockIdx.y << 6, col0 = blockIdx.x << 6;
  int lr = t >> 2, lk = (t & 3) << 2;
  float acc[4][4] = {};
  int ar = row0 + lr;
  bool arok = ar < N;
  const float* Ap = A + (size_t)(arok ? ar : 0) * K + lk;
  const float* Wp = W + (size_t)(col0 + lr) * K + lk;
  float am = 1.f;
  if (AMASK) am = arok ? rowmask[ar] : 0.f;
  for (int k0 = 0; k0 < K; k0 += 16) {
    float4 av;
    if (arok) av = *(const float4*)(Ap + k0);
    else { av.x=0;av.y=0;av.z=0;av.w=0; }
    if (AMASK) { av.x*=am; av.y*=am; av.z*=am; av.w*=am; }
    float4 bv = *(const float4*)(Wp + k0);
    As[lk+0][lr]=av.x; As[lk+1][lr]=av.y; As[lk+2][lr]=av.z; As[lk+3][lr]=av.w;
    Bs[lk+0][lr]=bv.x; Bs[lk+1][lr]=bv.y; Bs[lk+2][lr]=bv.z; Bs[lk+3][lr]=bv.w;
    __syncthreads();
    #pragma unroll
    for (int k=0;k<16;k++){
      float4 af = *(const float4*)&As[k][ty<<2];
      float4 bf = *(const float4*)&Bs[k][tx<<2];
      float a4[4]={af.x,af.y,af.z,af.w};
      float b4[4]={bf.x,bf.y,bf.z,bf.w};
      #pragma unroll
      for (int i=0;i<4;i++)
        #pragma unroll
        for (int j=0;j<4;j++)
          acc[i][j] += a4[i]*b4[j];
    }
    __syncthreads();
  }
  #pragma unroll
  for (int i=0;i<4;i++){
    int row = row0 + (ty<<2) + i;
    if (row >= N) break;
    int colb = col0 + (tx<<2);
    float rm = 1.f;
    if (EPI==EPI_RELU_MASK || EPI==EPI_RES_MASK || EPI==EPI_RES_GAMMA_MASK)
      rm = rowmask[row];
    const float* rr = nullptr;
    if (EPI==EPI_RES || EPI==EPI_RES_MASK || EPI==EPI_RES_GAMMA_MASK)
      rr = res + (size_t)row*O + colb;
    float vv_[4];
    #pragma unroll
    for (int j=0;j<4;j++){
      float v = acc[i][j] + bias[colb+j];
      if constexpr (EPI==EPI_SCALE) v *= scale;
      else if constexpr (EPI==EPI_GELU) v = 0.5f*v*(1.f+erff(v*0.7071067811865475f));
      else if constexpr (EPI==EPI_RES) v = rr[j] + v;
      else if constexpr (EPI==EPI_RELU_MASK) v = fmaxf(v,0.f)*rm;
      else if constexpr (EPI==EPI_RES_MASK) v = rr[j] + v*rm;
      else if constexpr (EPI==EPI_RES_GAMMA_MASK) v = (rr[j] + gamma[colb+j]*v)*rm;
      else if constexpr (EPI==EPI_TANH) v = tanhf(v);
      vv_[j]=v;
    }
    float4 ov; ov.x=vv_[0]; ov.y=vv_[1]; ov.z=vv_[2]; ov.w=vv_[3];
    *(float4*)(Y + (size_t)row*O + colb) = ov;
  }
}

// ---------------- tiled windowed-rel attention -------------------------------
// One block = one (b,h) and a tile of 32 query rows. 512 threads.
// QK: thread t owns q=t>>4, k's = (t&15)+16j (32 score regs, fully unrolled).
// P stored in LDS (pad 516 -> conflict-free AV reads). K/V staged in 128-row tiles.
__global__ __launch_bounds__(512) void attn_tile_k(const float* __restrict__ Q,
    const float* __restrict__ Kb, const float* __restrict__ Vb,
    const float* __restrict__ relk, const float* __restrict__ relv,
    const float* __restrict__ mask, float* __restrict__ O){
  __shared__ float Qs[32][68];
  __shared__ float KV[128][68];
  __shared__ float Sc[32][516];
  __shared__ float ms_[512];
  __shared__ float rk[9][64];
  __shared__ float rv[9][64];

  int qt = blockIdx.x;                // 0..15
  int bh = blockIdx.y;                // 0..63
  int h = bh & 7, b_ = bh >> 3;
  int t = threadIdx.x;
  int l0 = qt * 32;
  const size_t rowoff = (size_t)b_ * 512;

  // stage mask slice + rel tables + Q tile
  ms_[t & 511] = mask[rowoff + (t & 511)];
  for (int i = t; i < 576; i += 512){
    ((float*)rk)[i] = relk[i];
    ((float*)rv)[i] = relv[i];
  }
  {
    int r = t >> 4, c4 = (t & 15) << 2;    // 32 rows x 16 float4
    float4 qv = *(const float4*)&Q[((rowoff + l0 + r) << 9) + h*64 + c4];
    *(float4*)&Qs[r][c4] = qv;
  }
  __syncthreads();

  int q  = t >> 4;          // 0..31
  int kg = t & 15;          // 0..15
  int l  = l0 + q;          // global query row
  float ml = ms_[l];

  float sreg[4][8];
  // ---- QK over 4 K-tiles of 128 rows ----
  #pragma unroll
  for (int tt = 0; tt < 4; ++tt){
    __syncthreads();
    #pragma unroll
    for (int rep = 0; rep < 4; ++rep){
      int f4 = rep*512 + t;               // 2048 float4 = 128 rows x 16
      int r = f4 >> 4, c4 = (f4 & 15) << 2;
      float4 kv = *(const float4*)&Kb[((rowoff + tt*128 + r) << 9) + h*64 + c4];
      *(float4*)&KV[r][c4] = kv;
    }
    __syncthreads();
    float s8[8] = {0,0,0,0,0,0,0,0};
    for (int d4 = 0; d4 < 16; ++d4){
      float4 qv = *(const float4*)&Qs[q][d4<<2];
      #pragma unroll
      for (int jl = 0; jl < 8; ++jl){
        float4 kv = *(const float4*)&KV[kg + 16*jl][d4<<2];
        s8[jl] += qv.x*kv.x + qv.y*kv.y + qv.z*kv.z + qv.w*kv.w;
      }
    }
    #pragma unroll
    for (int jl = 0; jl < 8; ++jl) sreg[tt][jl] = s8[jl];
  }

  // ---- rel_k window add + attention mask ----
  #pragma unroll
  for (int j = 0; j < 32; ++j){
    int m = kg + 16*j;
    int dlt = m - l + 4;
    if (dlt >= 0 && dlt <= 8){
      float p = 0.f;
      for (int d4 = 0; d4 < 16; ++d4){
        float4 qv = *(const float4*)&Qs[q][d4<<2];
        float4 rkv = *(const float4*)&rk[dlt][d4<<2];
        p += qv.x*rkv.x + qv.y*rkv.y + qv.z*rkv.z + qv.w*rkv.w;
      }
      sreg[j>>3][j&7] += p;
    }
    if (ml * ms_[m] == 0.f) sreg[j>>3][j&7] = -10000.f;
  }

  // ---- softmax over the row (own 32 + 16-thread group reduce) ----
  float mx = -3.4e38f;
  #pragma unroll
  for (int j = 0; j < 32; ++j) mx = fmaxf(mx, sreg[j>>3][j&7]);
  #pragma unroll
  for (int o = 8; o >= 1; o >>= 1) mx = fmaxf(mx, __shfl_xor(mx, o));
  float sum = 0.f;
  #pragma unroll
  for (int j = 0; j < 32; ++j){
    float e = expf(sreg[j>>3][j&7] - mx);
    sreg[j>>3][j&7] = e;
    sum += e;
  }
  #pragma unroll
  for (int o = 8; o >= 1; o >>= 1) sum += __shfl_xor(sum, o);
  float inv = 1.f / sum;
  #pragma unroll
  for (int j = 0; j < 32; ++j) Sc[q][kg + 16*j] = sreg[j>>3][j&7] * inv;

  // ---- AV over 4 V-tiles of 128 rows ----
  int dg = t & 15;                       // output dims dg*4..dg*4+3
  float4 acc; acc.x=0; acc.y=0; acc.z=0; acc.w=0;
  for (int tt = 0; tt < 4; ++tt){
    __syncthreads();
    #pragma unroll
    for (int rep = 0; rep < 4; ++rep){
      int f4 = rep*512 + t;
      int r = f4 >> 4, c4 = (f4 & 15) << 2;
      float4 vv_ = *(const float4*)&Vb[((rowoff + tt*128 + r) << 9) + h*64 + c4];
      *(float4*)&KV[r][c4] = vv_;
    }
    __syncthreads();
    for (int mm = 0; mm < 128; mm += 4){
      float4 p4 = *(const float4*)&Sc[q][tt*128 + mm];
      float4 v0 = *(const float4*)&KV[mm+0][dg<<2];
      float4 v1 = *(const float4*)&KV[mm+1][dg<<2];
      float4 v2 = *(const float4*)&KV[mm+2][dg<<2];
      float4 v3 = *(const float4*)&KV[mm+3][dg<<2];
      acc.x += p4.x*v0.x + p4.y*v1.x + p4.z*v2.x + p4.w*v3.x;
      acc.y += p4.x*v0.y + p4.y*v1.y + p4.z*v2.y + p4.w*v3.y;
      acc.z += p4.x*v0.z + p4.y*v1.z + p4.z*v2.z + p4.w*v3.z;
      acc.w += p4.x*v0.w + p4.y*v1.w + p4.z*v2.w + p4.w*v3.w;
    }
  }
  // ---- rel_v window ----
  #pragma unroll
  for (int dlt = 0; dlt < 9; ++dlt){
    int m = l + dlt - 4;
    if (m >= 0 && m < 512){
      float p = Sc[q][m];
      float4 rvv = *(const float4*)&rv[dlt][dg<<2];
      acc.x += p*rvv.x; acc.y += p*rvv.y; acc.z += p*rvv.z; acc.w += p*rvv.w;
    }
  }
  *(float4*)&O[((rowoff + l) << 9) + h*64 + (dg<<2)] = acc;
}

// ---------------- style attention: lane-parallel over s ----------------------
__global__ __launch_bounds__(128) void style_attn_k(const float* __restrict__ Q,
    const float* __restrict__ kk, const float* __restrict__ vv,
    const float* __restrict__ mask, float* __restrict__ O){
  int n = blockIdx.x;
  int h = threadIdx.x >> 6, lane = threadIdx.x & 63;
  __shared__ float qh[512];      // both heads' q row
  __shared__ float aw[2][64];
  {
    float4 v = ((const float4*)(Q + ((size_t)n<<9)))[threadIdx.x];
    *(float4*)&qh[threadIdx.x*4] = v;
  }
  __syncthreads();
  float sc;
  if (lane < 50){
    float s = 0.f;
    const float* kr = kk + lane*512 + h*256;
    const float* qr = qh + h*256;
    for (int d4 = 0; d4 < 64; ++d4){
      float4 kv = *(const float4*)&kr[d4*4];
      s += qr[d4*4]*kv.x + qr[d4*4+1]*kv.y + qr[d4*4+2]*kv.z + qr[d4*4+3]*kv.w;
    }
    sc = s * 0.044194173824159216f;   // C**-0.5
  } else sc = -1e30f;
  float mx = wave_max(sc);
  float ex = (lane < 50) ? expf(sc - mx) : 0.f;
  float sm = wave_sum(ex);
  float keep = (mask[n] == 0.f) ? 0.f : 1.f;
  aw[h][lane] = ex / sm * keep;
  __syncthreads();
  float4 acc; acc.x=0; acc.y=0; acc.z=0; acc.w=0;
  const float* vb = vv + h*256 + lane*4;
  for (int s = 0; s < 50; ++s){
    float a = aw[h][s];
    const float4 vvv = *(const float4*)&vb[(size_t)s*512];
    acc.x += a*vvv.x; acc.y += a*vvv.y; acc.z += a*vvv.z; acc.w += a*vvv.w;
  }
  *(float4*)&O[((size_t)n<<9) + h*256 + lane*4] = acc;
}

// ---------------- final: out[b,c,l] = xn[b,l,c]*mask[b,l] ----------------
__global__ __launch_bounds__(256) void transpose_out_k(const float* __restrict__ xn,
    const float* __restrict__ mask, float* __restrict__ out){
  __shared__ float tile[32][33];
  int b_ = blockIdx.z; int c0 = blockIdx.x*32; int l0 = blockIdx.y*32;
  int tx = threadIdx.x & 31, ty = threadIdx.x >> 5;
  #pragma unroll
  for (int r=0;r<4;r++){
    int l = l0 + ty + r*8;
    tile[ty + r*8][tx] = xn[(((size_t)(b_*512 + l))<<9) + c0 + tx];
  }
  __syncthreads();
  float mm = mask[b_*512 + l0 + tx];
  #pragma unroll
  for (int r=0;r<4;r++){
    int c = c0 + ty + r*8;
    out[(((size_t)(b_*512 + c))<<9) + l0 + tx] = tile[tx][ty + r*8] * mm;
  }
}

extern "C" void kernel_launch(void* const* d_in, const int* in_sizes, int n_in,
                              void* d_out, int out_size, void* d_ws, size_t ws_size,
                              hipStream_t stream) {
  const int*   tokens   = (const int*)  d_in[0];
  const float* style_v  = (const float*)d_in[1];
  const float* mask     = (const float*)d_in[2];
  const float* embed_w  = (const float*)d_in[3];
  const float* cw_dw_w  = (const float*)d_in[4];
  const float* cw_dw_b  = (const float*)d_in[5];
  const float* cw_ln_g  = (const float*)d_in[6];
  const float* cw_ln_b  = (const float*)d_in[7];
  const float* cw_pw1_w = (const float*)d_in[8];
  const float* cw_pw1_b = (const float*)d_in[9];
  const float* cw_pw2_w = (const float*)d_in[10];
  const float* cw_pw2_b = (const float*)d_in[11];
  const float* cw_gamma = (const float*)d_in[12];
  const float* aq_w = (const float*)d_in[13];
  const float* aq_b = (const float*)d_in[14];
  const float* ak_w = (const float*)d_in[15];
  const float* ak_b = (const float*)d_in[16];
  const float* av_w = (const float*)d_in[17];
  const float* av_b = (const float*)d_in[18];
  const float* ao_w = (const float*)d_in[19];
  const float* ao_b = (const float*)d_in[20];
  const float* rel_k = (const float*)d_in[21];
  const float* rel_v = (const float*)d_in[22];
  const float* ln1_g = (const float*)d_in[23];
  const float* ln1_b = (const float*)d_in[24];
  const float* ln2_g = (const float*)d_in[25];
  const float* ln2_b = (const float*)d_in[26];
  const float* ffn_w1 = (const float*)d_in[27];
  const float* ffn_b1 = (const float*)d_in[28];
  const float* ffn_w2 = (const float*)d_in[29];
  const float* ffn_b2 = (const float*)d_in[30];
  const float* style_key = (const float*)d_in[31];
  const float* sq_w = (const float*)d_in[32];
  const float* sq_b = (const float*)d_in[33];
  const float* sk_w = (const float*)d_in[34];
  const float* sk_b = (const float*)d_in[35];
  const float* sv_w = (const float*)d_in[36];
  const float* sv_b = (const float*)d_in[37];
  const float* so_w = (const float*)d_in[38];
  const float* so_b = (const float*)d_in[39];
  const float* sn_g = (const float*)d_in[40];
  const float* sn_b = (const float*)d_in[41];

  const int N = NROWS;           // 4096 rows
  float* ws = (float*)d_ws;
  float* X  = ws;                         // (N,512)
  float* T  = X  + (size_t)N*512;         // (N,512)
  float* Qb = T  + (size_t)N*512;         // (N,512)
  float* Kb = Qb + (size_t)N*512;         // (N,512)
  float* Vb = Kb + (size_t)N*512;         // (N,512)
  float* Hb = Vb + (size_t)N*512;         // (N,2048)
  float* KK = Hb + (size_t)N*2048;        // 2*(50,512)
  float* VV = KK + 2*50*512;              // 2*(50,512)

  dim3 g512(8, 64), g2048(32, 64), gS(8, 1);

  embed_k<<<4096,128,0,stream>>>(tokens, embed_w, X);

  // ---- ConvNeXt blocks ----
  for (int i=0;i<4;i++){
    maskmul_k<<<2048,256,0,stream>>>(X, mask);
    dwconv_k<<<4096,128,0,stream>>>(X, cw_dw_w + (size_t)i*512*5, cw_dw_b + i*512, mask, T);
    ln_rows<<<1024,256,0,stream>>>(T, cw_ln_g+i*512, cw_ln_b+i*512, T, N);
    gemm_nt<EPI_GELU,false><<<g2048,256,0,stream>>>(T, cw_pw1_w + (size_t)i*2048*512,
        cw_pw1_b+i*2048, nullptr, nullptr, nullptr, Hb, N, 512, 2048, 0.f);
    gemm_nt<EPI_RES_GAMMA_MASK,false><<<g512,256,0,stream>>>(Hb, cw_pw2_w + (size_t)i*512*2048,
        cw_pw2_b+i*512, X, cw_gamma+i*512, mask, X, N, 2048, 512, 0.f);
  }
  maskmul_k<<<2048,256,0,stream>>>(X, mask);

  // ---- Attention layers ----
  for (int i=0;i<6;i++){
    size_t wo = (size_t)i*512*512;
    gemm_nt<EPI_SCALE,false><<<g512,256,0,stream>>>(X, aq_w+wo, aq_b+i*512,
        nullptr,nullptr,nullptr, Qb, N,512,512, 0.125f);
    gemm_nt<EPI_BIAS,false><<<g512,256,0,stream>>>(X, ak_w+wo, ak_b+i*512,
        nullptr,nullptr,nullptr, Kb, N,512,512, 0.f);
    gemm_nt<EPI_BIAS,false><<<g512,256,0,stream>>>(X, av_w+wo, av_b+i*512,
        nullptr,nullptr,nullptr, Vb, N,512,512, 0.f);
    attn_tile_k<<<dim3(16,64),512,0,stream>>>(Qb, Kb, Vb, rel_k + (size_t)i*9*64,
        rel_v + (size_t)i*9*64, mask, T);
    gemm_nt<EPI_RES,false><<<g512,256,0,stream>>>(T, ao_w+wo, ao_b+i*512,
        X, nullptr, nullptr, Qb, N,512,512, 0.f);
    ln_rows<<<1024,256,0,stream>>>(Qb, ln1_g+i*512, ln1_b+i*512, X, N);
    gemm_nt<EPI_RELU_MASK,true><<<g2048,256,0,stream>>>(X, ffn_w1 + (size_t)i*2048*512,
        ffn_b1+i*2048, nullptr, nullptr, mask, Hb, N,512,2048, 0.f);
    gemm_nt<EPI_RES_MASK,false><<<g512,256,0,stream>>>(Hb, ffn_w2 + (size_t)i*512*2048,
        ffn_b2+i*512, X, nullptr, mask, Qb, N,2048,512, 0.f);
    ln_rows<<<1024,256,0,stream>>>(Qb, ln2_g+i*512, ln2_b+i*512, X, N);
  }
  maskmul_k<<<2048,256,0,stream>>>(X, mask);

  // ---- Style attention ----
  gemm_nt<EPI_TANH,false><<<gS,256,0,stream>>>(style_key, sk_w, sk_b,
      nullptr,nullptr,nullptr, KK, 50,512,512, 0.f);
  gemm_nt<EPI_TANH,false><<<gS,256,0,stream>>>(style_key, sk_w+262144, sk_b+512,
      nullptr,nullptr,nullptr, KK+25600, 50,512,512, 0.f);
  gemm_nt<EPI_BIAS,false><<<gS,256,0,stream>>>(style_v, sv_w, sv_b,
      nullptr,nullptr,nullptr, VV, 50,512,512, 0.f);
  gemm_nt<EPI_BIAS,false><<<gS,256,0,stream>>>(style_v, sv_w+262144, sv_b+512,
      nullptr,nullptr,nullptr, VV+25600, 50,512,512, 0.f);

  // layer 0: xin = X (xt)
  gemm_nt<EPI_BIAS,false><<<g512,256,0,stream>>>(X, sq_w, sq_b,
      nullptr,nullptr,nullptr, Qb, N,512,512, 0.f);
  style_attn_k<<<4096,128,0,stream>>>(Qb, KK, VV, mask, T);
  gemm_nt<EPI_RES_MASK,false><<<g512,256,0,stream>>>(T, so_w, so_b,
      X, nullptr, mask, Kb, N,512,512, 0.f);          // x1 = xt + o*mask
  // layer 1: xin = x1 (Kb); residual still xt (X)
  gemm_nt<EPI_BIAS,false><<<g512,256,0,stream>>>(Kb, sq_w+262144, sq_b+512,
      nullptr,nullptr,nullptr, Qb, N,512,512, 0.f);
  style_attn_k<<<4096,128,0,stream>>>(Qb, KK+25600, VV+25600, mask, T);
  gemm_nt<EPI_RES_MASK,false><<<g512,256,0,stream>>>(T, so_w+262144, so_b+512,
      X, nullptr, mask, Vb, N,512,512, 0.f);          // x2 = xt + o*mask

  ln_rows<<<1024,256,0,stream>>>(Vb, sn_g, sn_b, Qb, N);
  transpose_out_k<<<dim3(16,16,8),256,0,stream>>>(Qb, mask, (float*)d_out);
}

// Round 5
// 5004.588 us; speedup vs baseline: 3.9120x; 3.9120x over previous
//
#include <hip/hip_runtime.h>
#include <cstdint>

// Model dims (fixed)
#define Bb 8
#define Ll 512
#define Cc 512
#define Hh 8
#define HD 64
#define Ff 2048
#define Ss 50
#define NROWS 4096   // B*L

__device__ __forceinline__ float wave_sum(float v){
  #pragma unroll
  for (int o=32;o>=1;o>>=1) v += __shfl_xor(v,o);
  return v;
}
__device__ __forceinline__ float wave_max(float v){
  #pragma unroll
  for (int o=32;o>=1;o>>=1) v = fmaxf(v,__shfl_xor(v,o));
  return v;
}

// ---------------- embed gather: x[(b*L+l)*C+c] = embed[tok][c] ----------------
__global__ __launch_bounds__(128) void embed_k(const int* __restrict__ tok,
    const float* __restrict__ emb, float* __restrict__ x){
  int n = blockIdx.x;
  int t = tok[n];
  ((float4*)(x + ((size_t)n<<9)))[threadIdx.x] =
      ((const float4*)(emb + ((size_t)t<<9)))[threadIdx.x];
}

// ---------------- x *= mask[row] (in-place) ----------------
__global__ __launch_bounds__(256) void maskmul_k(float* __restrict__ x,
    const float* __restrict__ mask){
  int i = blockIdx.x*256 + threadIdx.x;        // float4 index
  float m = mask[i >> 7];                      // row = (4*i)/512
  float4 v = ((float4*)x)[i];
  v.x*=m; v.y*=m; v.z*=m; v.w*=m;
  ((float4*)x)[i]=v;
}

// ---------------- depthwise conv K=5, edge-replicate pad, +bias, *mask --------
__global__ __launch_bounds__(128) void dwconv_k(const float* __restrict__ x,
    const float* __restrict__ w, const float* __restrict__ bias,
    const float* __restrict__ mask, float* __restrict__ h){
  int n = blockIdx.x; int b_ = n >> 9, l = n & 511;
  int c0 = threadIdx.x * 4;
  float acc0=bias[c0], acc1=bias[c0+1], acc2=bias[c0+2], acc3=bias[c0+3];
  #pragma unroll
  for (int k=0;k<5;k++){
    int ls = l + k - 2; ls = ls < 0 ? 0 : (ls > 511 ? 511 : ls);
    const float4 xv = *(const float4*)&x[((size_t)(b_*512 + ls) << 9) + c0];
    acc0 += w[(c0+0)*5+k]*xv.x;
    acc1 += w[(c0+1)*5+k]*xv.y;
    acc2 += w[(c0+2)*5+k]*xv.z;
    acc3 += w[(c0+3)*5+k]*xv.w;
  }
  float mm = mask[n];
  float4 o; o.x=acc0*mm; o.y=acc1*mm; o.z=acc2*mm; o.w=acc3*mm;
  *(float4*)&h[((size_t)n << 9) + c0] = o;
}

// ---------------- rowwise LayerNorm over C=512: one wave per row ----------------
__global__ __launch_bounds__(256) void ln_rows(const float* __restrict__ x,
    const float* __restrict__ g, const float* __restrict__ bt,
    float* __restrict__ y, int nrows){
  int wid = threadIdx.x >> 6, lane = threadIdx.x & 63;
  int row = blockIdx.x*4 + wid;
  if (row >= nrows) return;
  const float4* xr = (const float4*)(x + ((size_t)row<<9));
  float4 a = xr[lane*2], b = xr[lane*2+1];
  float s = a.x+a.y+a.z+a.w+b.x+b.y+b.z+b.w;
  s = wave_sum(s);
  float m = s * (1.f/512.f);
  float d0=a.x-m,d1=a.y-m,d2=a.z-m,d3=a.w-m,d4=b.x-m,d5=b.y-m,d6=b.z-m,d7=b.w-m;
  float sq = d0*d0+d1*d1+d2*d2+d3*d3+d4*d4+d5*d5+d6*d6+d7*d7;
  sq = wave_sum(sq);
  float var = sq * (1.f/512.f);
  float inv = 1.f/sqrtf(var + 1e-6f);
  const float4* gr = (const float4*)g; const float4* br = (const float4*)bt;
  float4 g0=gr[lane*2], g1=gr[lane*2+1], b0=br[lane*2], b1=br[lane*2+1];
  float4 o0, o1;
  o0.x=d0*inv*g0.x+b0.x; o0.y=d1*inv*g0.y+b0.y; o0.z=d2*inv*g0.z+b0.z; o0.w=d3*inv*g0.w+b0.w;
  o1.x=d4*inv*g1.x+b1.x; o1.y=d5*inv*g1.y+b1.y; o1.z=d6*inv*g1.z+b1.z; o1.w=d7*inv*g1.w+b1.w;
  float4* yr = (float4*)(y + ((size_t)row<<9));
  yr[lane*2]=o0; yr[lane*2+1]=o1;
}

// ---------------- GEMM: Y[n,o] = sum_k A[n,k]*W[o,k]  (+ fused epilogues) -------
#define EPI_BIAS 0
#define EPI_SCALE 1
#define EPI_GELU 2
#define EPI_RES 3
#define EPI_RELU_MASK 4
#define EPI_RES_MASK 5
#define EPI_RES_GAMMA_MASK 6
#define EPI_TANH 7

template<int EPI, bool AMASK>
__global__ __launch_bounds__(256) void gemm_nt(
    const float* __restrict__ A, const float* __restrict__ W,
    const float* __restrict__ bias, const float* __restrict__ res,
    const float* __restrict__ gamma, const float* __restrict__ rowmask,
    float* __restrict__ Y, int N, int K, int O, float scale)
{
  __shared__ float As[16][68];
  __shared__ float Bs[16][68];
  int t = threadIdx.x;
  int tx = t & 15, ty = t >> 4;
  int row0 = blockIdx.y << 6, col0 = blockIdx.x << 6;
  int lr = t >> 2, lk = (t & 3) << 2;
  float acc[4][4] = {};
  int ar = row0 + lr;
  bool arok = ar < N;
  const float* Ap = A + (size_t)(arok ? ar : 0) * K + lk;
  const float* Wp = W + (size_t)(col0 + lr) * K + lk;
  float am = 1.f;
  if (AMASK) am = arok ? rowmask[ar] : 0.f;
  for (int k0 = 0; k0 < K; k0 += 16) {
    float4 av;
    if (arok) av = *(const float4*)(Ap + k0);
    else { av.x=0;av.y=0;av.z=0;av.w=0; }
    if (AMASK) { av.x*=am; av.y*=am; av.z*=am; av.w*=am; }
    float4 bv = *(const float4*)(Wp + k0);
    As[lk+0][lr]=av.x; As[lk+1][lr]=av.y; As[lk+2][lr]=av.z; As[lk+3][lr]=av.w;
    Bs[lk+0][lr]=bv.x; Bs[lk+1][lr]=bv.y; Bs[lk+2][lr]=bv.z; Bs[lk+3][lr]=bv.w;
    __syncthreads();
    #pragma unroll
    for (int k=0;k<16;k++){
      float4 af = *(const float4*)&As[k][ty<<2];
      float4 bf = *(const float4*)&Bs[k][tx<<2];
      float a4[4]={af.x,af.y,af.z,af.w};
      float b4[4]={bf.x,bf.y,bf.z,bf.w};
      #pragma unroll
      for (int i=0;i<4;i++)
        #pragma unroll
        for (int j=0;j<4;j++)
          acc[i][j] += a4[i]*b4[j];
    }
    __syncthreads();
  }
  #pragma unroll
  for (int i=0;i<4;i++){
    int row = row0 + (ty<<2) + i;
    if (row >= N) break;
    int colb = col0 + (tx<<2);
    float rm = 1.f;
    if (EPI==EPI_RELU_MASK || EPI==EPI_RES_MASK || EPI==EPI_RES_GAMMA_MASK)
      rm = rowmask[row];
    const float* rr = nullptr;
    if (EPI==EPI_RES || EPI==EPI_RES_MASK || EPI==EPI_RES_GAMMA_MASK)
      rr = res + (size_t)row*O + colb;
    float vv_[4];
    #pragma unroll
    for (int j=0;j<4;j++){
      float v = acc[i][j] + bias[colb+j];
      if constexpr (EPI==EPI_SCALE) v *= scale;
      else if constexpr (EPI==EPI_GELU) v = 0.5f*v*(1.f+erff(v*0.7071067811865475f));
      else if constexpr (EPI==EPI_RES) v = rr[j] + v;
      else if constexpr (EPI==EPI_RELU_MASK) v = fmaxf(v,0.f)*rm;
      else if constexpr (EPI==EPI_RES_MASK) v = rr[j] + v*rm;
      else if constexpr (EPI==EPI_RES_GAMMA_MASK) v = (rr[j] + gamma[colb+j]*v)*rm;
      else if constexpr (EPI==EPI_TANH) v = tanhf(v);
      vv_[j]=v;
    }
    float4 ov; ov.x=vv_[0]; ov.y=vv_[1]; ov.z=vv_[2]; ov.w=vv_[3];
    *(float4*)(Y + (size_t)row*O + colb) = ov;
  }
}

// ---------------- tiled windowed-rel attention (spill-free) -------------------
// Block = (b,h, 16-query tile), 256 threads. Scores live in LDS only; the only
// per-thread state is 4 static scalars (s0..s3) and the fp32 accumulator.
// Softmax normalization is folded into the AV epilogue (out *= 1/sum).
__global__ __launch_bounds__(256) void attn_tile_k(const float* __restrict__ Q,
    const float* __restrict__ Kb, const float* __restrict__ Vb,
    const float* __restrict__ relk, const float* __restrict__ relv,
    const float* __restrict__ mask, float* __restrict__ O){
  __shared__ float ms_[512];
  __shared__ float rk[9][64];
  __shared__ float rv[9][64];
  __shared__ float Qs[16][68];
  __shared__ float qrel[16][12];
  __shared__ float KV[64][68];
  __shared__ float Sc[16][520];

  int qt = blockIdx.x;                 // 0..31
  int bh = blockIdx.y;                 // 0..63
  int h = bh & 7, b_ = bh >> 3;
  int t = threadIdx.x;
  int l0 = qt * 16;
  const size_t rowoff = (size_t)b_ * 512;

  // ---- stage mask, rel tables, Q tile ----
  ms_[t]       = mask[rowoff + t];
  ms_[t + 256] = mask[rowoff + t + 256];
  for (int i = t; i < 576; i += 256){
    ((float*)rk)[i] = relk[i];
    ((float*)rv)[i] = relv[i];
  }
  {
    int r = t >> 4, c4 = (t & 15) << 2;     // 16 rows x 16 float4
    *(float4*)&Qs[r][c4] =
        *(const float4*)&Q[((rowoff + l0 + r) << 9) + h*64 + c4];
  }
  __syncthreads();

  // ---- qrel[q][dlt] = Qs[q] . rk[dlt]  (144 dot-64 tasks) ----
  if (t < 144){
    int dlt = t >> 4, q_ = t & 15;
    float s = 0.f;
    for (int d = 0; d < 64; ++d) s += Qs[q_][d] * rk[dlt][d];
    qrel[q_][dlt] = s;
  }

  int q  = t >> 4;           // 0..15 query within tile
  int kg = t & 15;           // 0..15 key/dim group
  int l  = l0 + q;

  // ---- QK over 8 K-tiles of 64 rows; scores -> Sc (unnormalized) ----
  float ml = 0.f;
  for (int tt = 0; tt < 8; ++tt){
    __syncthreads();
    if (tt == 0) ml = ms_[l];
    #pragma unroll
    for (int rep = 0; rep < 4; ++rep){
      int f4 = rep*256 + t;                // 1024 float4 = 64 rows x 16
      int r = f4 >> 4, c4 = (f4 & 15) << 2;
      *(float4*)&KV[r][c4] =
          *(const float4*)&Kb[((rowoff + tt*64 + r) << 9) + h*64 + c4];
    }
    __syncthreads();
    float s0=0.f, s1=0.f, s2=0.f, s3=0.f;
    #pragma unroll 4
    for (int d4 = 0; d4 < 16; ++d4){
      float4 qv = *(const float4*)&Qs[q][d4<<2];
      float4 k0 = *(const float4*)&KV[kg     ][d4<<2];
      float4 k1 = *(const float4*)&KV[kg + 16][d4<<2];
      float4 k2 = *(const float4*)&KV[kg + 32][d4<<2];
      float4 k3 = *(const float4*)&KV[kg + 48][d4<<2];
      s0 += qv.x*k0.x + qv.y*k0.y + qv.z*k0.z + qv.w*k0.w;
      s1 += qv.x*k1.x + qv.y*k1.y + qv.z*k1.z + qv.w*k1.w;
      s2 += qv.x*k2.x + qv.y*k2.y + qv.z*k2.z + qv.w*k2.w;
      s3 += qv.x*k3.x + qv.y*k3.y + qv.z*k3.z + qv.w*k3.w;
    }
    int mb = tt*64 + kg;
    { int m = mb;      int dlt = m - l + 4;
      if (dlt >= 0 && dlt <= 8) s0 += qrel[q][dlt];
      if (ml * ms_[m] == 0.f) s0 = -10000.f;  Sc[q][m] = s0; }
    { int m = mb + 16; int dlt = m - l + 4;
      if (dlt >= 0 && dlt <= 8) s1 += qrel[q][dlt];
      if (ml * ms_[m] == 0.f) s1 = -10000.f;  Sc[q][m] = s1; }
    { int m = mb + 32; int dlt = m - l + 4;
      if (dlt >= 0 && dlt <= 8) s2 += qrel[q][dlt];
      if (ml * ms_[m] == 0.f) s2 = -10000.f;  Sc[q][m] = s2; }
    { int m = mb + 48; int dlt = m - l + 4;
      if (dlt >= 0 && dlt <= 8) s3 += qrel[q][dlt];
      if (ml * ms_[m] == 0.f) s3 = -10000.f;  Sc[q][m] = s3; }
  }

  // ---- softmax on self-owned columns (kg + 16*jj); 16-lane group reduce ----
  float mx = -3.4e38f;
  for (int jj = 0; jj < 32; ++jj) mx = fmaxf(mx, Sc[q][kg + 16*jj]);
  #pragma unroll
  for (int o = 8; o >= 1; o >>= 1) mx = fmaxf(mx, __shfl_xor(mx, o));
  float sum = 0.f;
  for (int jj = 0; jj < 32; ++jj){
    float e = expf(Sc[q][kg + 16*jj] - mx);
    sum += e;
    Sc[q][kg + 16*jj] = e;
  }
  #pragma unroll
  for (int o = 8; o >= 1; o >>= 1) sum += __shfl_xor(sum, o);
  float inv = 1.f / sum;

  // ---- AV over 8 V-tiles of 64 rows; dg = kg owns dims dg*4..dg*4+3 ----
  int dg = kg;
  float4 acc; acc.x=0.f; acc.y=0.f; acc.z=0.f; acc.w=0.f;
  for (int tt = 0; tt < 8; ++tt){
    __syncthreads();
    #pragma unroll
    for (int rep = 0; rep < 4; ++rep){
      int f4 = rep*256 + t;
      int r = f4 >> 4, c4 = (f4 & 15) << 2;
      *(float4*)&KV[r][c4] =
          *(const float4*)&Vb[((rowoff + tt*64 + r) << 9) + h*64 + c4];
    }
    __syncthreads();
    int base = tt*64;
    #pragma unroll 4
    for (int mm = 0; mm < 64; mm += 4){
      float p0 = Sc[q][base+mm+0], p1 = Sc[q][base+mm+1];
      float p2 = Sc[q][base+mm+2], p3 = Sc[q][base+mm+3];
      float4 v0 = *(const float4*)&KV[mm+0][dg<<2];
      float4 v1 = *(const float4*)&KV[mm+1][dg<<2];
      float4 v2 = *(const float4*)&KV[mm+2][dg<<2];
      float4 v3 = *(const float4*)&KV[mm+3][dg<<2];
      acc.x += p0*v0.x + p1*v1.x + p2*v2.x + p3*v3.x;
      acc.y += p0*v0.y + p1*v1.y + p2*v2.y + p3*v3.y;
      acc.z += p0*v0.z + p1*v1.z + p2*v2.z + p3*v3.z;
      acc.w += p0*v0.w + p1*v1.w + p2*v2.w + p3*v3.w;
    }
  }
  // ---- rel_v window (uses unnormalized e's, normalized at the end) ----
  #pragma unroll
  for (int dlt = 0; dlt < 9; ++dlt){
    int m = l + dlt - 4;
    if (m >= 0 && m < 512){
      float p = Sc[q][m];
      float4 r4 = *(const float4*)&rv[dlt][dg<<2];
      acc.x += p*r4.x; acc.y += p*r4.y; acc.z += p*r4.z; acc.w += p*r4.w;
    }
  }
  acc.x *= inv; acc.y *= inv; acc.z *= inv; acc.w *= inv;
  *(float4*)&O[((rowoff + l) << 9) + h*64 + (dg<<2)] = acc;
}

// ---------------- style attention: lane-parallel over s ----------------------
__global__ __launch_bounds__(128) void style_attn_k(const float* __restrict__ Q,
    const float* __restrict__ kk, const float* __restrict__ vv,
    const float* __restrict__ mask, float* __restrict__ O){
  int n = blockIdx.x;
  int h = threadIdx.x >> 6, lane = threadIdx.x & 63;
  __shared__ float qh[512];      // both heads' q row
  __shared__ float aw[2][64];
  {
    float4 v = ((const float4*)(Q + ((size_t)n<<9)))[threadIdx.x];
    *(float4*)&qh[threadIdx.x*4] = v;
  }
  __syncthreads();
  float sc;
  if (lane < 50){
    float s = 0.f;
    const float* kr = kk + lane*512 + h*256;
    const float* qr = qh + h*256;
    for (int d4 = 0; d4 < 64; ++d4){
      float4 kv = *(const float4*)&kr[d4*4];
      s += qr[d4*4]*kv.x + qr[d4*4+1]*kv.y + qr[d4*4+2]*kv.z + qr[d4*4+3]*kv.w;
    }
    sc = s * 0.044194173824159216f;   // C**-0.5
  } else sc = -1e30f;
  float mx = wave_max(sc);
  float ex = (lane < 50) ? expf(sc - mx) : 0.f;
  float sm = wave_sum(ex);
  float keep = (mask[n] == 0.f) ? 0.f : 1.f;
  aw[h][lane] = ex / sm * keep;
  __syncthreads();
  float4 acc; acc.x=0; acc.y=0; acc.z=0; acc.w=0;
  const float* vb = vv + h*256 + lane*4;
  for (int s = 0; s < 50; ++s){
    float a = aw[h][s];
    const float4 vvv = *(const float4*)&vb[(size_t)s*512];
    acc.x += a*vvv.x; acc.y += a*vvv.y; acc.z += a*vvv.z; acc.w += a*vvv.w;
  }
  *(float4*)&O[((size_t)n<<9) + h*256 + lane*4] = acc;
}

// ---------------- final: out[b,c,l] = xn[b,l,c]*mask[b,l] ----------------
__global__ __launch_bounds__(256) void transpose_out_k(const float* __restrict__ xn,
    const float* __restrict__ mask, float* __restrict__ out){
  __shared__ float tile[32][33];
  int b_ = blockIdx.z; int c0 = blockIdx.x*32; int l0 = blockIdx.y*32;
  int tx = threadIdx.x & 31, ty = threadIdx.x >> 5;
  #pragma unroll
  for (int r=0;r<4;r++){
    int l = l0 + ty + r*8;
    tile[ty + r*8][tx] = xn[(((size_t)(b_*512 + l))<<9) + c0 + tx];
  }
  __syncthreads();
  float mm = mask[b_*512 + l0 + tx];
  #pragma unroll
  for (int r=0;r<4;r++){
    int c = c0 + ty + r*8;
    out[(((size_t)(b_*512 + c))<<9) + l0 + tx] = tile[tx][ty + r*8] * mm;
  }
}

extern "C" void kernel_launch(void* const* d_in, const int* in_sizes, int n_in,
                              void* d_out, int out_size, void* d_ws, size_t ws_size,
                              hipStream_t stream) {
  const int*   tokens   = (const int*)  d_in[0];
  const float* style_v  = (const float*)d_in[1];
  const float* mask     = (const float*)d_in[2];
  const float* embed_w  = (const float*)d_in[3];
  const float* cw_dw_w  = (const float*)d_in[4];
  const float* cw_dw_b  = (const float*)d_in[5];
  const float* cw_ln_g  = (const float*)d_in[6];
  const float* cw_ln_b  = (const float*)d_in[7];
  const float* cw_pw1_w = (const float*)d_in[8];
  const float* cw_pw1_b = (const float*)d_in[9];
  const float* cw_pw2_w = (const float*)d_in[10];
  const float* cw_pw2_b = (const float*)d_in[11];
  const float* cw_gamma = (const float*)d_in[12];
  const float* aq_w = (const float*)d_in[13];
  const float* aq_b = (const float*)d_in[14];
  const float* ak_w = (const float*)d_in[15];
  const float* ak_b = (const float*)d_in[16];
  const float* av_w = (const float*)d_in[17];
  const float* av_b = (const float*)d_in[18];
  const float* ao_w = (const float*)d_in[19];
  const float* ao_b = (const float*)d_in[20];
  const float* rel_k = (const float*)d_in[21];
  const float* rel_v = (const float*)d_in[22];
  const float* ln1_g = (const float*)d_in[23];
  const float* ln1_b = (const float*)d_in[24];
  const float* ln2_g = (const float*)d_in[25];
  const float* ln2_b = (const float*)d_in[26];
  const float* ffn_w1 = (const float*)d_in[27];
  const float* ffn_b1 = (const float*)d_in[28];
  const float* ffn_w2 = (const float*)d_in[29];
  const float* ffn_b2 = (const float*)d_in[30];
  const float* style_key = (const float*)d_in[31];
  const float* sq_w = (const float*)d_in[32];
  const float* sq_b = (const float*)d_in[33];
  const float* sk_w = (const float*)d_in[34];
  const float* sk_b = (const float*)d_in[35];
  const float* sv_w = (const float*)d_in[36];
  const float* sv_b = (const float*)d_in[37];
  const float* so_w = (const float*)d_in[38];
  const float* so_b = (const float*)d_in[39];
  const float* sn_g = (const float*)d_in[40];
  const float* sn_b = (const float*)d_in[41];

  const int N = NROWS;           // 4096 rows
  float* ws = (float*)d_ws;
  float* X  = ws;                         // (N,512)
  float* T  = X  + (size_t)N*512;         // (N,512)
  float* Qb = T  + (size_t)N*512;         // (N,512)
  float* Kb = Qb + (size_t)N*512;         // (N,512)
  float* Vb = Kb + (size_t)N*512;         // (N,512)
  float* Hb = Vb + (size_t)N*512;         // (N,2048)
  float* KK = Hb + (size_t)N*2048;        // 2*(50,512)
  float* VV = KK + 2*50*512;              // 2*(50,512)

  dim3 g512(8, 64), g2048(32, 64), gS(8, 1);

  embed_k<<<4096,128,0,stream>>>(tokens, embed_w, X);

  // ---- ConvNeXt blocks ----
  for (int i=0;i<4;i++){
    maskmul_k<<<2048,256,0,stream>>>(X, mask);
    dwconv_k<<<4096,128,0,stream>>>(X, cw_dw_w + (size_t)i*512*5, cw_dw_b + i*512, mask, T);
    ln_rows<<<1024,256,0,stream>>>(T, cw_ln_g+i*512, cw_ln_b+i*512, T, N);
    gemm_nt<EPI_GELU,false><<<g2048,256,0,stream>>>(T, cw_pw1_w + (size_t)i*2048*512,
        cw_pw1_b+i*2048, nullptr, nullptr, nullptr, Hb, N, 512, 2048, 0.f);
    gemm_nt<EPI_RES_GAMMA_MASK,false><<<g512,256,0,stream>>>(Hb, cw_pw2_w + (size_t)i*512*2048,
        cw_pw2_b+i*512, X, cw_gamma+i*512, mask, X, N, 2048, 512, 0.f);
  }
  maskmul_k<<<2048,256,0,stream>>>(X, mask);

  // ---- Attention layers ----
  for (int i=0;i<6;i++){
    size_t wo = (size_t)i*512*512;
    gemm_nt<EPI_SCALE,false><<<g512,256,0,stream>>>(X, aq_w+wo, aq_b+i*512,
        nullptr,nullptr,nullptr, Qb, N,512,512, 0.125f);
    gemm_nt<EPI_BIAS,false><<<g512,256,0,stream>>>(X, ak_w+wo, ak_b+i*512,
        nullptr,nullptr,nullptr, Kb, N,512,512, 0.f);
    gemm_nt<EPI_BIAS,false><<<g512,256,0,stream>>>(X, av_w+wo, av_b+i*512,
        nullptr,nullptr,nullptr, Vb, N,512,512, 0.f);
    attn_tile_k<<<dim3(32,64),256,0,stream>>>(Qb, Kb, Vb, rel_k + (size_t)i*9*64,
        rel_v + (size_t)i*9*64, mask, T);
    gemm_nt<EPI_RES,false><<<g512,256,0,stream>>>(T, ao_w+wo, ao_b+i*512,
        X, nullptr, nullptr, Qb, N,512,512, 0.f);
    ln_rows<<<1024,256,0,stream>>>(Qb, ln1_g+i*512, ln1_b+i*512, X, N);
    gemm_nt<EPI_RELU_MASK,true><<<g2048,256,0,stream>>>(X, ffn_w1 + (size_t)i*2048*512,
        ffn_b1+i*2048, nullptr, nullptr, mask, Hb, N,512,2048, 0.f);
    gemm_nt<EPI_RES_MASK,false><<<g512,256,0,stream>>>(Hb, ffn_w2 + (size_t)i*512*2048,
        ffn_b2+i*512, X, nullptr, mask, Qb, N,2048,512, 0.f);
    ln_rows<<<1024,256,0,stream>>>(Qb, ln2_g+i*512, ln2_b+i*512, X, N);
  }
  maskmul_k<<<2048,256,0,stream>>>(X, mask);

  // ---- Style attention ----
  gemm_nt<EPI_TANH,false><<<gS,256,0,stream>>>(style_key, sk_w, sk_b,
      nullptr,nullptr,nullptr, KK, 50,512,512, 0.f);
  gemm_nt<EPI_TANH,false><<<gS,256,0,stream>>>(style_key, sk_w+262144, sk_b+512,
      nullptr,nullptr,nullptr, KK+25600, 50,512,512, 0.f);
  gemm_nt<EPI_BIAS,false><<<gS,256,0,stream>>>(style_v, sv_w, sv_b,
      nullptr,nullptr,nullptr, VV, 50,512,512, 0.f);
  gemm_nt<EPI_BIAS,false><<<gS,256,0,stream>>>(style_v, sv_w+262144, sv_b+512,
      nullptr,nullptr,nullptr, VV+25600, 50,512,512, 0.f);

  // layer 0: xin = X (xt)
  gemm_nt<EPI_BIAS,false><<<g512,256,0,stream>>>(X, sq_w, sq_b,
      nullptr,nullptr,nullptr, Qb, N,512,512, 0.f);
  style_attn_k<<<4096,128,0,stream>>>(Qb, KK, VV, mask, T);
  gemm_nt<EPI_RES_MASK,false><<<g512,256,0,stream>>>(T, so_w, so_b,
      X, nullptr, mask, Kb, N,512,512, 0.f);          // x1 = xt + o*mask
  // layer 1: xin = x1 (Kb); residual still xt (X)
  gemm_nt<EPI_BIAS,false><<<g512,256,0,stream>>>(Kb, sq_w+262144, sq_b+512,
      nullptr,nullptr,nullptr, Qb, N,512,512, 0.f);
  style_attn_k<<<4096,128,0,stream>>>(Qb, KK+25600, VV+25600, mask, T);
  gemm_nt<EPI_RES_MASK,false><<<g512,256,0,stream>>>(T, so_w+262144, so_b+512,
      X, nullptr, mask, Vb, N,512,512, 0.f);          // x2 = xt + o*mask

  ln_rows<<<1024,256,0,stream>>>(Vb, sn_g, sn_b, Qb, N);
  transpose_out_k<<<dim3(16,16,8),256,0,stream>>>(Qb, mask, (float*)d_out);
}

// Round 6
// 3080.735 us; speedup vs baseline: 6.3550x; 1.6245x over previous
//
#include <hip/hip_runtime.h>
#include <cstdint>

// Model dims (fixed)
#define Bb 8
#define Ll 512
#define Cc 512
#define Hh 8
#define HD 64
#define Ff 2048
#define Ss 50
#define NROWS 4096   // B*L

typedef __attribute__((ext_vector_type(8))) short short8v;  // 8 bf16 (4 VGPR)
typedef __attribute__((ext_vector_type(4))) float f32x4;

__device__ __forceinline__ float wave_sum(float v){
  #pragma unroll
  for (int o=32;o>=1;o>>=1) v += __shfl_xor(v,o);
  return v;
}
__device__ __forceinline__ float wave_max(float v){
  #pragma unroll
  for (int o=32;o>=1;o>>=1) v = fmaxf(v,__shfl_xor(v,o));
  return v;
}

// split fp32 -> bf16 hi + bf16 lo (RNE both);  a ~= hi + lo, |err| ~ 2^-18 |a|
__device__ __forceinline__ void splitf(float a, unsigned short& hi, unsigned short& lo){
  unsigned u = __float_as_uint(a);
  unsigned r = u + 0x7FFFu + ((u>>16)&1u);
  hi = (unsigned short)(r >> 16);
  float hif = __uint_as_float(((unsigned)hi) << 16);
  float l = a - hif;
  unsigned ul = __float_as_uint(l);
  unsigned rl = ul + 0x7FFFu + ((ul>>16)&1u);
  lo = (unsigned short)(rl >> 16);
}
__device__ __forceinline__ void wr8(unsigned short* ph, unsigned short* pl, float4 v){
  unsigned short h0,h1,h2,h3,l0,l1,l2,l3;
  splitf(v.x,h0,l0); splitf(v.y,h1,l1); splitf(v.z,h2,l2); splitf(v.w,h3,l3);
  *(ushort4*)ph = make_ushort4(h0,h1,h2,h3);
  *(ushort4*)pl = make_ushort4(l0,l1,l2,l3);
}

// ---------------- embed gather ----------------
__global__ __launch_bounds__(128) void embed_k(const int* __restrict__ tok,
    const float* __restrict__ emb, float* __restrict__ x){
  int n = blockIdx.x;
  int t = tok[n];
  ((float4*)(x + ((size_t)n<<9)))[threadIdx.x] =
      ((const float4*)(emb + ((size_t)t<<9)))[threadIdx.x];
}

// ---------------- x *= mask[row] ----------------
__global__ __launch_bounds__(256) void maskmul_k(float* __restrict__ x,
    const float* __restrict__ mask){
  int i = blockIdx.x*256 + threadIdx.x;
  float m = mask[i >> 7];
  float4 v = ((float4*)x)[i];
  v.x*=m; v.y*=m; v.z*=m; v.w*=m;
  ((float4*)x)[i]=v;
}

// ---------------- depthwise conv K=5, edge pad, +bias, *mask --------
__global__ __launch_bounds__(128) void dwconv_k(const float* __restrict__ x,
    const float* __restrict__ w, const float* __restrict__ bias,
    const float* __restrict__ mask, float* __restrict__ h){
  int n = blockIdx.x; int b_ = n >> 9, l = n & 511;
  int c0 = threadIdx.x * 4;
  float acc0=bias[c0], acc1=bias[c0+1], acc2=bias[c0+2], acc3=bias[c0+3];
  #pragma unroll
  for (int k=0;k<5;k++){
    int ls = l + k - 2; ls = ls < 0 ? 0 : (ls > 511 ? 511 : ls);
    const float4 xv = *(const float4*)&x[((size_t)(b_*512 + ls) << 9) + c0];
    acc0 += w[(c0+0)*5+k]*xv.x;
    acc1 += w[(c0+1)*5+k]*xv.y;
    acc2 += w[(c0+2)*5+k]*xv.z;
    acc3 += w[(c0+3)*5+k]*xv.w;
  }
  float mm = mask[n];
  float4 o; o.x=acc0*mm; o.y=acc1*mm; o.z=acc2*mm; o.w=acc3*mm;
  *(float4*)&h[((size_t)n << 9) + c0] = o;
}

// ---------------- rowwise LayerNorm over C=512 ----------------
__global__ __launch_bounds__(256) void ln_rows(const float* __restrict__ x,
    const float* __restrict__ g, const float* __restrict__ bt,
    float* __restrict__ y, int nrows){
  int wid = threadIdx.x >> 6, lane = threadIdx.x & 63;
  int row = blockIdx.x*4 + wid;
  if (row >= nrows) return;
  const float4* xr = (const float4*)(x + ((size_t)row<<9));
  float4 a = xr[lane*2], b = xr[lane*2+1];
  float s = a.x+a.y+a.z+a.w+b.x+b.y+b.z+b.w;
  s = wave_sum(s);
  float m = s * (1.f/512.f);
  float d0=a.x-m,d1=a.y-m,d2=a.z-m,d3=a.w-m,d4=b.x-m,d5=b.y-m,d6=b.z-m,d7=b.w-m;
  float sq = d0*d0+d1*d1+d2*d2+d3*d3+d4*d4+d5*d5+d6*d6+d7*d7;
  sq = wave_sum(sq);
  float var = sq * (1.f/512.f);
  float inv = 1.f/sqrtf(var + 1e-6f);
  const float4* gr = (const float4*)g; const float4* br = (const float4*)bt;
  float4 g0=gr[lane*2], g1=gr[lane*2+1], b0=br[lane*2], b1=br[lane*2+1];
  float4 o0, o1;
  o0.x=d0*inv*g0.x+b0.x; o0.y=d1*inv*g0.y+b0.y; o0.z=d2*inv*g0.z+b0.z; o0.w=d3*inv*g0.w+b0.w;
  o1.x=d4*inv*g1.x+b1.x; o1.y=d5*inv*g1.y+b1.y; o1.z=d6*inv*g1.z+b1.z; o1.w=d7*inv*g1.w+b1.w;
  float4* yr = (float4*)(y + ((size_t)row<<9));
  yr[lane*2]=o0; yr[lane*2+1]=o1;
}

#define EPI_BIAS 0
#define EPI_SCALE 1
#define EPI_GELU 2
#define EPI_RES 3
#define EPI_RELU_MASK 4
#define EPI_RES_MASK 5
#define EPI_RES_GAMMA_MASK 6
#define EPI_TANH 7

// ---------------- fp32 VALU GEMM (small style GEMMs only) ----------------
template<int EPI, bool AMASK>
__global__ __launch_bounds__(256) void gemm_nt(
    const float* __restrict__ A, const float* __restrict__ W,
    const float* __restrict__ bias, const float* __restrict__ res,
    const float* __restrict__ gamma, const float* __restrict__ rowmask,
    float* __restrict__ Y, int N, int K, int O, float scale)
{
  __shared__ float As[16][68];
  __shared__ float Bs[16][68];
  int t = threadIdx.x;
  int tx = t & 15, ty = t >> 4;
  int row0 = blockIdx.y << 6, col0 = blockIdx.x << 6;
  int lr = t >> 2, lk = (t & 3) << 2;
  float acc[4][4] = {};
  int ar = row0 + lr;
  bool arok = ar < N;
  const float* Ap = A + (size_t)(arok ? ar : 0) * K + lk;
  const float* Wp = W + (size_t)(col0 + lr) * K + lk;
  float am = 1.f;
  if (AMASK) am = arok ? rowmask[ar] : 0.f;
  for (int k0 = 0; k0 < K; k0 += 16) {
    float4 av;
    if (arok) av = *(const float4*)(Ap + k0);
    else { av.x=0;av.y=0;av.z=0;av.w=0; }
    if (AMASK) { av.x*=am; av.y*=am; av.z*=am; av.w*=am; }
    float4 bv = *(const float4*)(Wp + k0);
    As[lk+0][lr]=av.x; As[lk+1][lr]=av.y; As[lk+2][lr]=av.z; As[lk+3][lr]=av.w;
    Bs[lk+0][lr]=bv.x; Bs[lk+1][lr]=bv.y; Bs[lk+2][lr]=bv.z; Bs[lk+3][lr]=bv.w;
    __syncthreads();
    #pragma unroll
    for (int k=0;k<16;k++){
      float4 af = *(const float4*)&As[k][ty<<2];
      float4 bf = *(const float4*)&Bs[k][tx<<2];
      float a4[4]={af.x,af.y,af.z,af.w};
      float b4[4]={bf.x,bf.y,bf.z,bf.w};
      #pragma unroll
      for (int i=0;i<4;i++)
        #pragma unroll
        for (int j=0;j<4;j++)
          acc[i][j] += a4[i]*b4[j];
    }
    __syncthreads();
  }
  #pragma unroll
  for (int i=0;i<4;i++){
    int row = row0 + (ty<<2) + i;
    if (row >= N) break;
    int colb = col0 + (tx<<2);
    float vv_[4];
    #pragma unroll
    for (int j=0;j<4;j++){
      float v = acc[i][j] + bias[colb+j];
      if constexpr (EPI==EPI_TANH) v = tanhf(v);
      vv_[j]=v;
    }
    float4 ov; ov.x=vv_[0]; ov.y=vv_[1]; ov.z=vv_[2]; ov.w=vv_[3];
    *(float4*)(Y + (size_t)row*O + colb) = ov;
  }
}

// ---------------- split-bf16 MFMA GEMM: Y[n,o] = sum_k A[n,k]*W[o,k] ----------
// Tile 64(M) x 128(N) x 32(K). 4 waves 2x2; wave tile 32x64 = 2x4 fragments.
// a = hi+lo (bf16 RNE); acc += ah*bh + ah*bl + al*bh  (fp32-grade accuracy).
template<int EPI, bool AMASK>
__global__ __launch_bounds__(256) void gemm_mfma(
    const float* __restrict__ A, const float* __restrict__ W,
    const float* __restrict__ bias, const float* __restrict__ res,
    const float* __restrict__ gamma, const float* __restrict__ rowmask,
    float* __restrict__ Y, int K, int O, float scale)
{
  __shared__ unsigned short Ah[64][40], Al[64][40];
  __shared__ unsigned short Bh[128][40], Bl[128][40];
  int t = threadIdx.x;
  int row0 = blockIdx.y << 6;
  int col0 = blockIdx.x << 7;
  int lane = t & 63, wid = t >> 6;
  int wr = wid >> 1, wc = wid & 1;

  // staging: A rows ar0, ar0+32 (same col); B rows br0+32r (same col)
  int ar0 = t >> 3, ac0 = (t & 7) << 2;
  const float* Arow0 = A + (size_t)(row0 + ar0) * K + ac0;
  const float* Brow0 = W + (size_t)(col0 + ar0) * K + ac0;
  float amk0 = 1.f, amk1 = 1.f;
  if (AMASK){ amk0 = rowmask[row0 + ar0]; amk1 = rowmask[row0 + ar0 + 32]; }

  f32x4 acc[2][4] = {};
  int nsteps = K >> 5;
  float4 a0 = *(const float4*)(Arow0);
  float4 a1 = *(const float4*)(Arow0 + (size_t)32*K);
  float4 b0 = *(const float4*)(Brow0);
  float4 b1 = *(const float4*)(Brow0 + (size_t)32*K);
  float4 b2 = *(const float4*)(Brow0 + (size_t)64*K);
  float4 b3 = *(const float4*)(Brow0 + (size_t)96*K);

  for (int s = 0; s < nsteps; ++s){
    if (AMASK){
      a0.x*=amk0; a0.y*=amk0; a0.z*=amk0; a0.w*=amk0;
      a1.x*=amk1; a1.y*=amk1; a1.z*=amk1; a1.w*=amk1;
    }
    __syncthreads();
    wr8(&Ah[ar0][ac0],    &Al[ar0][ac0],    a0);
    wr8(&Ah[ar0+32][ac0], &Al[ar0+32][ac0], a1);
    wr8(&Bh[ar0][ac0],    &Bl[ar0][ac0],    b0);
    wr8(&Bh[ar0+32][ac0], &Bl[ar0+32][ac0], b1);
    wr8(&Bh[ar0+64][ac0], &Bl[ar0+64][ac0], b2);
    wr8(&Bh[ar0+96][ac0], &Bl[ar0+96][ac0], b3);
    __syncthreads();
    if (s + 1 < nsteps){
      int ko = (s + 1) << 5;
      a0 = *(const float4*)(Arow0 + ko);
      a1 = *(const float4*)(Arow0 + (size_t)32*K + ko);
      b0 = *(const float4*)(Brow0 + ko);
      b1 = *(const float4*)(Brow0 + (size_t)32*K + ko);
      b2 = *(const float4*)(Brow0 + (size_t)64*K + ko);
      b3 = *(const float4*)(Brow0 + (size_t)96*K + ko);
    }
    int fr = lane & 15, fc = (lane >> 4) << 3;
    short8v ah[2], al[2], bh4[4], bl4[4];
    #pragma unroll
    for (int mt=0; mt<2; ++mt){
      int r = (wr<<5) + (mt<<4) + fr;
      ah[mt] = *(const short8v*)&Ah[r][fc];
      al[mt] = *(const short8v*)&Al[r][fc];
    }
    #pragma unroll
    for (int nt=0; nt<4; ++nt){
      int r = (wc<<6) + (nt<<4) + fr;
      bh4[nt] = *(const short8v*)&Bh[r][fc];
      bl4[nt] = *(const short8v*)&Bl[r][fc];
    }
    #pragma unroll
    for (int mt=0; mt<2; ++mt)
      #pragma unroll
      for (int nt=0; nt<4; ++nt){
        f32x4 c = acc[mt][nt];
        c = __builtin_amdgcn_mfma_f32_16x16x32_bf16(ah[mt], bh4[nt], c, 0,0,0);
        c = __builtin_amdgcn_mfma_f32_16x16x32_bf16(ah[mt], bl4[nt], c, 0,0,0);
        c = __builtin_amdgcn_mfma_f32_16x16x32_bf16(al[mt], bh4[nt], c, 0,0,0);
        acc[mt][nt] = c;
      }
  }

  // epilogue: C/D layout col=lane&15, row=(lane>>4)*4+j  [m89/m91]
  int rb = row0 + (wr<<5) + ((lane>>4)<<2);
  int cb = col0 + (wc<<6) + (lane & 15);
  float bs[4], gm[4];
  #pragma unroll
  for (int nt=0; nt<4; ++nt){
    bs[nt] = bias[cb + (nt<<4)];
    if constexpr (EPI==EPI_RES_GAMMA_MASK) gm[nt] = gamma[cb + (nt<<4)];
  }
  #pragma unroll
  for (int mt=0; mt<2; ++mt)
    #pragma unroll
    for (int j=0; j<4; ++j){
      int row = rb + (mt<<4) + j;
      float rm = 1.f;
      if constexpr (EPI==EPI_RELU_MASK || EPI==EPI_RES_MASK || EPI==EPI_RES_GAMMA_MASK)
        rm = rowmask[row];
      const float* rr = nullptr;
      if constexpr (EPI==EPI_RES || EPI==EPI_RES_MASK || EPI==EPI_RES_GAMMA_MASK)
        rr = res + (size_t)row*O + cb;
      float* yr = Y + (size_t)row*O + cb;
      #pragma unroll
      for (int nt=0; nt<4; ++nt){
        float v = acc[mt][nt][j] + bs[nt];
        if constexpr (EPI==EPI_SCALE) v *= scale;
        else if constexpr (EPI==EPI_GELU) v = 0.5f*v*(1.f+erff(v*0.7071067811865475f));
        else if constexpr (EPI==EPI_RES) v = rr[nt<<4] + v;
        else if constexpr (EPI==EPI_RELU_MASK) v = fmaxf(v,0.f)*rm;
        else if constexpr (EPI==EPI_RES_MASK) v = rr[nt<<4] + v*rm;
        else if constexpr (EPI==EPI_RES_GAMMA_MASK) v = (rr[nt<<4] + gm[nt]*v)*rm;
        yr[nt<<4] = v;
      }
    }
}

// ---------------- tiled windowed-rel attention (unchanged from r5) -----------
__global__ __launch_bounds__(256) void attn_tile_k(const float* __restrict__ Q,
    const float* __restrict__ Kb, const float* __restrict__ Vb,
    const float* __restrict__ relk, const float* __restrict__ relv,
    const float* __restrict__ mask, float* __restrict__ O){
  __shared__ float ms_[512];
  __shared__ float rk[9][64];
  __shared__ float rv[9][64];
  __shared__ float Qs[16][68];
  __shared__ float qrel[16][12];
  __shared__ float KV[64][68];
  __shared__ float Sc[16][520];

  int qt = blockIdx.x;
  int bh = blockIdx.y;
  int h = bh & 7, b_ = bh >> 3;
  int t = threadIdx.x;
  int l0 = qt * 16;
  const size_t rowoff = (size_t)b_ * 512;

  ms_[t]       = mask[rowoff + t];
  ms_[t + 256] = mask[rowoff + t + 256];
  for (int i = t; i < 576; i += 256){
    ((float*)rk)[i] = relk[i];
    ((float*)rv)[i] = relv[i];
  }
  {
    int r = t >> 4, c4 = (t & 15) << 2;
    *(float4*)&Qs[r][c4] =
        *(const float4*)&Q[((rowoff + l0 + r) << 9) + h*64 + c4];
  }
  __syncthreads();

  if (t < 144){
    int dlt = t >> 4, q_ = t & 15;
    float s = 0.f;
    for (int d = 0; d < 64; ++d) s += Qs[q_][d] * rk[dlt][d];
    qrel[q_][dlt] = s;
  }

  int q  = t >> 4;
  int kg = t & 15;
  int l  = l0 + q;

  float ml = 0.f;
  for (int tt = 0; tt < 8; ++tt){
    __syncthreads();
    if (tt == 0) ml = ms_[l];
    #pragma unroll
    for (int rep = 0; rep < 4; ++rep){
      int f4 = rep*256 + t;
      int r = f4 >> 4, c4 = (f4 & 15) << 2;
      *(float4*)&KV[r][c4] =
          *(const float4*)&Kb[((rowoff + tt*64 + r) << 9) + h*64 + c4];
    }
    __syncthreads();
    float s0=0.f, s1=0.f, s2=0.f, s3=0.f;
    #pragma unroll 4
    for (int d4 = 0; d4 < 16; ++d4){
      float4 qv = *(const float4*)&Qs[q][d4<<2];
      float4 k0 = *(const float4*)&KV[kg     ][d4<<2];
      float4 k1 = *(const float4*)&KV[kg + 16][d4<<2];
      float4 k2 = *(const float4*)&KV[kg + 32][d4<<2];
      float4 k3 = *(const float4*)&KV[kg + 48][d4<<2];
      s0 += qv.x*k0.x + qv.y*k0.y + qv.z*k0.z + qv.w*k0.w;
      s1 += qv.x*k1.x + qv.y*k1.y + qv.z*k1.z + qv.w*k1.w;
      s2 += qv.x*k2.x + qv.y*k2.y + qv.z*k2.z + qv.w*k2.w;
      s3 += qv.x*k3.x + qv.y*k3.y + qv.z*k3.z + qv.w*k3.w;
    }
    int mb = tt*64 + kg;
    { int m = mb;      int dlt = m - l + 4;
      if (dlt >= 0 && dlt <= 8) s0 += qrel[q][dlt];
      if (ml * ms_[m] == 0.f) s0 = -10000.f;  Sc[q][m] = s0; }
    { int m = mb + 16; int dlt = m - l + 4;
      if (dlt >= 0 && dlt <= 8) s1 += qrel[q][dlt];
      if (ml * ms_[m] == 0.f) s1 = -10000.f;  Sc[q][m] = s1; }
    { int m = mb + 32; int dlt = m - l + 4;
      if (dlt >= 0 && dlt <= 8) s2 += qrel[q][dlt];
      if (ml * ms_[m] == 0.f) s2 = -10000.f;  Sc[q][m] = s2; }
    { int m = mb + 48; int dlt = m - l + 4;
      if (dlt >= 0 && dlt <= 8) s3 += qrel[q][dlt];
      if (ml * ms_[m] == 0.f) s3 = -10000.f;  Sc[q][m] = s3; }
  }

  float mx = -3.4e38f;
  for (int jj = 0; jj < 32; ++jj) mx = fmaxf(mx, Sc[q][kg + 16*jj]);
  #pragma unroll
  for (int o = 8; o >= 1; o >>= 1) mx = fmaxf(mx, __shfl_xor(mx, o));
  float sum = 0.f;
  for (int jj = 0; jj < 32; ++jj){
    float e = expf(Sc[q][kg + 16*jj] - mx);
    sum += e;
    Sc[q][kg + 16*jj] = e;
  }
  #pragma unroll
  for (int o = 8; o >= 1; o >>= 1) sum += __shfl_xor(sum, o);
  float inv = 1.f / sum;

  int dg = kg;
  float4 acc; acc.x=0.f; acc.y=0.f; acc.z=0.f; acc.w=0.f;
  for (int tt = 0; tt < 8; ++tt){
    __syncthreads();
    #pragma unroll
    for (int rep = 0; rep < 4; ++rep){
      int f4 = rep*256 + t;
      int r = f4 >> 4, c4 = (f4 & 15) << 2;
      *(float4*)&KV[r][c4] =
          *(const float4*)&Vb[((rowoff + tt*64 + r) << 9) + h*64 + c4];
    }
    __syncthreads();
    int base = tt*64;
    #pragma unroll 4
    for (int mm = 0; mm < 64; mm += 4){
      float p0 = Sc[q][base+mm+0], p1 = Sc[q][base+mm+1];
      float p2 = Sc[q][base+mm+2], p3 = Sc[q][base+mm+3];
      float4 v0 = *(const float4*)&KV[mm+0][dg<<2];
      float4 v1 = *(const float4*)&KV[mm+1][dg<<2];
      float4 v2 = *(const float4*)&KV[mm+2][dg<<2];
      float4 v3 = *(const float4*)&KV[mm+3][dg<<2];
      acc.x += p0*v0.x + p1*v1.x + p2*v2.x + p3*v3.x;
      acc.y += p0*v0.y + p1*v1.y + p2*v2.y + p3*v3.y;
      acc.z += p0*v0.z + p1*v1.z + p2*v2.z + p3*v3.z;
      acc.w += p0*v0.w + p1*v1.w + p2*v2.w + p3*v3.w;
    }
  }
  #pragma unroll
  for (int dlt = 0; dlt < 9; ++dlt){
    int m = l + dlt - 4;
    if (m >= 0 && m < 512){
      float p = Sc[q][m];
      float4 r4 = *(const float4*)&rv[dlt][dg<<2];
      acc.x += p*r4.x; acc.y += p*r4.y; acc.z += p*r4.z; acc.w += p*r4.w;
    }
  }
  acc.x *= inv; acc.y *= inv; acc.z *= inv; acc.w *= inv;
  *(float4*)&O[((rowoff + l) << 9) + h*64 + (dg<<2)] = acc;
}

// ---------------- style attention ----------------
__global__ __launch_bounds__(128) void style_attn_k(const float* __restrict__ Q,
    const float* __restrict__ kk, const float* __restrict__ vv,
    const float* __restrict__ mask, float* __restrict__ O){
  int n = blockIdx.x;
  int h = threadIdx.x >> 6, lane = threadIdx.x & 63;
  __shared__ float qh[512];
  __shared__ float aw[2][64];
  {
    float4 v = ((const float4*)(Q + ((size_t)n<<9)))[threadIdx.x];
    *(float4*)&qh[threadIdx.x*4] = v;
  }
  __syncthreads();
  float sc;
  if (lane < 50){
    float s = 0.f;
    const float* kr = kk + lane*512 + h*256;
    const float* qr = qh + h*256;
    for (int d4 = 0; d4 < 64; ++d4){
      float4 kv = *(const float4*)&kr[d4*4];
      s += qr[d4*4]*kv.x + qr[d4*4+1]*kv.y + qr[d4*4+2]*kv.z + qr[d4*4+3]*kv.w;
    }
    sc = s * 0.044194173824159216f;
  } else sc = -1e30f;
  float mx = wave_max(sc);
  float ex = (lane < 50) ? expf(sc - mx) : 0.f;
  float sm = wave_sum(ex);
  float keep = (mask[n] == 0.f) ? 0.f : 1.f;
  aw[h][lane] = ex / sm * keep;
  __syncthreads();
  float4 acc; acc.x=0; acc.y=0; acc.z=0; acc.w=0;
  const float* vb = vv + h*256 + lane*4;
  for (int s = 0; s < 50; ++s){
    float a = aw[h][s];
    const float4 vvv = *(const float4*)&vb[(size_t)s*512];
    acc.x += a*vvv.x; acc.y += a*vvv.y; acc.z += a*vvv.z; acc.w += a*vvv.w;
  }
  *(float4*)&O[((size_t)n<<9) + h*256 + lane*4] = acc;
}

// ---------------- final transpose ----------------
__global__ __launch_bounds__(256) void transpose_out_k(const float* __restrict__ xn,
    const float* __restrict__ mask, float* __restrict__ out){
  __shared__ float tile[32][33];
  int b_ = blockIdx.z; int c0 = blockIdx.x*32; int l0 = blockIdx.y*32;
  int tx = threadIdx.x & 31, ty = threadIdx.x >> 5;
  #pragma unroll
  for (int r=0;r<4;r++){
    int l = l0 + ty + r*8;
    tile[ty + r*8][tx] = xn[(((size_t)(b_*512 + l))<<9) + c0 + tx];
  }
  __syncthreads();
  float mm = mask[b_*512 + l0 + tx];
  #pragma unroll
  for (int r=0;r<4;r++){
    int c = c0 + ty + r*8;
    out[(((size_t)(b_*512 + c))<<9) + l0 + tx] = tile[tx][ty + r*8] * mm;
  }
}

extern "C" void kernel_launch(void* const* d_in, const int* in_sizes, int n_in,
                              void* d_out, int out_size, void* d_ws, size_t ws_size,
                              hipStream_t stream) {
  const int*   tokens   = (const int*)  d_in[0];
  const float* style_v  = (const float*)d_in[1];
  const float* mask     = (const float*)d_in[2];
  const float* embed_w  = (const float*)d_in[3];
  const float* cw_dw_w  = (const float*)d_in[4];
  const float* cw_dw_b  = (const float*)d_in[5];
  const float* cw_ln_g  = (const float*)d_in[6];
  const float* cw_ln_b  = (const float*)d_in[7];
  const float* cw_pw1_w = (const float*)d_in[8];
  const float* cw_pw1_b = (const float*)d_in[9];
  const float* cw_pw2_w = (const float*)d_in[10];
  const float* cw_pw2_b = (const float*)d_in[11];
  const float* cw_gamma = (const float*)d_in[12];
  const float* aq_w = (const float*)d_in[13];
  const float* aq_b = (const float*)d_in[14];
  const float* ak_w = (const float*)d_in[15];
  const float* ak_b = (const float*)d_in[16];
  const float* av_w = (const float*)d_in[17];
  const float* av_b = (const float*)d_in[18];
  const float* ao_w = (const float*)d_in[19];
  const float* ao_b = (const float*)d_in[20];
  const float* rel_k = (const float*)d_in[21];
  const float* rel_v = (const float*)d_in[22];
  const float* ln1_g = (const float*)d_in[23];
  const float* ln1_b = (const float*)d_in[24];
  const float* ln2_g = (const float*)d_in[25];
  const float* ln2_b = (const float*)d_in[26];
  const float* ffn_w1 = (const float*)d_in[27];
  const float* ffn_b1 = (const float*)d_in[28];
  const float* ffn_w2 = (const float*)d_in[29];
  const float* ffn_b2 = (const float*)d_in[30];
  const float* style_key = (const float*)d_in[31];
  const float* sq_w = (const float*)d_in[32];
  const float* sq_b = (const float*)d_in[33];
  const float* sk_w = (const float*)d_in[34];
  const float* sk_b = (const float*)d_in[35];
  const float* sv_w = (const float*)d_in[36];
  const float* sv_b = (const float*)d_in[37];
  const float* so_w = (const float*)d_in[38];
  const float* so_b = (const float*)d_in[39];
  const float* sn_g = (const float*)d_in[40];
  const float* sn_b = (const float*)d_in[41];

  const int N = NROWS;
  float* ws = (float*)d_ws;
  float* X  = ws;
  float* T  = X  + (size_t)N*512;
  float* Qb = T  + (size_t)N*512;
  float* Kb = Qb + (size_t)N*512;
  float* Vb = Kb + (size_t)N*512;
  float* Hb = Vb + (size_t)N*512;
  float* KK = Hb + (size_t)N*2048;
  float* VV = KK + 2*50*512;

  dim3 gm512(4, 64), gm2048(16, 64), gS(8, 1);

  embed_k<<<4096,128,0,stream>>>(tokens, embed_w, X);

  // ---- ConvNeXt blocks ----
  for (int i=0;i<4;i++){
    maskmul_k<<<2048,256,0,stream>>>(X, mask);
    dwconv_k<<<4096,128,0,stream>>>(X, cw_dw_w + (size_t)i*512*5, cw_dw_b + i*512, mask, T);
    ln_rows<<<1024,256,0,stream>>>(T, cw_ln_g+i*512, cw_ln_b+i*512, T, N);
    gemm_mfma<EPI_GELU,false><<<gm2048,256,0,stream>>>(T, cw_pw1_w + (size_t)i*2048*512,
        cw_pw1_b+i*2048, nullptr, nullptr, nullptr, Hb, 512, 2048, 0.f);
    gemm_mfma<EPI_RES_GAMMA_MASK,false><<<gm512,256,0,stream>>>(Hb, cw_pw2_w + (size_t)i*512*2048,
        cw_pw2_b+i*512, X, cw_gamma+i*512, mask, X, 2048, 512, 0.f);
  }
  maskmul_k<<<2048,256,0,stream>>>(X, mask);

  // ---- Attention layers ----
  for (int i=0;i<6;i++){
    size_t wo = (size_t)i*512*512;
    gemm_mfma<EPI_SCALE,false><<<gm512,256,0,stream>>>(X, aq_w+wo, aq_b+i*512,
        nullptr,nullptr,nullptr, Qb, 512,512, 0.125f);
    gemm_mfma<EPI_BIAS,false><<<gm512,256,0,stream>>>(X, ak_w+wo, ak_b+i*512,
        nullptr,nullptr,nullptr, Kb, 512,512, 0.f);
    gemm_mfma<EPI_BIAS,false><<<gm512,256,0,stream>>>(X, av_w+wo, av_b+i*512,
        nullptr,nullptr,nullptr, Vb, 512,512, 0.f);
    attn_tile_k<<<dim3(32,64),256,0,stream>>>(Qb, Kb, Vb, rel_k + (size_t)i*9*64,
        rel_v + (size_t)i*9*64, mask, T);
    gemm_mfma<EPI_RES,false><<<gm512,256,0,stream>>>(T, ao_w+wo, ao_b+i*512,
        X, nullptr, nullptr, Qb, 512,512, 0.f);
    ln_rows<<<1024,256,0,stream>>>(Qb, ln1_g+i*512, ln1_b+i*512, X, N);
    gemm_mfma<EPI_RELU_MASK,true><<<gm2048,256,0,stream>>>(X, ffn_w1 + (size_t)i*2048*512,
        ffn_b1+i*2048, nullptr, nullptr, mask, Hb, 512,2048, 0.f);
    gemm_mfma<EPI_RES_MASK,false><<<gm512,256,0,stream>>>(Hb, ffn_w2 + (size_t)i*512*2048,
        ffn_b2+i*512, X, nullptr, mask, Qb, 2048,512, 0.f);
    ln_rows<<<1024,256,0,stream>>>(Qb, ln2_g+i*512, ln2_b+i*512, X, N);
  }
  maskmul_k<<<2048,256,0,stream>>>(X, mask);

  // ---- Style attention ----
  gemm_nt<EPI_TANH,false><<<gS,256,0,stream>>>(style_key, sk_w, sk_b,
      nullptr,nullptr,nullptr, KK, 50,512,512, 0.f);
  gemm_nt<EPI_TANH,false><<<gS,256,0,stream>>>(style_key, sk_w+262144, sk_b+512,
      nullptr,nullptr,nullptr, KK+25600, 50,512,512, 0.f);
  gemm_nt<EPI_BIAS,false><<<gS,256,0,stream>>>(style_v, sv_w, sv_b,
      nullptr,nullptr,nullptr, VV, 50,512,512, 0.f);
  gemm_nt<EPI_BIAS,false><<<gS,256,0,stream>>>(style_v, sv_w+262144, sv_b+512,
      nullptr,nullptr,nullptr, VV+25600, 50,512,512, 0.f);

  // layer 0: xin = X (xt)
  gemm_mfma<EPI_BIAS,false><<<gm512,256,0,stream>>>(X, sq_w, sq_b,
      nullptr,nullptr,nullptr, Qb, 512,512, 0.f);
  style_attn_k<<<4096,128,0,stream>>>(Qb, KK, VV, mask, T);
  gemm_mfma<EPI_RES_MASK,false><<<gm512,256,0,stream>>>(T, so_w, so_b,
      X, nullptr, mask, Kb, 512,512, 0.f);            // x1 = xt + o*mask
  // layer 1: xin = x1 (Kb); residual still xt (X)
  gemm_mfma<EPI_BIAS,false><<<gm512,256,0,stream>>>(Kb, sq_w+262144, sq_b+512,
      nullptr,nullptr,nullptr, Qb, 512,512, 0.f);
  style_attn_k<<<4096,128,0,stream>>>(Qb, KK+25600, VV+25600, mask, T);
  gemm_mfma<EPI_RES_MASK,false><<<gm512,256,0,stream>>>(T, so_w+262144, so_b+512,
      X, nullptr, mask, Vb, 512,512, 0.f);            // x2 = xt + o*mask

  ln_rows<<<1024,256,0,stream>>>(Vb, sn_g, sn_b, Qb, N);
  transpose_out_k<<<dim3(16,16,8),256,0,stream>>>(Qb, mask, (float*)d_out);
}

// Round 7
// 2727.267 us; speedup vs baseline: 7.1786x; 1.1296x over previous
//
#include <hip/hip_runtime.h>
#include <cstdint>

#define Bb 8
#define Ll 512
#define Cc 512
#define Hh 8
#define HD 64
#define Ff 2048
#define Ss 50
#define NROWS 4096   // B*L
#define QKVS 1536

typedef __attribute__((ext_vector_type(8))) short short8v;  // 8 bf16 (4 VGPR)
typedef __attribute__((ext_vector_type(4))) float f32x4;

__device__ __forceinline__ float wave_sum(float v){
  #pragma unroll
  for (int o=32;o>=1;o>>=1) v += __shfl_xor(v,o);
  return v;
}
__device__ __forceinline__ float wave_max(float v){
  #pragma unroll
  for (int o=32;o>=1;o>>=1) v = fmaxf(v,__shfl_xor(v,o));
  return v;
}

// split fp32 -> bf16 hi + bf16 lo (RNE both);  a ~= hi + lo
__device__ __forceinline__ void splitf(float a, unsigned short& hi, unsigned short& lo){
  unsigned u = __float_as_uint(a);
  unsigned r = u + 0x7FFFu + ((u>>16)&1u);
  hi = (unsigned short)(r >> 16);
  float hif = __uint_as_float(((unsigned)hi) << 16);
  float l = a - hif;
  unsigned ul = __float_as_uint(l);
  unsigned rl = ul + 0x7FFFu + ((ul>>16)&1u);
  lo = (unsigned short)(rl >> 16);
}
__device__ __forceinline__ void split4(float4 v, unsigned short* hi, unsigned short* lo){
  unsigned short h0,h1,h2,h3,l0,l1,l2,l3;
  splitf(v.x,h0,l0); splitf(v.y,h1,l1); splitf(v.z,h2,l2); splitf(v.w,h3,l3);
  *(ushort4*)hi = make_ushort4(h0,h1,h2,h3);
  *(ushort4*)lo = make_ushort4(l0,l1,l2,l3);
}

// ---------------- weight split (flat) ----------------
__global__ __launch_bounds__(256) void split_k(const float* __restrict__ src,
    unsigned short* __restrict__ hi, unsigned short* __restrict__ lo, int n4){
  for (int i = blockIdx.x*256 + threadIdx.x; i < n4; i += gridDim.x*256){
    float4 v = ((const float4*)src)[i];
    split4(v, (unsigned short*)((ushort4*)hi + i), (unsigned short*)((ushort4*)lo + i));
  }
}

// qkv interleave split: dst planes laid out [6 layers][1536 rows][512]
__global__ __launch_bounds__(256) void split_qkv_k(const float* __restrict__ q,
    const float* __restrict__ k, const float* __restrict__ v,
    unsigned short* __restrict__ hi, unsigned short* __restrict__ lo){
  const int n4 = 6*QKVS*512/4;
  for (int i = blockIdx.x*256 + threadIdx.x; i < n4; i += gridDim.x*256){
    int e = i << 2;
    int layer = e / 786432;           // 1536*512
    int r = e - layer*786432;
    int which = r >> 18;              // /262144
    int off = r & 262143;
    const float* s = (which==0) ? q : (which==1) ? k : v;
    float4 vv = *(const float4*)(s + (size_t)layer*262144 + off);
    split4(vv, (unsigned short*)((ushort4*)hi + i), (unsigned short*)((ushort4*)lo + i));
  }
}

// ---------------- embed gather ----------------
__global__ __launch_bounds__(128) void embed_k(const int* __restrict__ tok,
    const float* __restrict__ emb, float* __restrict__ x){
  int n = blockIdx.x;
  int t = tok[n];
  ((float4*)(x + ((size_t)n<<9)))[threadIdx.x] =
      ((const float4*)(emb + ((size_t)t<<9)))[threadIdx.x];
}

// ---------------- x *= mask[row] ----------------
__global__ __launch_bounds__(256) void maskmul_k(float* __restrict__ x,
    const float* __restrict__ mask){
  int i = blockIdx.x*256 + threadIdx.x;
  float m = mask[i >> 7];
  float4 v = ((float4*)x)[i];
  v.x*=m; v.y*=m; v.z*=m; v.w*=m;
  ((float4*)x)[i]=v;
}
// masked + dual split write
__global__ __launch_bounds__(256) void maskmul_split_k(float* __restrict__ x,
    const float* __restrict__ mask, unsigned short* __restrict__ xh,
    unsigned short* __restrict__ xl){
  int i = blockIdx.x*256 + threadIdx.x;
  float m = mask[i >> 7];
  float4 v = ((float4*)x)[i];
  v.x*=m; v.y*=m; v.z*=m; v.w*=m;
  ((float4*)x)[i]=v;
  split4(v, (unsigned short*)((ushort4*)xh + i), (unsigned short*)((ushort4*)xl + i));
}

// ---------------- depthwise conv K=5, edge pad, +bias, *mask --------
__global__ __launch_bounds__(128) void dwconv_k(const float* __restrict__ x,
    const float* __restrict__ w, const float* __restrict__ bias,
    const float* __restrict__ mask, float* __restrict__ h){
  int n = blockIdx.x; int b_ = n >> 9, l = n & 511;
  int c0 = threadIdx.x * 4;
  float acc0=bias[c0], acc1=bias[c0+1], acc2=bias[c0+2], acc3=bias[c0+3];
  #pragma unroll
  for (int k=0;k<5;k++){
    int ls = l + k - 2; ls = ls < 0 ? 0 : (ls > 511 ? 511 : ls);
    const float4 xv = *(const float4*)&x[((size_t)(b_*512 + ls) << 9) + c0];
    acc0 += w[(c0+0)*5+k]*xv.x;
    acc1 += w[(c0+1)*5+k]*xv.y;
    acc2 += w[(c0+2)*5+k]*xv.z;
    acc3 += w[(c0+3)*5+k]*xv.w;
  }
  float mm = mask[n];
  float4 o; o.x=acc0*mm; o.y=acc1*mm; o.z=acc2*mm; o.w=acc3*mm;
  *(float4*)&h[((size_t)n << 9) + c0] = o;
}

// ---------------- rowwise LayerNorm over C=512 (optional dual split write) ----
template<bool SPLIT>
__global__ __launch_bounds__(256) void ln_rows(const float* __restrict__ x,
    const float* __restrict__ g, const float* __restrict__ bt,
    float* __restrict__ y, unsigned short* __restrict__ yh,
    unsigned short* __restrict__ yl, int nrows){
  int wid = threadIdx.x >> 6, lane = threadIdx.x & 63;
  int row = blockIdx.x*4 + wid;
  if (row >= nrows) return;
  const float4* xr = (const float4*)(x + ((size_t)row<<9));
  float4 a = xr[lane*2], b = xr[lane*2+1];
  float s = a.x+a.y+a.z+a.w+b.x+b.y+b.z+b.w;
  s = wave_sum(s);
  float m = s * (1.f/512.f);
  float d0=a.x-m,d1=a.y-m,d2=a.z-m,d3=a.w-m,d4=b.x-m,d5=b.y-m,d6=b.z-m,d7=b.w-m;
  float sq = d0*d0+d1*d1+d2*d2+d3*d3+d4*d4+d5*d5+d6*d6+d7*d7;
  sq = wave_sum(sq);
  float var = sq * (1.f/512.f);
  float inv = 1.f/sqrtf(var + 1e-6f);
  const float4* gr = (const float4*)g; const float4* br = (const float4*)bt;
  float4 g0=gr[lane*2], g1=gr[lane*2+1], b0=br[lane*2], b1=br[lane*2+1];
  float4 o0, o1;
  o0.x=d0*inv*g0.x+b0.x; o0.y=d1*inv*g0.y+b0.y; o0.z=d2*inv*g0.z+b0.z; o0.w=d3*inv*g0.w+b0.w;
  o1.x=d4*inv*g1.x+b1.x; o1.y=d5*inv*g1.y+b1.y; o1.z=d6*inv*g1.z+b1.z; o1.w=d7*inv*g1.w+b1.w;
  float4* yr = (float4*)(y + ((size_t)row<<9));
  yr[lane*2]=o0; yr[lane*2+1]=o1;
  if constexpr (SPLIT){
    size_t base = ((size_t)row<<9) + lane*8;
    split4(o0, yh+base,   yl+base);
    split4(o1, yh+base+4, yl+base+4);
  }
}

#define EPI_BIAS 0
#define EPI_SCALE 1
#define EPI_GELU 2
#define EPI_RES 3
#define EPI_RELU_MASK 4
#define EPI_RES_MASK 5
#define EPI_RES_GAMMA_MASK 6
#define EPI_TANH 7
#define EPI_QKV 8

// ---------------- fp32 VALU GEMM (style sk/sv only, 50 rows) ----------------
template<int EPI>
__global__ __launch_bounds__(256) void gemm_nt(
    const float* __restrict__ A, const float* __restrict__ W,
    const float* __restrict__ bias,
    float* __restrict__ Y, int N, int K, int O)
{
  __shared__ float As[16][68];
  __shared__ float Bs[16][68];
  int t = threadIdx.x;
  int tx = t & 15, ty = t >> 4;
  int row0 = blockIdx.y << 6, col0 = blockIdx.x << 6;
  int lr = t >> 2, lk = (t & 3) << 2;
  float acc[4][4] = {};
  int ar = row0 + lr;
  bool arok = ar < N;
  const float* Ap = A + (size_t)(arok ? ar : 0) * K + lk;
  const float* Wp = W + (size_t)(col0 + lr) * K + lk;
  for (int k0 = 0; k0 < K; k0 += 16) {
    float4 av;
    if (arok) av = *(const float4*)(Ap + k0);
    else { av.x=0;av.y=0;av.z=0;av.w=0; }
    float4 bv = *(const float4*)(Wp + k0);
    As[lk+0][lr]=av.x; As[lk+1][lr]=av.y; As[lk+2][lr]=av.z; As[lk+3][lr]=av.w;
    Bs[lk+0][lr]=bv.x; Bs[lk+1][lr]=bv.y; Bs[lk+2][lr]=bv.z; Bs[lk+3][lr]=bv.w;
    __syncthreads();
    #pragma unroll
    for (int k=0;k<16;k++){
      float4 af = *(const float4*)&As[k][ty<<2];
      float4 bf = *(const float4*)&Bs[k][tx<<2];
      float a4[4]={af.x,af.y,af.z,af.w};
      float b4[4]={bf.x,bf.y,bf.z,bf.w};
      #pragma unroll
      for (int i=0;i<4;i++)
        #pragma unroll
        for (int j=0;j<4;j++)
          acc[i][j] += a4[i]*b4[j];
    }
    __syncthreads();
  }
  #pragma unroll
  for (int i=0;i<4;i++){
    int row = row0 + (ty<<2) + i;
    if (row >= N) break;
    int colb = col0 + (tx<<2);
    float vv_[4];
    #pragma unroll
    for (int j=0;j<4;j++){
      float v = acc[i][j] + bias[colb+j];
      if constexpr (EPI==EPI_TANH) v = tanhf(v);
      vv_[j]=v;
    }
    float4 ov; ov.x=vv_[0]; ov.y=vv_[1]; ov.z=vv_[2]; ov.w=vv_[3];
    *(float4*)(Y + (size_t)row*O + colb) = ov;
  }
}

// ---------------- pre-split MFMA GEMM ----------------
// A planes (Ah,Al) [N][K] bf16, W planes [O][K] bf16. Tile 64x128x32, 4 waves.
// acc += ah*bh + ah*bl + al*bh. OUT: 0 = fp32 Y, 1 = planes Yh/Yl.
// EPI_QKV: bias tables q/k/v passed via bias/res/gamma; scale on cols<512.
template<int EPI, bool AMASK, int OUT>
__global__ __launch_bounds__(256) void gemm_ps(
    const unsigned short* __restrict__ Ah, const unsigned short* __restrict__ Al,
    const unsigned short* __restrict__ Wh, const unsigned short* __restrict__ Wl,
    const float* __restrict__ bias, const float* __restrict__ res,
    const float* __restrict__ gamma, const float* __restrict__ rowmask,
    float* __restrict__ Y, unsigned short* __restrict__ Yh,
    unsigned short* __restrict__ Yl, int K, int O, float scale)
{
  __shared__ unsigned short AhS[64][40], AlS[64][40];
  __shared__ unsigned short BhS[128][40], BlS[128][40];
  int t = threadIdx.x;
  int row0 = blockIdx.y << 6, col0 = blockIdx.x << 7;
  int lane = t & 63, wid = t >> 6;
  int wr = wid >> 1, wc = wid & 1;

  int sr = t >> 2, sc = (t & 3) << 3;   // 64 rows x 32 cols per plane
  const unsigned short* Ahg = Ah + (size_t)(row0 + sr)*K + sc;
  const unsigned short* Alg = Al + (size_t)(row0 + sr)*K + sc;
  const unsigned short* Bhg = Wh + (size_t)(col0 + sr)*K + sc;
  const unsigned short* Blg = Wl + (size_t)(col0 + sr)*K + sc;
  float am = 1.f;
  if (AMASK) am = rowmask[row0 + sr];

  f32x4 acc[2][4] = {};
  int nsteps = K >> 5;
  short8v ah_ = *(const short8v*)(Ahg);
  short8v al_ = *(const short8v*)(Alg);
  short8v bh0_ = *(const short8v*)(Bhg);
  short8v bl0_ = *(const short8v*)(Blg);
  short8v bh1_ = *(const short8v*)(Bhg + (size_t)64*K);
  short8v bl1_ = *(const short8v*)(Blg + (size_t)64*K);

  for (int s = 0; s < nsteps; ++s){
    if (AMASK && am == 0.f){ ah_ ^= ah_; al_ ^= al_; }
    __syncthreads();
    *(short8v*)&AhS[sr][sc] = ah_;
    *(short8v*)&AlS[sr][sc] = al_;
    *(short8v*)&BhS[sr][sc] = bh0_;
    *(short8v*)&BlS[sr][sc] = bl0_;
    *(short8v*)&BhS[sr+64][sc] = bh1_;
    *(short8v*)&BlS[sr+64][sc] = bl1_;
    __syncthreads();
    if (s+1 < nsteps){
      int ko = (s+1) << 5;
      ah_ = *(const short8v*)(Ahg + ko);
      al_ = *(const short8v*)(Alg + ko);
      bh0_ = *(const short8v*)(Bhg + ko);
      bl0_ = *(const short8v*)(Blg + ko);
      bh1_ = *(const short8v*)(Bhg + (size_t)64*K + ko);
      bl1_ = *(const short8v*)(Blg + (size_t)64*K + ko);
    }
    int fr = lane & 15, fc = (lane >> 4) << 3;
    short8v ahf[2], alf[2], bhf[4], blf[4];
    #pragma unroll
    for (int mt=0; mt<2; ++mt){
      int r = (wr<<5) + (mt<<4) + fr;
      ahf[mt] = *(const short8v*)&AhS[r][fc];
      alf[mt] = *(const short8v*)&AlS[r][fc];
    }
    #pragma unroll
    for (int nt=0; nt<4; ++nt){
      int r = (wc<<6) + (nt<<4) + fr;
      bhf[nt] = *(const short8v*)&BhS[r][fc];
      blf[nt] = *(const short8v*)&BlS[r][fc];
    }
    #pragma unroll
    for (int mt=0; mt<2; ++mt)
      #pragma unroll
      for (int nt=0; nt<4; ++nt){
        f32x4 c = acc[mt][nt];
        c = __builtin_amdgcn_mfma_f32_16x16x32_bf16(ahf[mt], bhf[nt], c, 0,0,0);
        c = __builtin_amdgcn_mfma_f32_16x16x32_bf16(ahf[mt], blf[nt], c, 0,0,0);
        c = __builtin_amdgcn_mfma_f32_16x16x32_bf16(alf[mt], bhf[nt], c, 0,0,0);
        acc[mt][nt] = c;
      }
  }

  // epilogue: C/D col=lane&15, row=(lane>>4)*4+j
  int rb = row0 + (wr<<5) + ((lane>>4)<<2);
  int cb = col0 + (wc<<6) + (lane & 15);
  float bs[4], gm[4];
  #pragma unroll
  for (int nt=0; nt<4; ++nt){
    int col = cb + (nt<<4);
    if constexpr (EPI==EPI_QKV){
      int which = blockIdx.x >> 2;
      const float* bp = (which==0) ? bias : (which==1) ? res : gamma;
      bs[nt] = bp[col & 511];
    } else {
      bs[nt] = bias[col];
      if constexpr (EPI==EPI_RES_GAMMA_MASK) gm[nt] = gamma[col];
    }
  }
  float qscale = 1.f;
  if constexpr (EPI==EPI_QKV) qscale = ((blockIdx.x>>2)==0) ? scale : 1.f;
  #pragma unroll
  for (int mt=0; mt<2; ++mt)
    #pragma unroll
    for (int j=0; j<4; ++j){
      int row = rb + (mt<<4) + j;
      float rm = 1.f;
      if constexpr (EPI==EPI_RELU_MASK || EPI==EPI_RES_MASK || EPI==EPI_RES_GAMMA_MASK)
        rm = rowmask[row];
      const float* rr = nullptr;
      if constexpr (EPI==EPI_RES || EPI==EPI_RES_MASK || EPI==EPI_RES_GAMMA_MASK)
        rr = res + (size_t)row*O + cb;
      #pragma unroll
      for (int nt=0; nt<4; ++nt){
        float v = acc[mt][nt][j] + bs[nt];
        if constexpr (EPI==EPI_SCALE) v *= scale;
        else if constexpr (EPI==EPI_QKV) v *= qscale;
        else if constexpr (EPI==EPI_GELU) v = 0.5f*v*(1.f+erff(v*0.7071067811865475f));
        else if constexpr (EPI==EPI_RES) v = rr[nt<<4] + v;
        else if constexpr (EPI==EPI_RELU_MASK) v = fmaxf(v,0.f)*rm;
        else if constexpr (EPI==EPI_RES_MASK) v = rr[nt<<4] + v*rm;
        else if constexpr (EPI==EPI_RES_GAMMA_MASK) v = (rr[nt<<4] + gm[nt]*v)*rm;
        size_t oidx = (size_t)row*O + cb + (nt<<4);
        if constexpr (OUT==0) Y[oidx] = v;
        else { unsigned short h,l; splitf(v,h,l); Yh[oidx]=h; Yl[oidx]=l; }
      }
    }
}

// ---------------- tiled windowed-rel attention (QKV packed input, split out) --
__global__ __launch_bounds__(256) void attn_tile_k(const float* __restrict__ QKV,
    const float* __restrict__ relk, const float* __restrict__ relv,
    const float* __restrict__ mask, unsigned short* __restrict__ Oh,
    unsigned short* __restrict__ Ol){
  __shared__ float ms_[512];
  __shared__ float rk[9][64];
  __shared__ float rv[9][64];
  __shared__ float Qs[16][68];
  __shared__ float qrel[16][12];
  __shared__ float KV[64][68];
  __shared__ float Sc[16][520];

  int qt = blockIdx.x;
  int bh = blockIdx.y;
  int h = bh & 7, b_ = bh >> 3;
  int t = threadIdx.x;
  int l0 = qt * 16;
  const size_t rowoff = (size_t)b_ * 512;

  ms_[t]       = mask[rowoff + t];
  ms_[t + 256] = mask[rowoff + t + 256];
  for (int i = t; i < 576; i += 256){
    ((float*)rk)[i] = relk[i];
    ((float*)rv)[i] = relv[i];
  }
  {
    int r = t >> 4, c4 = (t & 15) << 2;
    *(float4*)&Qs[r][c4] =
        *(const float4*)&QKV[(rowoff + l0 + r)*QKVS + h*64 + c4];
  }
  __syncthreads();

  if (t < 144){
    int dlt = t >> 4, q_ = t & 15;
    float s = 0.f;
    for (int d = 0; d < 64; ++d) s += Qs[q_][d] * rk[dlt][d];
    qrel[q_][dlt] = s;
  }

  int q  = t >> 4;
  int kg = t & 15;
  int l  = l0 + q;

  float ml = 0.f;
  for (int tt = 0; tt < 8; ++tt){
    __syncthreads();
    if (tt == 0) ml = ms_[l];
    #pragma unroll
    for (int rep = 0; rep < 4; ++rep){
      int f4 = rep*256 + t;
      int r = f4 >> 4, c4 = (f4 & 15) << 2;
      *(float4*)&KV[r][c4] =
          *(const float4*)&QKV[(rowoff + tt*64 + r)*QKVS + 512 + h*64 + c4];
    }
    __syncthreads();
    float s0=0.f, s1=0.f, s2=0.f, s3=0.f;
    #pragma unroll 4
    for (int d4 = 0; d4 < 16; ++d4){
      float4 qv = *(const float4*)&Qs[q][d4<<2];
      float4 k0 = *(const float4*)&KV[kg     ][d4<<2];
      float4 k1 = *(const float4*)&KV[kg + 16][d4<<2];
      float4 k2 = *(const float4*)&KV[kg + 32][d4<<2];
      float4 k3 = *(const float4*)&KV[kg + 48][d4<<2];
      s0 += qv.x*k0.x + qv.y*k0.y + qv.z*k0.z + qv.w*k0.w;
      s1 += qv.x*k1.x + qv.y*k1.y + qv.z*k1.z + qv.w*k1.w;
      s2 += qv.x*k2.x + qv.y*k2.y + qv.z*k2.z + qv.w*k2.w;
      s3 += qv.x*k3.x + qv.y*k3.y + qv.z*k3.z + qv.w*k3.w;
    }
    int mb = tt*64 + kg;
    { int m = mb;      int dlt = m - l + 4;
      if (dlt >= 0 && dlt <= 8) s0 += qrel[q][dlt];
      if (ml * ms_[m] == 0.f) s0 = -10000.f;  Sc[q][m] = s0; }
    { int m = mb + 16; int dlt = m - l + 4;
      if (dlt >= 0 && dlt <= 8) s1 += qrel[q][dlt];
      if (ml * ms_[m] == 0.f) s1 = -10000.f;  Sc[q][m] = s1; }
    { int m = mb + 32; int dlt = m - l + 4;
      if (dlt >= 0 && dlt <= 8) s2 += qrel[q][dlt];
      if (ml * ms_[m] == 0.f) s2 = -10000.f;  Sc[q][m] = s2; }
    { int m = mb + 48; int dlt = m - l + 4;
      if (dlt >= 0 && dlt <= 8) s3 += qrel[q][dlt];
      if (ml * ms_[m] == 0.f) s3 = -10000.f;  Sc[q][m] = s3; }
  }

  float mx = -3.4e38f;
  for (int jj = 0; jj < 32; ++jj) mx = fmaxf(mx, Sc[q][kg + 16*jj]);
  #pragma unroll
  for (int o = 8; o >= 1; o >>= 1) mx = fmaxf(mx, __shfl_xor(mx, o));
  float sum = 0.f;
  for (int jj = 0; jj < 32; ++jj){
    float e = expf(Sc[q][kg + 16*jj] - mx);
    sum += e;
    Sc[q][kg + 16*jj] = e;
  }
  #pragma unroll
  for (int o = 8; o >= 1; o >>= 1) sum += __shfl_xor(sum, o);
  float inv = 1.f / sum;

  int dg = kg;
  float4 acc; acc.x=0.f; acc.y=0.f; acc.z=0.f; acc.w=0.f;
  for (int tt = 0; tt < 8; ++tt){
    __syncthreads();
    #pragma unroll
    for (int rep = 0; rep < 4; ++rep){
      int f4 = rep*256 + t;
      int r = f4 >> 4, c4 = (f4 & 15) << 2;
      *(float4*)&KV[r][c4] =
          *(const float4*)&QKV[(rowoff + tt*64 + r)*QKVS + 1024 + h*64 + c4];
    }
    __syncthreads();
    int base = tt*64;
    #pragma unroll 4
    for (int mm = 0; mm < 64; mm += 4){
      float p0 = Sc[q][base+mm+0], p1 = Sc[q][base+mm+1];
      float p2 = Sc[q][base+mm+2], p3 = Sc[q][base+mm+3];
      float4 v0 = *(const float4*)&KV[mm+0][dg<<2];
      float4 v1 = *(const float4*)&KV[mm+1][dg<<2];
      float4 v2 = *(const float4*)&KV[mm+2][dg<<2];
      float4 v3 = *(const float4*)&KV[mm+3][dg<<2];
      acc.x += p0*v0.x + p1*v1.x + p2*v2.x + p3*v3.x;
      acc.y += p0*v0.y + p1*v1.y + p2*v2.y + p3*v3.y;
      acc.z += p0*v0.z + p1*v1.z + p2*v2.z + p3*v3.z;
      acc.w += p0*v0.w + p1*v1.w + p2*v2.w + p3*v3.w;
    }
  }
  #pragma unroll
  for (int dlt = 0; dlt < 9; ++dlt){
    int m = l + dlt - 4;
    if (m >= 0 && m < 512){
      float p = Sc[q][m];
      float4 r4 = *(const float4*)&rv[dlt][dg<<2];
      acc.x += p*r4.x; acc.y += p*r4.y; acc.z += p*r4.z; acc.w += p*r4.w;
    }
  }
  acc.x *= inv; acc.y *= inv; acc.z *= inv; acc.w *= inv;
  size_t oidx = ((rowoff + l) << 9) + h*64 + (dg<<2);
  split4(acc, Oh+oidx, Ol+oidx);
}

// ---------------- style attention (split out) ----------------
__global__ __launch_bounds__(128) void style_attn_k(const float* __restrict__ Q,
    const float* __restrict__ kk, const float* __restrict__ vv,
    const float* __restrict__ mask, unsigned short* __restrict__ Oh,
    unsigned short* __restrict__ Ol){
  int n = blockIdx.x;
  int h = threadIdx.x >> 6, lane = threadIdx.x & 63;
  __shared__ float qh[512];
  __shared__ float aw[2][64];
  {
    float4 v = ((const float4*)(Q + ((size_t)n<<9)))[threadIdx.x];
    *(float4*)&qh[threadIdx.x*4] = v;
  }
  __syncthreads();
  float sc;
  if (lane < 50){
    float s = 0.f;
    const float* kr = kk + lane*512 + h*256;
    const float* qr = qh + h*256;
    for (int d4 = 0; d4 < 64; ++d4){
      float4 kv = *(const float4*)&kr[d4*4];
      s += qr[d4*4]*kv.x + qr[d4*4+1]*kv.y + qr[d4*4+2]*kv.z + qr[d4*4+3]*kv.w;
    }
    sc = s * 0.044194173824159216f;
  } else sc = -1e30f;
  float mx = wave_max(sc);
  float ex = (lane < 50) ? expf(sc - mx) : 0.f;
  float sm = wave_sum(ex);
  float keep = (mask[n] == 0.f) ? 0.f : 1.f;
  aw[h][lane] = ex / sm * keep;
  __syncthreads();
  float4 acc; acc.x=0; acc.y=0; acc.z=0; acc.w=0;
  const float* vb = vv + h*256 + lane*4;
  for (int s = 0; s < 50; ++s){
    float a = aw[h][s];
    const float4 vvv = *(const float4*)&vb[(size_t)s*512];
    acc.x += a*vvv.x; acc.y += a*vvv.y; acc.z += a*vvv.z; acc.w += a*vvv.w;
  }
  size_t oidx = ((size_t)n<<9) + h*256 + lane*4;
  split4(acc, Oh+oidx, Ol+oidx);
}

// ---------------- final transpose ----------------
__global__ __launch_bounds__(256) void transpose_out_k(const float* __restrict__ xn,
    const float* __restrict__ mask, float* __restrict__ out){
  __shared__ float tile[32][33];
  int b_ = blockIdx.z; int c0 = blockIdx.x*32; int l0 = blockIdx.y*32;
  int tx = threadIdx.x & 31, ty = threadIdx.x >> 5;
  #pragma unroll
  for (int r=0;r<4;r++){
    int l = l0 + ty + r*8;
    tile[ty + r*8][tx] = xn[(((size_t)(b_*512 + l))<<9) + c0 + tx];
  }
  __syncthreads();
  float mm = mask[b_*512 + l0 + tx];
  #pragma unroll
  for (int r=0;r<4;r++){
    int c = c0 + ty + r*8;
    out[(((size_t)(b_*512 + c))<<9) + l0 + tx] = tile[tx][ty + r*8] * mm;
  }
}

extern "C" void kernel_launch(void* const* d_in, const int* in_sizes, int n_in,
                              void* d_out, int out_size, void* d_ws, size_t ws_size,
                              hipStream_t stream) {
  const int*   tokens   = (const int*)  d_in[0];
  const float* style_v  = (const float*)d_in[1];
  const float* mask     = (const float*)d_in[2];
  const float* embed_w  = (const float*)d_in[3];
  const float* cw_dw_w  = (const float*)d_in[4];
  const float* cw_dw_b  = (const float*)d_in[5];
  const float* cw_ln_g  = (const float*)d_in[6];
  const float* cw_ln_b  = (const float*)d_in[7];
  const float* cw_pw1_w = (const float*)d_in[8];
  const float* cw_pw1_b = (const float*)d_in[9];
  const float* cw_pw2_w = (const float*)d_in[10];
  const float* cw_pw2_b = (const float*)d_in[11];
  const float* cw_gamma = (const float*)d_in[12];
  const float* aq_w = (const float*)d_in[13];
  const float* aq_b = (const float*)d_in[14];
  const float* ak_w = (const float*)d_in[15];
  const float* ak_b = (const float*)d_in[16];
  const float* av_w = (const float*)d_in[17];
  const float* av_b = (const float*)d_in[18];
  const float* ao_w = (const float*)d_in[19];
  const float* ao_b = (const float*)d_in[20];
  const float* rel_k = (const float*)d_in[21];
  const float* rel_v = (const float*)d_in[22];
  const float* ln1_g = (const float*)d_in[23];
  const float* ln1_b = (const float*)d_in[24];
  const float* ln2_g = (const float*)d_in[25];
  const float* ln2_b = (const float*)d_in[26];
  const float* ffn_w1 = (const float*)d_in[27];
  const float* ffn_b1 = (const float*)d_in[28];
  const float* ffn_w2 = (const float*)d_in[29];
  const float* ffn_b2 = (const float*)d_in[30];
  const float* style_key = (const float*)d_in[31];
  const float* sq_w = (const float*)d_in[32];
  const float* sq_b = (const float*)d_in[33];
  const float* sk_w = (const float*)d_in[34];
  const float* sk_b = (const float*)d_in[35];
  const float* sv_w = (const float*)d_in[36];
  const float* sv_b = (const float*)d_in[37];
  const float* so_w = (const float*)d_in[38];
  const float* so_b = (const float*)d_in[39];
  const float* sn_g = (const float*)d_in[40];
  const float* sn_b = (const float*)d_in[41];

  const int N = NROWS;
  char* cur = (char*)d_ws;
  auto nextF = [&](size_t n)->float*{ float* p=(float*)cur; cur += n*sizeof(float); return p; };
  auto nextU = [&](size_t n)->unsigned short*{ unsigned short* p=(unsigned short*)cur; cur += n*2; return p; };

  float* X   = nextF((size_t)N*512);
  float* T   = nextF((size_t)N*512);
  float* Qb  = nextF((size_t)N*512);
  float* Vb  = nextF((size_t)N*512);
  float* QKVb= nextF((size_t)N*QKVS);
  float* KK  = nextF(2*50*512);
  float* VV  = nextF(2*50*512);
  unsigned short* Xh = nextU((size_t)N*512);
  unsigned short* Xl = nextU((size_t)N*512);
  unsigned short* Th = nextU((size_t)N*512);
  unsigned short* Tl = nextU((size_t)N*512);
  unsigned short* Hbh = nextU((size_t)N*2048);
  unsigned short* Hbl = nextU((size_t)N*2048);
  // weight planes
  unsigned short* pw1h = nextU(4194304); unsigned short* pw1l = nextU(4194304);
  unsigned short* pw2h = nextU(4194304); unsigned short* pw2l = nextU(4194304);
  unsigned short* qkvh = nextU((size_t)6*QKVS*512); unsigned short* qkvl = nextU((size_t)6*QKVS*512);
  unsigned short* aoh  = nextU(1572864); unsigned short* aol  = nextU(1572864);
  unsigned short* f1h  = nextU(6291456); unsigned short* f1l  = nextU(6291456);
  unsigned short* f2h  = nextU(6291456); unsigned short* f2l  = nextU(6291456);
  unsigned short* sqh  = nextU(524288);  unsigned short* sql  = nextU(524288);
  unsigned short* soh  = nextU(524288);  unsigned short* sol  = nextU(524288);

  // ---- weight prep ----
  split_k<<<1024,256,0,stream>>>(cw_pw1_w, pw1h, pw1l, 4194304/4);
  split_k<<<1024,256,0,stream>>>(cw_pw2_w, pw2h, pw2l, 4194304/4);
  split_qkv_k<<<1024,256,0,stream>>>(aq_w, ak_w, av_w, qkvh, qkvl);
  split_k<<<1024,256,0,stream>>>(ao_w, aoh, aol, 1572864/4);
  split_k<<<1024,256,0,stream>>>(ffn_w1, f1h, f1l, 6291456/4);
  split_k<<<1024,256,0,stream>>>(ffn_w2, f2h, f2l, 6291456/4);
  split_k<<<512,256,0,stream>>>(sq_w, sqh, sql, 524288/4);
  split_k<<<512,256,0,stream>>>(so_w, soh, sol, 524288/4);

  dim3 gm512(4,64), gm2048(16,64), gmqkv(12,64), gS(8,1);

  embed_k<<<4096,128,0,stream>>>(tokens, embed_w, X);

  // ---- ConvNeXt blocks ----
  for (int i=0;i<4;i++){
    maskmul_k<<<2048,256,0,stream>>>(X, mask);
    dwconv_k<<<4096,128,0,stream>>>(X, cw_dw_w + (size_t)i*512*5, cw_dw_b + i*512, mask, T);
    ln_rows<true><<<1024,256,0,stream>>>(T, cw_ln_g+i*512, cw_ln_b+i*512, T, Th, Tl, N);
    gemm_ps<EPI_GELU,false,1><<<gm2048,256,0,stream>>>(Th, Tl,
        pw1h + (size_t)i*1048576, pw1l + (size_t)i*1048576,
        cw_pw1_b+i*2048, nullptr, nullptr, nullptr, nullptr, Hbh, Hbl, 512, 2048, 0.f);
    gemm_ps<EPI_RES_GAMMA_MASK,false,0><<<gm512,256,0,stream>>>(Hbh, Hbl,
        pw2h + (size_t)i*1048576, pw2l + (size_t)i*1048576,
        cw_pw2_b+i*512, X, cw_gamma+i*512, mask, X, nullptr, nullptr, 2048, 512, 0.f);
  }
  maskmul_split_k<<<2048,256,0,stream>>>(X, mask, Xh, Xl);

  // ---- Attention layers ----
  for (int i=0;i<6;i++){
    gemm_ps<EPI_QKV,false,0><<<gmqkv,256,0,stream>>>(Xh, Xl,
        qkvh + (size_t)i*QKVS*512, qkvl + (size_t)i*QKVS*512,
        aq_b+i*512, ak_b+i*512, av_b+i*512, nullptr, QKVb, nullptr, nullptr,
        512, QKVS, 0.125f);
    attn_tile_k<<<dim3(32,64),256,0,stream>>>(QKVb, rel_k + (size_t)i*9*64,
        rel_v + (size_t)i*9*64, mask, Th, Tl);
    gemm_ps<EPI_RES,false,0><<<gm512,256,0,stream>>>(Th, Tl,
        aoh + (size_t)i*262144, aol + (size_t)i*262144,
        ao_b+i*512, X, nullptr, nullptr, Qb, nullptr, nullptr, 512, 512, 0.f);
    ln_rows<true><<<1024,256,0,stream>>>(Qb, ln1_g+i*512, ln1_b+i*512, X, Xh, Xl, N);
    gemm_ps<EPI_RELU_MASK,true,1><<<gm2048,256,0,stream>>>(Xh, Xl,
        f1h + (size_t)i*1048576, f1l + (size_t)i*1048576,
        ffn_b1+i*2048, nullptr, nullptr, mask, nullptr, Hbh, Hbl, 512, 2048, 0.f);
    gemm_ps<EPI_RES_MASK,false,0><<<gm512,256,0,stream>>>(Hbh, Hbl,
        f2h + (size_t)i*1048576, f2l + (size_t)i*1048576,
        ffn_b2+i*512, X, nullptr, mask, Qb, nullptr, nullptr, 2048, 512, 0.f);
    ln_rows<true><<<1024,256,0,stream>>>(Qb, ln2_g+i*512, ln2_b+i*512, X, Xh, Xl, N);
  }
  maskmul_split_k<<<2048,256,0,stream>>>(X, mask, Xh, Xl);

  // ---- Style attention ----
  gemm_nt<EPI_TANH><<<gS,256,0,stream>>>(style_key, sk_w, sk_b, KK, 50,512,512);
  gemm_nt<EPI_TANH><<<gS,256,0,stream>>>(style_key, sk_w+262144, sk_b+512, KK+25600, 50,512,512);
  gemm_nt<EPI_BIAS><<<gS,256,0,stream>>>(style_v, sv_w, sv_b, VV, 50,512,512);
  gemm_nt<EPI_BIAS><<<gS,256,0,stream>>>(style_v, sv_w+262144, sv_b+512, VV+25600, 50,512,512);

  // layer 0: xin = masked X
  gemm_ps<EPI_BIAS,false,0><<<gm512,256,0,stream>>>(Xh, Xl, sqh, sql,
      sq_b, nullptr, nullptr, nullptr, Qb, nullptr, nullptr, 512, 512, 0.f);
  style_attn_k<<<4096,128,0,stream>>>(Qb, KK, VV, mask, Th, Tl);
  gemm_ps<EPI_RES_MASK,false,1><<<gm512,256,0,stream>>>(Th, Tl, soh, sol,
      so_b, X, nullptr, mask, nullptr, Hbh, Hbl, 512, 512, 0.f);   // x1 planes
  // layer 1: xin = x1 (planes in Hbh/Hbl); residual xt = X
  gemm_ps<EPI_BIAS,false,0><<<gm512,256,0,stream>>>(Hbh, Hbl, sqh+262144, sql+262144,
      sq_b+512, nullptr, nullptr, nullptr, Qb, nullptr, nullptr, 512, 512, 0.f);
  style_attn_k<<<4096,128,0,stream>>>(Qb, KK+25600, VV+25600, mask, Th, Tl);
  gemm_ps<EPI_RES_MASK,false,0><<<gm512,256,0,stream>>>(Th, Tl, soh+262144, sol+262144,
      so_b+512, X, nullptr, mask, Vb, nullptr, nullptr, 512, 512, 0.f);  // x2

  ln_rows<false><<<1024,256,0,stream>>>(Vb, sn_g, sn_b, Qb, nullptr, nullptr, N);
  transpose_out_k<<<dim3(16,16,8),256,0,stream>>>(Qb, mask, (float*)d_out);
}

// Round 8
// 2307.079 us; speedup vs baseline: 8.4861x; 1.1821x over previous
//
#include <hip/hip_runtime.h>
#include <cstdint>

#define Bb 8
#define Ll 512
#define Cc 512
#define Hh 8
#define HD 64
#define Ff 2048
#define Ss 50
#define NROWS 4096   // B*L
#define QKVS 1536

typedef __attribute__((ext_vector_type(8))) short short8v;  // 8 bf16 (4 VGPR)
typedef __attribute__((ext_vector_type(4))) float f32x4;

__device__ __forceinline__ float wave_sum(float v){
  #pragma unroll
  for (int o=32;o>=1;o>>=1) v += __shfl_xor(v,o);
  return v;
}
__device__ __forceinline__ float wave_max(float v){
  #pragma unroll
  for (int o=32;o>=1;o>>=1) v = fmaxf(v,__shfl_xor(v,o));
  return v;
}
__device__ __forceinline__ float bf2f(unsigned short u){
  return __uint_as_float(((unsigned)u) << 16);
}

// cheap split: hi = trunc-bf16(a); lo = trunc-bf16(a - hi). err ~ 2^-16 |a|
__device__ __forceinline__ void splitc(float a, unsigned short& hi, unsigned short& lo){
  unsigned u = __float_as_uint(a);
  hi = (unsigned short)(u >> 16);
  float l = a - __uint_as_float(u & 0xFFFF0000u);
  lo = (unsigned short)(__float_as_uint(l) >> 16);
}
__device__ __forceinline__ void split4(float4 v, unsigned short* hi, unsigned short* lo){
  unsigned short h0,h1,h2,h3,l0,l1,l2,l3;
  splitc(v.x,h0,l0); splitc(v.y,h1,l1); splitc(v.z,h2,l2); splitc(v.w,h3,l3);
  *(ushort4*)hi = make_ushort4(h0,h1,h2,h3);
  *(ushort4*)lo = make_ushort4(l0,l1,l2,l3);
}

// ---------------- weight split (flat) ----------------
__global__ __launch_bounds__(256) void split_k(const float* __restrict__ src,
    unsigned short* __restrict__ hi, unsigned short* __restrict__ lo, int n4){
  for (int i = blockIdx.x*256 + threadIdx.x; i < n4; i += gridDim.x*256){
    float4 v = ((const float4*)src)[i];
    split4(v, (unsigned short*)((ushort4*)hi + i), (unsigned short*)((ushort4*)lo + i));
  }
}

// qkv interleave split: dst planes laid out [6 layers][1536 rows][512]
__global__ __launch_bounds__(256) void split_qkv_k(const float* __restrict__ q,
    const float* __restrict__ k, const float* __restrict__ v,
    unsigned short* __restrict__ hi, unsigned short* __restrict__ lo){
  const int n4 = 6*QKVS*512/4;
  for (int i = blockIdx.x*256 + threadIdx.x; i < n4; i += gridDim.x*256){
    int e = i << 2;
    int layer = e / 786432;           // 1536*512
    int r = e - layer*786432;
    int which = r >> 18;              // /262144
    int off = r & 262143;
    const float* s = (which==0) ? q : (which==1) ? k : v;
    float4 vv = *(const float4*)(s + (size_t)layer*262144 + off);
    split4(vv, (unsigned short*)((ushort4*)hi + i), (unsigned short*)((ushort4*)lo + i));
  }
}

// ---------------- embed gather ----------------
__global__ __launch_bounds__(128) void embed_k(const int* __restrict__ tok,
    const float* __restrict__ emb, float* __restrict__ x){
  int n = blockIdx.x;
  int t = tok[n];
  ((float4*)(x + ((size_t)n<<9)))[threadIdx.x] =
      ((const float4*)(emb + ((size_t)t<<9)))[threadIdx.x];
}

// ---------------- x *= mask[row] ----------------
__global__ __launch_bounds__(256) void maskmul_k(float* __restrict__ x,
    const float* __restrict__ mask){
  int i = blockIdx.x*256 + threadIdx.x;
  float m = mask[i >> 7];
  float4 v = ((float4*)x)[i];
  v.x*=m; v.y*=m; v.z*=m; v.w*=m;
  ((float4*)x)[i]=v;
}
__global__ __launch_bounds__(256) void maskmul_split_k(float* __restrict__ x,
    const float* __restrict__ mask, unsigned short* __restrict__ xh,
    unsigned short* __restrict__ xl){
  int i = blockIdx.x*256 + threadIdx.x;
  float m = mask[i >> 7];
  float4 v = ((float4*)x)[i];
  v.x*=m; v.y*=m; v.z*=m; v.w*=m;
  ((float4*)x)[i]=v;
  split4(v, (unsigned short*)((ushort4*)xh + i), (unsigned short*)((ushort4*)xl + i));
}

// ---------------- depthwise conv K=5, edge pad, +bias, *mask --------
__global__ __launch_bounds__(128) void dwconv_k(const float* __restrict__ x,
    const float* __restrict__ w, const float* __restrict__ bias,
    const float* __restrict__ mask, float* __restrict__ h){
  int n = blockIdx.x; int b_ = n >> 9, l = n & 511;
  int c0 = threadIdx.x * 4;
  float acc0=bias[c0], acc1=bias[c0+1], acc2=bias[c0+2], acc3=bias[c0+3];
  #pragma unroll
  for (int k=0;k<5;k++){
    int ls = l + k - 2; ls = ls < 0 ? 0 : (ls > 511 ? 511 : ls);
    const float4 xv = *(const float4*)&x[((size_t)(b_*512 + ls) << 9) + c0];
    acc0 += w[(c0+0)*5+k]*xv.x;
    acc1 += w[(c0+1)*5+k]*xv.y;
    acc2 += w[(c0+2)*5+k]*xv.z;
    acc3 += w[(c0+3)*5+k]*xv.w;
  }
  float mm = mask[n];
  float4 o; o.x=acc0*mm; o.y=acc1*mm; o.z=acc2*mm; o.w=acc3*mm;
  *(float4*)&h[((size_t)n << 9) + c0] = o;
}

// ---------------- rowwise LayerNorm over C=512 (optional dual split write) ----
template<bool SPLIT>
__global__ __launch_bounds__(256) void ln_rows(const float* __restrict__ x,
    const float* __restrict__ g, const float* __restrict__ bt,
    float* __restrict__ y, unsigned short* __restrict__ yh,
    unsigned short* __restrict__ yl, int nrows){
  int wid = threadIdx.x >> 6, lane = threadIdx.x & 63;
  int row = blockIdx.x*4 + wid;
  if (row >= nrows) return;
  const float4* xr = (const float4*)(x + ((size_t)row<<9));
  float4 a = xr[lane*2], b = xr[lane*2+1];
  float s = a.x+a.y+a.z+a.w+b.x+b.y+b.z+b.w;
  s = wave_sum(s);
  float m = s * (1.f/512.f);
  float d0=a.x-m,d1=a.y-m,d2=a.z-m,d3=a.w-m,d4=b.x-m,d5=b.y-m,d6=b.z-m,d7=b.w-m;
  float sq = d0*d0+d1*d1+d2*d2+d3*d3+d4*d4+d5*d5+d6*d6+d7*d7;
  sq = wave_sum(sq);
  float var = sq * (1.f/512.f);
  float inv = 1.f/sqrtf(var + 1e-6f);
  const float4* gr = (const float4*)g; const float4* br = (const float4*)bt;
  float4 g0=gr[lane*2], g1=gr[lane*2+1], b0=br[lane*2], b1=br[lane*2+1];
  float4 o0, o1;
  o0.x=d0*inv*g0.x+b0.x; o0.y=d1*inv*g0.y+b0.y; o0.z=d2*inv*g0.z+b0.z; o0.w=d3*inv*g0.w+b0.w;
  o1.x=d4*inv*g1.x+b1.x; o1.y=d5*inv*g1.y+b1.y; o1.z=d6*inv*g1.z+b1.z; o1.w=d7*inv*g1.w+b1.w;
  float4* yr = (float4*)(y + ((size_t)row<<9));
  yr[lane*2]=o0; yr[lane*2+1]=o1;
  if constexpr (SPLIT){
    size_t base = ((size_t)row<<9) + lane*8;
    split4(o0, yh+base,   yl+base);
    split4(o1, yh+base+4, yl+base+4);
  }
}

#define EPI_BIAS 0
#define EPI_SCALE 1
#define EPI_GELU 2
#define EPI_RES 3
#define EPI_RELU_MASK 4
#define EPI_RES_MASK 5
#define EPI_RES_GAMMA_MASK 6
#define EPI_TANH 7
#define EPI_QKV 8

// ---------------- fp32 VALU GEMM (style sk/sv only, 50 rows) ----------------
template<int EPI>
__global__ __launch_bounds__(256) void gemm_nt(
    const float* __restrict__ A, const float* __restrict__ W,
    const float* __restrict__ bias,
    float* __restrict__ Y, int N, int K, int O)
{
  __shared__ float As[16][68];
  __shared__ float Bs[16][68];
  int t = threadIdx.x;
  int tx = t & 15, ty = t >> 4;
  int row0 = blockIdx.y << 6, col0 = blockIdx.x << 6;
  int lr = t >> 2, lk = (t & 3) << 2;
  float acc[4][4] = {};
  int ar = row0 + lr;
  bool arok = ar < N;
  const float* Ap = A + (size_t)(arok ? ar : 0) * K + lk;
  const float* Wp = W + (size_t)(col0 + lr) * K + lk;
  for (int k0 = 0; k0 < K; k0 += 16) {
    float4 av;
    if (arok) av = *(const float4*)(Ap + k0);
    else { av.x=0;av.y=0;av.z=0;av.w=0; }
    float4 bv = *(const float4*)(Wp + k0);
    As[lk+0][lr]=av.x; As[lk+1][lr]=av.y; As[lk+2][lr]=av.z; As[lk+3][lr]=av.w;
    Bs[lk+0][lr]=bv.x; Bs[lk+1][lr]=bv.y; Bs[lk+2][lr]=bv.z; Bs[lk+3][lr]=bv.w;
    __syncthreads();
    #pragma unroll
    for (int k=0;k<16;k++){
      float4 af = *(const float4*)&As[k][ty<<2];
      float4 bf = *(const float4*)&Bs[k][tx<<2];
      float a4[4]={af.x,af.y,af.z,af.w};
      float b4[4]={bf.x,bf.y,bf.z,bf.w};
      #pragma unroll
      for (int i=0;i<4;i++)
        #pragma unroll
        for (int j=0;j<4;j++)
          acc[i][j] += a4[i]*b4[j];
    }
    __syncthreads();
  }
  #pragma unroll
  for (int i=0;i<4;i++){
    int row = row0 + (ty<<2) + i;
    if (row >= N) break;
    int colb = col0 + (tx<<2);
    float vv_[4];
    #pragma unroll
    for (int j=0;j<4;j++){
      float v = acc[i][j] + bias[colb+j];
      if constexpr (EPI==EPI_TANH) v = tanhf(v);
      vv_[j]=v;
    }
    float4 ov; ov.x=vv_[0]; ov.y=vv_[1]; ov.z=vv_[2]; ov.w=vv_[3];
    *(float4*)(Y + (size_t)row*O + colb) = ov;
  }
}

// ---------------- pre-split MFMA GEMM ----------------
template<int EPI, bool AMASK, int OUT>
__global__ __launch_bounds__(256) void gemm_ps(
    const unsigned short* __restrict__ Ah, const unsigned short* __restrict__ Al,
    const unsigned short* __restrict__ Wh, const unsigned short* __restrict__ Wl,
    const float* __restrict__ bias, const float* __restrict__ res,
    const float* __restrict__ gamma, const float* __restrict__ rowmask,
    float* __restrict__ Y, unsigned short* __restrict__ Yh,
    unsigned short* __restrict__ Yl, int K, int O, float scale)
{
  __shared__ unsigned short AhS[64][40], AlS[64][40];
  __shared__ unsigned short BhS[128][40], BlS[128][40];
  int t = threadIdx.x;
  int row0 = blockIdx.y << 6, col0 = blockIdx.x << 7;
  int lane = t & 63, wid = t >> 6;
  int wr = wid >> 1, wc = wid & 1;

  int sr = t >> 2, sc = (t & 3) << 3;
  const unsigned short* Ahg = Ah + (size_t)(row0 + sr)*K + sc;
  const unsigned short* Alg = Al + (size_t)(row0 + sr)*K + sc;
  const unsigned short* Bhg = Wh + (size_t)(col0 + sr)*K + sc;
  const unsigned short* Blg = Wl + (size_t)(col0 + sr)*K + sc;
  float am = 1.f;
  if (AMASK) am = rowmask[row0 + sr];

  f32x4 acc[2][4] = {};
  int nsteps = K >> 5;
  short8v ah_ = *(const short8v*)(Ahg);
  short8v al_ = *(const short8v*)(Alg);
  short8v bh0_ = *(const short8v*)(Bhg);
  short8v bl0_ = *(const short8v*)(Blg);
  short8v bh1_ = *(const short8v*)(Bhg + (size_t)64*K);
  short8v bl1_ = *(const short8v*)(Blg + (size_t)64*K);

  for (int s = 0; s < nsteps; ++s){
    if (AMASK && am == 0.f){ ah_ ^= ah_; al_ ^= al_; }
    __syncthreads();
    *(short8v*)&AhS[sr][sc] = ah_;
    *(short8v*)&AlS[sr][sc] = al_;
    *(short8v*)&BhS[sr][sc] = bh0_;
    *(short8v*)&BlS[sr][sc] = bl0_;
    *(short8v*)&BhS[sr+64][sc] = bh1_;
    *(short8v*)&BlS[sr+64][sc] = bl1_;
    __syncthreads();
    if (s+1 < nsteps){
      int ko = (s+1) << 5;
      ah_ = *(const short8v*)(Ahg + ko);
      al_ = *(const short8v*)(Alg + ko);
      bh0_ = *(const short8v*)(Bhg + ko);
      bl0_ = *(const short8v*)(Blg + ko);
      bh1_ = *(const short8v*)(Bhg + (size_t)64*K + ko);
      bl1_ = *(const short8v*)(Blg + (size_t)64*K + ko);
    }
    int fr = lane & 15, fc = (lane >> 4) << 3;
    short8v ahf[2], alf[2], bhf[4], blf[4];
    #pragma unroll
    for (int mt=0; mt<2; ++mt){
      int r = (wr<<5) + (mt<<4) + fr;
      ahf[mt] = *(const short8v*)&AhS[r][fc];
      alf[mt] = *(const short8v*)&AlS[r][fc];
    }
    #pragma unroll
    for (int nt=0; nt<4; ++nt){
      int r = (wc<<6) + (nt<<4) + fr;
      bhf[nt] = *(const short8v*)&BhS[r][fc];
      blf[nt] = *(const short8v*)&BlS[r][fc];
    }
    #pragma unroll
    for (int mt=0; mt<2; ++mt)
      #pragma unroll
      for (int nt=0; nt<4; ++nt){
        f32x4 c = acc[mt][nt];
        c = __builtin_amdgcn_mfma_f32_16x16x32_bf16(ahf[mt], bhf[nt], c, 0,0,0);
        c = __builtin_amdgcn_mfma_f32_16x16x32_bf16(ahf[mt], blf[nt], c, 0,0,0);
        c = __builtin_amdgcn_mfma_f32_16x16x32_bf16(alf[mt], bhf[nt], c, 0,0,0);
        acc[mt][nt] = c;
      }
  }

  int rb = row0 + (wr<<5) + ((lane>>4)<<2);
  int cb = col0 + (wc<<6) + (lane & 15);
  float bs[4], gm[4];
  #pragma unroll
  for (int nt=0; nt<4; ++nt){
    int col = cb + (nt<<4);
    if constexpr (EPI==EPI_QKV){
      int which = blockIdx.x >> 2;
      const float* bp = (which==0) ? bias : (which==1) ? res : gamma;
      bs[nt] = bp[col & 511];
    } else {
      bs[nt] = bias[col];
      if constexpr (EPI==EPI_RES_GAMMA_MASK) gm[nt] = gamma[col];
    }
  }
  float qscale = 1.f;
  if constexpr (EPI==EPI_QKV) qscale = ((blockIdx.x>>2)==0) ? scale : 1.f;
  #pragma unroll
  for (int mt=0; mt<2; ++mt)
    #pragma unroll
    for (int j=0; j<4; ++j){
      int row = rb + (mt<<4) + j;
      float rm = 1.f;
      if constexpr (EPI==EPI_RELU_MASK || EPI==EPI_RES_MASK || EPI==EPI_RES_GAMMA_MASK)
        rm = rowmask[row];
      const float* rr = nullptr;
      if constexpr (EPI==EPI_RES || EPI==EPI_RES_MASK || EPI==EPI_RES_GAMMA_MASK)
        rr = res + (size_t)row*O + cb;
      #pragma unroll
      for (int nt=0; nt<4; ++nt){
        float v = acc[mt][nt][j] + bs[nt];
        if constexpr (EPI==EPI_SCALE) v *= scale;
        else if constexpr (EPI==EPI_QKV) v *= qscale;
        else if constexpr (EPI==EPI_GELU) v = 0.5f*v*(1.f+erff(v*0.7071067811865475f));
        else if constexpr (EPI==EPI_RES) v = rr[nt<<4] + v;
        else if constexpr (EPI==EPI_RELU_MASK) v = fmaxf(v,0.f)*rm;
        else if constexpr (EPI==EPI_RES_MASK) v = rr[nt<<4] + v*rm;
        else if constexpr (EPI==EPI_RES_GAMMA_MASK) v = (rr[nt<<4] + gm[nt]*v)*rm;
        size_t oidx = (size_t)row*O + cb + (nt<<4);
        if constexpr (OUT==0) Y[oidx] = v;
        else { unsigned short h,l; splitc(v,h,l); Yh[oidx]=h; Yl[oidx]=l; }
      }
    }
}

// ---------------- V transpose: planes [N][1536] cols 1024.. -> VT[b][512d][512tok]
__global__ __launch_bounds__(256) void transpose_v_k(
    const unsigned short* __restrict__ Vh, const unsigned short* __restrict__ Vl,
    unsigned short* __restrict__ VTh, unsigned short* __restrict__ VTl){
  __shared__ unsigned short t0[64][72];
  __shared__ unsigned short t1[64][72];
  int dt = blockIdx.x, tb = blockIdx.y, b = blockIdx.z;
  int t = threadIdx.x;
  int r = t >> 3, c = (t & 7) << 3;   // r 0..31
  #pragma unroll
  for (int rep = 0; rep < 2; ++rep){
    int rr = rep*32 + r;
    size_t g = ((size_t)b*512 + tb*64 + rr)*QKVS + 1024 + dt*64 + c;
    *(short8v*)&t0[rr][c] = *(const short8v*)&Vh[g];
    *(short8v*)&t1[rr][c] = *(const short8v*)&Vl[g];
  }
  __syncthreads();
  #pragma unroll
  for (int rep = 0; rep < 2; ++rep){
    int rr = rep*32 + r;   // out row: d-local
    short8v vh_, vl_;
    #pragma unroll
    for (int i = 0; i < 8; ++i){ vh_[i] = (short)t0[c+i][rr]; vl_[i] = (short)t1[c+i][rr]; }
    size_t g = ((size_t)b*512 + dt*64 + rr)*512 + tb*64 + c;
    *(short8v*)&VTh[g] = vh_;
    *(short8v*)&VTl[g] = vl_;
  }
}

// ---------------- MFMA windowed-rel attention ----------------
// Block = (16 q-rows, b,h), 256 threads = 4 waves; wave w owns score cols /
// output dims [w*16, w*16+16). Scores & P stored as bf16 hi/lo planes in LDS.
__global__ __launch_bounds__(256) void attn_mf(
    const unsigned short* __restrict__ Ph_g, const unsigned short* __restrict__ Pl_g,
    const unsigned short* __restrict__ VTh_g, const unsigned short* __restrict__ VTl_g,
    const float* __restrict__ relk, const float* __restrict__ relv,
    const float* __restrict__ mask, unsigned short* __restrict__ Oh,
    unsigned short* __restrict__ Ol)
{
  __shared__ float ms_[512];
  __shared__ float rk[9][64];
  __shared__ float rv[9][64];
  __shared__ unsigned short Qh[16][72], Ql[16][72];
  __shared__ float qrel[16][12];
  __shared__ unsigned short Kh[64][72], Kl[64][72];
  __shared__ unsigned short Sh[16][520], Sl[16][520];
  __shared__ float invs[16];

  int qt = blockIdx.x, bh = blockIdx.y;
  int h = bh & 7, b_ = bh >> 3;
  int t = threadIdx.x;
  int l0 = qt * 16;
  const size_t rowoff = (size_t)b_ * 512;
  int lane = t & 63, w = t >> 6;

  ms_[t] = mask[rowoff + t]; ms_[t+256] = mask[rowoff + t + 256];
  for (int i = t; i < 576; i += 256){ ((float*)rk)[i] = relk[i]; ((float*)rv)[i] = relv[i]; }
  {
    int idx = t & 127; int r = idx >> 3, c = (idx & 7) << 3;
    size_t g = (rowoff + l0 + r)*QKVS + h*64 + c;
    if (t < 128) *(short8v*)&Qh[r][c] = *(const short8v*)&Ph_g[g];
    else         *(short8v*)&Ql[r][c] = *(const short8v*)&Pl_g[g];
  }
  __syncthreads();
  if (t < 144){
    int dlt = t >> 4, q_ = t & 15;
    float s = 0.f;
    for (int d = 0; d < 64; ++d){
      float qf = bf2f(Qh[q_][d]) + bf2f(Ql[q_][d]);
      s += qf * rk[dlt][d];
    }
    qrel[q_][dlt] = s;
  }

  int fr = lane & 15, fc = (lane >> 4) << 3;
  // ---- QK over 8 tiles of 64 keys ----
  for (int tt = 0; tt < 8; ++tt){
    __syncthreads();
    #pragma unroll
    for (int rep = 0; rep < 2; ++rep){
      int idx = rep*256 + t; int r = idx >> 3, c = (idx & 7) << 3;
      size_t g = (rowoff + tt*64 + r)*QKVS + 512 + h*64 + c;
      *(short8v*)&Kh[r][c] = *(const short8v*)&Ph_g[g];
      *(short8v*)&Kl[r][c] = *(const short8v*)&Pl_g[g];
    }
    __syncthreads();
    short8v ah0 = *(const short8v*)&Qh[fr][fc];
    short8v ah1 = *(const short8v*)&Qh[fr][32+fc];
    short8v al0 = *(const short8v*)&Ql[fr][fc];
    short8v al1 = *(const short8v*)&Ql[fr][32+fc];
    int br = w*16 + fr;
    short8v bh0 = *(const short8v*)&Kh[br][fc];
    short8v bh1 = *(const short8v*)&Kh[br][32+fc];
    short8v bl0 = *(const short8v*)&Kl[br][fc];
    short8v bl1 = *(const short8v*)&Kl[br][32+fc];
    f32x4 c4 = {};
    c4 = __builtin_amdgcn_mfma_f32_16x16x32_bf16(ah0,bh0,c4,0,0,0);
    c4 = __builtin_amdgcn_mfma_f32_16x16x32_bf16(ah1,bh1,c4,0,0,0);
    c4 = __builtin_amdgcn_mfma_f32_16x16x32_bf16(ah0,bl0,c4,0,0,0);
    c4 = __builtin_amdgcn_mfma_f32_16x16x32_bf16(ah1,bl1,c4,0,0,0);
    c4 = __builtin_amdgcn_mfma_f32_16x16x32_bf16(al0,bh0,c4,0,0,0);
    c4 = __builtin_amdgcn_mfma_f32_16x16x32_bf16(al1,bh1,c4,0,0,0);
    int m = tt*64 + w*16 + fr;      // C col = lane&15
    float mm_ = ms_[m];
    #pragma unroll
    for (int j = 0; j < 4; ++j){
      int q = ((lane>>4)<<2) + j;
      int l = l0 + q;
      float s = c4[j];
      int dlt = m - l + 4;
      if (dlt >= 0 && dlt <= 8) s += qrel[q][dlt];
      if (ms_[l] * mm_ == 0.f) s = -10000.f;
      unsigned short hh, ll_;
      splitc(s, hh, ll_);
      Sh[q][m] = hh; Sl[q][m] = ll_;
    }
  }
  __syncthreads();

  // ---- softmax (thread owns cols kg+16j of row q); P planes written in place --
  {
    int q = t >> 4, kg = t & 15;
    float mx = -3.4e38f;
    for (int jj = 0; jj < 32; ++jj){
      int m = kg + (jj<<4);
      float s = bf2f(Sh[q][m]) + bf2f(Sl[q][m]);
      mx = fmaxf(mx, s);
    }
    #pragma unroll
    for (int o = 8; o >= 1; o >>= 1) mx = fmaxf(mx, __shfl_xor(mx, o));
    float sum = 0.f;
    for (int jj = 0; jj < 32; ++jj){
      int m = kg + (jj<<4);
      float s = bf2f(Sh[q][m]) + bf2f(Sl[q][m]);
      float e = expf(s - mx);
      sum += e;
      unsigned short hh, ll_; splitc(e, hh, ll_);
      Sh[q][m] = hh; Sl[q][m] = ll_;
    }
    #pragma unroll
    for (int o = 8; o >= 1; o >>= 1) sum += __shfl_xor(sum, o);
    if (kg == 0) invs[q] = 1.f / sum;
  }

  // ---- AV over 8 tiles of 64 keys (VT staged: rows = d, cols = token) ----
  f32x4 oacc = {};
  for (int tt = 0; tt < 8; ++tt){
    __syncthreads();
    #pragma unroll
    for (int rep = 0; rep < 2; ++rep){
      int idx = rep*256 + t; int r = idx >> 3, c = (idx & 7) << 3;
      size_t g = ((size_t)b_*512 + h*64 + r)*512 + tt*64 + c;
      *(short8v*)&Kh[r][c] = *(const short8v*)&VTh_g[g];
      *(short8v*)&Kl[r][c] = *(const short8v*)&VTl_g[g];
    }
    __syncthreads();
    #pragma unroll
    for (int ks = 0; ks < 2; ++ks){
      int moff = tt*64 + ks*32 + fc;
      short8v ah = *(const short8v*)&Sh[fr][moff];
      short8v al = *(const short8v*)&Sl[fr][moff];
      int br = w*16 + fr;
      short8v bh = *(const short8v*)&Kh[br][ks*32 + fc];
      short8v bl = *(const short8v*)&Kl[br][ks*32 + fc];
      oacc = __builtin_amdgcn_mfma_f32_16x16x32_bf16(ah,bh,oacc,0,0,0);
      oacc = __builtin_amdgcn_mfma_f32_16x16x32_bf16(ah,bl,oacc,0,0,0);
      oacc = __builtin_amdgcn_mfma_f32_16x16x32_bf16(al,bh,oacc,0,0,0);
    }
  }
  // ---- epilogue: rel_v window + normalize, write output planes ----
  {
    int d = w*16 + fr;    // C col = lane&15
    #pragma unroll
    for (int j = 0; j < 4; ++j){
      int q = ((lane>>4)<<2) + j;
      int l = l0 + q;
      float val = oacc[j];
      #pragma unroll
      for (int dlt = 0; dlt < 9; ++dlt){
        int m = l + dlt - 4;
        if (m >= 0 && m < 512){
          float e = bf2f(Sh[q][m]) + bf2f(Sl[q][m]);
          val += e * rv[dlt][d];
        }
      }
      val *= invs[q];
      unsigned short hh, ll_; splitc(val, hh, ll_);
      size_t oidx = ((rowoff + l) << 9) + h*64 + d;
      Oh[oidx] = hh; Ol[oidx] = ll_;
    }
  }
}

// ---------------- style attention (split out) ----------------
__global__ __launch_bounds__(128) void style_attn_k(const float* __restrict__ Q,
    const float* __restrict__ kk, const float* __restrict__ vv,
    const float* __restrict__ mask, unsigned short* __restrict__ Oh,
    unsigned short* __restrict__ Ol){
  int n = blockIdx.x;
  int h = threadIdx.x >> 6, lane = threadIdx.x & 63;
  __shared__ float qh[512];
  __shared__ float aw[2][64];
  {
    float4 v = ((const float4*)(Q + ((size_t)n<<9)))[threadIdx.x];
    *(float4*)&qh[threadIdx.x*4] = v;
  }
  __syncthreads();
  float sc;
  if (lane < 50){
    float s = 0.f;
    const float* kr = kk + lane*512 + h*256;
    const float* qr = qh + h*256;
    for (int d4 = 0; d4 < 64; ++d4){
      float4 kv = *(const float4*)&kr[d4*4];
      s += qr[d4*4]*kv.x + qr[d4*4+1]*kv.y + qr[d4*4+2]*kv.z + qr[d4*4+3]*kv.w;
    }
    sc = s * 0.044194173824159216f;
  } else sc = -1e30f;
  float mx = wave_max(sc);
  float ex = (lane < 50) ? expf(sc - mx) : 0.f;
  float sm = wave_sum(ex);
  float keep = (mask[n] == 0.f) ? 0.f : 1.f;
  aw[h][lane] = ex / sm * keep;
  __syncthreads();
  float4 acc; acc.x=0; acc.y=0; acc.z=0; acc.w=0;
  const float* vb = vv + h*256 + lane*4;
  for (int s = 0; s < 50; ++s){
    float a = aw[h][s];
    const float4 vvv = *(const float4*)&vb[(size_t)s*512];
    acc.x += a*vvv.x; acc.y += a*vvv.y; acc.z += a*vvv.z; acc.w += a*vvv.w;
  }
  size_t oidx = ((size_t)n<<9) + h*256 + lane*4;
  split4(acc, Oh+oidx, Ol+oidx);
}

// ---------------- final transpose ----------------
__global__ __launch_bounds__(256) void transpose_out_k(const float* __restrict__ xn,
    const float* __restrict__ mask, float* __restrict__ out){
  __shared__ float tile[32][33];
  int b_ = blockIdx.z; int c0 = blockIdx.x*32; int l0 = blockIdx.y*32;
  int tx = threadIdx.x & 31, ty = threadIdx.x >> 5;
  #pragma unroll
  for (int r=0;r<4;r++){
    int l = l0 + ty + r*8;
    tile[ty + r*8][tx] = xn[(((size_t)(b_*512 + l))<<9) + c0 + tx];
  }
  __syncthreads();
  float mm = mask[b_*512 + l0 + tx];
  #pragma unroll
  for (int r=0;r<4;r++){
    int c = c0 + ty + r*8;
    out[(((size_t)(b_*512 + c))<<9) + l0 + tx] = tile[tx][ty + r*8] * mm;
  }
}

extern "C" void kernel_launch(void* const* d_in, const int* in_sizes, int n_in,
                              void* d_out, int out_size, void* d_ws, size_t ws_size,
                              hipStream_t stream) {
  const int*   tokens   = (const int*)  d_in[0];
  const float* style_v  = (const float*)d_in[1];
  const float* mask     = (const float*)d_in[2];
  const float* embed_w  = (const float*)d_in[3];
  const float* cw_dw_w  = (const float*)d_in[4];
  const float* cw_dw_b  = (const float*)d_in[5];
  const float* cw_ln_g  = (const float*)d_in[6];
  const float* cw_ln_b  = (const float*)d_in[7];
  const float* cw_pw1_w = (const float*)d_in[8];
  const float* cw_pw1_b = (const float*)d_in[9];
  const float* cw_pw2_w = (const float*)d_in[10];
  const float* cw_pw2_b = (const float*)d_in[11];
  const float* cw_gamma = (const float*)d_in[12];
  const float* aq_w = (const float*)d_in[13];
  const float* aq_b = (const float*)d_in[14];
  const float* ak_w = (const float*)d_in[15];
  const float* ak_b = (const float*)d_in[16];
  const float* av_w = (const float*)d_in[17];
  const float* av_b = (const float*)d_in[18];
  const float* ao_w = (const float*)d_in[19];
  const float* ao_b = (const float*)d_in[20];
  const float* rel_k = (const float*)d_in[21];
  const float* rel_v = (const float*)d_in[22];
  const float* ln1_g = (const float*)d_in[23];
  const float* ln1_b = (const float*)d_in[24];
  const float* ln2_g = (const float*)d_in[25];
  const float* ln2_b = (const float*)d_in[26];
  const float* ffn_w1 = (const float*)d_in[27];
  const float* ffn_b1 = (const float*)d_in[28];
  const float* ffn_w2 = (const float*)d_in[29];
  const float* ffn_b2 = (const float*)d_in[30];
  const float* style_key = (const float*)d_in[31];
  const float* sq_w = (const float*)d_in[32];
  const float* sq_b = (const float*)d_in[33];
  const float* sk_w = (const float*)d_in[34];
  const float* sk_b = (const float*)d_in[35];
  const float* sv_w = (const float*)d_in[36];
  const float* sv_b = (const float*)d_in[37];
  const float* so_w = (const float*)d_in[38];
  const float* so_b = (const float*)d_in[39];
  const float* sn_g = (const float*)d_in[40];
  const float* sn_b = (const float*)d_in[41];

  const int N = NROWS;
  char* cur = (char*)d_ws;
  auto nextF = [&](size_t n)->float*{ float* p=(float*)cur; cur += n*sizeof(float); return p; };
  auto nextU = [&](size_t n)->unsigned short*{ unsigned short* p=(unsigned short*)cur; cur += n*2; return p; };

  float* X   = nextF((size_t)N*512);
  float* T   = nextF((size_t)N*512);
  float* Qb  = nextF((size_t)N*512);
  float* Vb  = nextF((size_t)N*512);
  float* KK  = nextF(2*50*512);
  float* VV  = nextF(2*50*512);
  unsigned short* Xh = nextU((size_t)N*512);
  unsigned short* Xl = nextU((size_t)N*512);
  unsigned short* Th = nextU((size_t)N*512);
  unsigned short* Tl = nextU((size_t)N*512);
  unsigned short* Hbh = nextU((size_t)N*2048);
  unsigned short* Hbl = nextU((size_t)N*2048);
  unsigned short* QKVh = nextU((size_t)N*QKVS);
  unsigned short* QKVl = nextU((size_t)N*QKVS);
  unsigned short* VTh = nextU((size_t)8*512*512);
  unsigned short* VTl = nextU((size_t)8*512*512);
  // weight planes
  unsigned short* pw1h = nextU(4194304); unsigned short* pw1l = nextU(4194304);
  unsigned short* pw2h = nextU(4194304); unsigned short* pw2l = nextU(4194304);
  unsigned short* qkvh = nextU((size_t)6*QKVS*512); unsigned short* qkvl = nextU((size_t)6*QKVS*512);
  unsigned short* aoh  = nextU(1572864); unsigned short* aol  = nextU(1572864);
  unsigned short* f1h  = nextU(6291456); unsigned short* f1l  = nextU(6291456);
  unsigned short* f2h  = nextU(6291456); unsigned short* f2l  = nextU(6291456);
  unsigned short* sqh  = nextU(524288);  unsigned short* sql  = nextU(524288);
  unsigned short* soh  = nextU(524288);  unsigned short* sol  = nextU(524288);

  // ---- weight prep ----
  split_k<<<1024,256,0,stream>>>(cw_pw1_w, pw1h, pw1l, 4194304/4);
  split_k<<<1024,256,0,stream>>>(cw_pw2_w, pw2h, pw2l, 4194304/4);
  split_qkv_k<<<1024,256,0,stream>>>(aq_w, ak_w, av_w, qkvh, qkvl);
  split_k<<<1024,256,0,stream>>>(ao_w, aoh, aol, 1572864/4);
  split_k<<<1024,256,0,stream>>>(ffn_w1, f1h, f1l, 6291456/4);
  split_k<<<1024,256,0,stream>>>(ffn_w2, f2h, f2l, 6291456/4);
  split_k<<<512,256,0,stream>>>(sq_w, sqh, sql, 524288/4);
  split_k<<<512,256,0,stream>>>(so_w, soh, sol, 524288/4);

  dim3 gm512(4,64), gm2048(16,64), gmqkv(12,64), gS(8,1);

  embed_k<<<4096,128,0,stream>>>(tokens, embed_w, X);

  // ---- ConvNeXt blocks ----
  for (int i=0;i<4;i++){
    maskmul_k<<<2048,256,0,stream>>>(X, mask);
    dwconv_k<<<4096,128,0,stream>>>(X, cw_dw_w + (size_t)i*512*5, cw_dw_b + i*512, mask, T);
    ln_rows<true><<<1024,256,0,stream>>>(T, cw_ln_g+i*512, cw_ln_b+i*512, T, Th, Tl, N);
    gemm_ps<EPI_GELU,false,1><<<gm2048,256,0,stream>>>(Th, Tl,
        pw1h + (size_t)i*1048576, pw1l + (size_t)i*1048576,
        cw_pw1_b+i*2048, nullptr, nullptr, nullptr, nullptr, Hbh, Hbl, 512, 2048, 0.f);
    gemm_ps<EPI_RES_GAMMA_MASK,false,0><<<gm512,256,0,stream>>>(Hbh, Hbl,
        pw2h + (size_t)i*1048576, pw2l + (size_t)i*1048576,
        cw_pw2_b+i*512, X, cw_gamma+i*512, mask, X, nullptr, nullptr, 2048, 512, 0.f);
  }
  maskmul_split_k<<<2048,256,0,stream>>>(X, mask, Xh, Xl);

  // ---- Attention layers ----
  for (int i=0;i<6;i++){
    gemm_ps<EPI_QKV,false,1><<<gmqkv,256,0,stream>>>(Xh, Xl,
        qkvh + (size_t)i*QKVS*512, qkvl + (size_t)i*QKVS*512,
        aq_b+i*512, ak_b+i*512, av_b+i*512, nullptr, nullptr, QKVh, QKVl,
        512, QKVS, 0.125f);
    transpose_v_k<<<dim3(8,8,8),256,0,stream>>>(QKVh, QKVl, VTh, VTl);
    attn_mf<<<dim3(32,64),256,0,stream>>>(QKVh, QKVl, VTh, VTl,
        rel_k + (size_t)i*9*64, rel_v + (size_t)i*9*64, mask, Th, Tl);
    gemm_ps<EPI_RES,false,0><<<gm512,256,0,stream>>>(Th, Tl,
        aoh + (size_t)i*262144, aol + (size_t)i*262144,
        ao_b+i*512, X, nullptr, nullptr, Qb, nullptr, nullptr, 512, 512, 0.f);
    ln_rows<true><<<1024,256,0,stream>>>(Qb, ln1_g+i*512, ln1_b+i*512, X, Xh, Xl, N);
    gemm_ps<EPI_RELU_MASK,true,1><<<gm2048,256,0,stream>>>(Xh, Xl,
        f1h + (size_t)i*1048576, f1l + (size_t)i*1048576,
        ffn_b1+i*2048, nullptr, nullptr, mask, nullptr, Hbh, Hbl, 512, 2048, 0.f);
    gemm_ps<EPI_RES_MASK,false,0><<<gm512,256,0,stream>>>(Hbh, Hbl,
        f2h + (size_t)i*1048576, f2l + (size_t)i*1048576,
        ffn_b2+i*512, X, nullptr, mask, Qb, nullptr, nullptr, 2048, 512, 0.f);
    ln_rows<true><<<1024,256,0,stream>>>(Qb, ln2_g+i*512, ln2_b+i*512, X, Xh, Xl, N);
  }
  maskmul_split_k<<<2048,256,0,stream>>>(X, mask, Xh, Xl);

  // ---- Style attention ----
  gemm_nt<EPI_TANH><<<gS,256,0,stream>>>(style_key, sk_w, sk_b, KK, 50,512,512);
  gemm_nt<EPI_TANH><<<gS,256,0,stream>>>(style_key, sk_w+262144, sk_b+512, KK+25600, 50,512,512);
  gemm_nt<EPI_BIAS><<<gS,256,0,stream>>>(style_v, sv_w, sv_b, VV, 50,512,512);
  gemm_nt<EPI_BIAS><<<gS,256,0,stream>>>(style_v, sv_w+262144, sv_b+512, VV+25600, 50,512,512);

  // layer 0: xin = masked X
  gemm_ps<EPI_BIAS,false,0><<<gm512,256,0,stream>>>(Xh, Xl, sqh, sql,
      sq_b, nullptr, nullptr, nullptr, Qb, nullptr, nullptr, 512, 512, 0.f);
  style_attn_k<<<4096,128,0,stream>>>(Qb, KK, VV, mask, Th, Tl);
  gemm_ps<EPI_RES_MASK,false,1><<<gm512,256,0,stream>>>(Th, Tl, soh, sol,
      so_b, X, nullptr, mask, nullptr, Hbh, Hbl, 512, 512, 0.f);   // x1 planes
  // layer 1: xin = x1 (planes); residual xt = X
  gemm_ps<EPI_BIAS,false,0><<<gm512,256,0,stream>>>(Hbh, Hbl, sqh+262144, sql+262144,
      sq_b+512, nullptr, nullptr, nullptr, Qb, nullptr, nullptr, 512, 512, 0.f);
  style_attn_k<<<4096,128,0,stream>>>(Qb, KK+25600, VV+25600, mask, Th, Tl);
  gemm_ps<EPI_RES_MASK,false,0><<<gm512,256,0,stream>>>(Th, Tl, soh+262144, sol+262144,
      so_b+512, X, nullptr, mask, Vb, nullptr, nullptr, 512, 512, 0.f);  // x2

  ln_rows<false><<<1024,256,0,stream>>>(Vb, sn_g, sn_b, Qb, nullptr, nullptr, N);
  transpose_out_k<<<dim3(16,16,8),256,0,stream>>>(Qb, mask, (float*)d_out);
}

// Round 9
// 2222.490 us; speedup vs baseline: 8.8091x; 1.0381x over previous
//
#include <hip/hip_runtime.h>
#include <cstdint>

#define Bb 8
#define Ll 512
#define Cc 512
#define Hh 8
#define HD 64
#define Ff 2048
#define Ss 50
#define NROWS 4096   // B*L
#define QKVS 1536

typedef __attribute__((ext_vector_type(8))) short short8v;  // 8 bf16 (4 VGPR)
typedef __attribute__((ext_vector_type(4))) float f32x4;

__device__ __forceinline__ float wave_sum(float v){
  #pragma unroll
  for (int o=32;o>=1;o>>=1) v += __shfl_xor(v,o);
  return v;
}
__device__ __forceinline__ float wave_max(float v){
  #pragma unroll
  for (int o=32;o>=1;o>>=1) v = fmaxf(v,__shfl_xor(v,o));
  return v;
}
__device__ __forceinline__ float bf2f(unsigned short u){
  return __uint_as_float(((unsigned)u) << 16);
}

// cheap split: hi = trunc-bf16(a); lo = trunc-bf16(a - hi). err ~ 2^-16 |a|
__device__ __forceinline__ void splitc(float a, unsigned short& hi, unsigned short& lo){
  unsigned u = __float_as_uint(a);
  hi = (unsigned short)(u >> 16);
  float l = a - __uint_as_float(u & 0xFFFF0000u);
  lo = (unsigned short)(__float_as_uint(l) >> 16);
}
__device__ __forceinline__ void split4(float4 v, unsigned short* hi, unsigned short* lo){
  unsigned short h0,h1,h2,h3,l0,l1,l2,l3;
  splitc(v.x,h0,l0); splitc(v.y,h1,l1); splitc(v.z,h2,l2); splitc(v.w,h3,l3);
  *(ushort4*)hi = make_ushort4(h0,h1,h2,h3);
  *(ushort4*)lo = make_ushort4(l0,l1,l2,l3);
}

// ---------------- weight split (flat) ----------------
__global__ __launch_bounds__(256) void split_k(const float* __restrict__ src,
    unsigned short* __restrict__ hi, unsigned short* __restrict__ lo, int n4){
  for (int i = blockIdx.x*256 + threadIdx.x; i < n4; i += gridDim.x*256){
    float4 v = ((const float4*)src)[i];
    split4(v, (unsigned short*)((ushort4*)hi + i), (unsigned short*)((ushort4*)lo + i));
  }
}

// qkv interleave split: dst planes laid out [6 layers][1536 rows][512]
__global__ __launch_bounds__(256) void split_qkv_k(const float* __restrict__ q,
    const float* __restrict__ k, const float* __restrict__ v,
    unsigned short* __restrict__ hi, unsigned short* __restrict__ lo){
  const int n4 = 6*QKVS*512/4;
  for (int i = blockIdx.x*256 + threadIdx.x; i < n4; i += gridDim.x*256){
    int e = i << 2;
    int layer = e / 786432;           // 1536*512
    int r = e - layer*786432;
    int which = r >> 18;              // /262144
    int off = r & 262143;
    const float* s = (which==0) ? q : (which==1) ? k : v;
    float4 vv = *(const float4*)(s + (size_t)layer*262144 + off);
    split4(vv, (unsigned short*)((ushort4*)hi + i), (unsigned short*)((ushort4*)lo + i));
  }
}

// ---------------- embed gather ----------------
__global__ __launch_bounds__(128) void embed_k(const int* __restrict__ tok,
    const float* __restrict__ emb, float* __restrict__ x){
  int n = blockIdx.x;
  int t = tok[n];
  ((float4*)(x + ((size_t)n<<9)))[threadIdx.x] =
      ((const float4*)(emb + ((size_t)t<<9)))[threadIdx.x];
}

// ---------------- x *= mask[row] ----------------
__global__ __launch_bounds__(256) void maskmul_k(float* __restrict__ x,
    const float* __restrict__ mask){
  int i = blockIdx.x*256 + threadIdx.x;
  float m = mask[i >> 7];
  float4 v = ((float4*)x)[i];
  v.x*=m; v.y*=m; v.z*=m; v.w*=m;
  ((float4*)x)[i]=v;
}
__global__ __launch_bounds__(256) void maskmul_split_k(float* __restrict__ x,
    const float* __restrict__ mask, unsigned short* __restrict__ xh,
    unsigned short* __restrict__ xl){
  int i = blockIdx.x*256 + threadIdx.x;
  float m = mask[i >> 7];
  float4 v = ((float4*)x)[i];
  v.x*=m; v.y*=m; v.z*=m; v.w*=m;
  ((float4*)x)[i]=v;
  split4(v, (unsigned short*)((ushort4*)xh + i), (unsigned short*)((ushort4*)xl + i));
}

// ---------------- depthwise conv K=5, edge pad, +bias, *mask --------
__global__ __launch_bounds__(128) void dwconv_k(const float* __restrict__ x,
    const float* __restrict__ w, const float* __restrict__ bias,
    const float* __restrict__ mask, float* __restrict__ h){
  int n = blockIdx.x; int b_ = n >> 9, l = n & 511;
  int c0 = threadIdx.x * 4;
  float acc0=bias[c0], acc1=bias[c0+1], acc2=bias[c0+2], acc3=bias[c0+3];
  #pragma unroll
  for (int k=0;k<5;k++){
    int ls = l + k - 2; ls = ls < 0 ? 0 : (ls > 511 ? 511 : ls);
    const float4 xv = *(const float4*)&x[((size_t)(b_*512 + ls) << 9) + c0];
    acc0 += w[(c0+0)*5+k]*xv.x;
    acc1 += w[(c0+1)*5+k]*xv.y;
    acc2 += w[(c0+2)*5+k]*xv.z;
    acc3 += w[(c0+3)*5+k]*xv.w;
  }
  float mm = mask[n];
  float4 o; o.x=acc0*mm; o.y=acc1*mm; o.z=acc2*mm; o.w=acc3*mm;
  *(float4*)&h[((size_t)n << 9) + c0] = o;
}

// ---------------- rowwise LayerNorm over C=512 (optional dual split write) ----
template<bool SPLIT>
__global__ __launch_bounds__(256) void ln_rows(const float* __restrict__ x,
    const float* __restrict__ g, const float* __restrict__ bt,
    float* __restrict__ y, unsigned short* __restrict__ yh,
    unsigned short* __restrict__ yl, int nrows){
  int wid = threadIdx.x >> 6, lane = threadIdx.x & 63;
  int row = blockIdx.x*4 + wid;
  if (row >= nrows) return;
  const float4* xr = (const float4*)(x + ((size_t)row<<9));
  float4 a = xr[lane*2], b = xr[lane*2+1];
  float s = a.x+a.y+a.z+a.w+b.x+b.y+b.z+b.w;
  s = wave_sum(s);
  float m = s * (1.f/512.f);
  float d0=a.x-m,d1=a.y-m,d2=a.z-m,d3=a.w-m,d4=b.x-m,d5=b.y-m,d6=b.z-m,d7=b.w-m;
  float sq = d0*d0+d1*d1+d2*d2+d3*d3+d4*d4+d5*d5+d6*d6+d7*d7;
  sq = wave_sum(sq);
  float var = sq * (1.f/512.f);
  float inv = 1.f/sqrtf(var + 1e-6f);
  const float4* gr = (const float4*)g; const float4* br = (const float4*)bt;
  float4 g0=gr[lane*2], g1=gr[lane*2+1], b0=br[lane*2], b1=br[lane*2+1];
  float4 o0, o1;
  o0.x=d0*inv*g0.x+b0.x; o0.y=d1*inv*g0.y+b0.y; o0.z=d2*inv*g0.z+b0.z; o0.w=d3*inv*g0.w+b0.w;
  o1.x=d4*inv*g1.x+b1.x; o1.y=d5*inv*g1.y+b1.y; o1.z=d6*inv*g1.z+b1.z; o1.w=d7*inv*g1.w+b1.w;
  float4* yr = (float4*)(y + ((size_t)row<<9));
  yr[lane*2]=o0; yr[lane*2+1]=o1;
  if constexpr (SPLIT){
    size_t base = ((size_t)row<<9) + lane*8;
    split4(o0, yh+base,   yl+base);
    split4(o1, yh+base+4, yl+base+4);
  }
}

#define EPI_BIAS 0
#define EPI_SCALE 1
#define EPI_GELU 2
#define EPI_RES 3
#define EPI_RELU_MASK 4
#define EPI_RES_MASK 5
#define EPI_RES_GAMMA_MASK 6
#define EPI_TANH 7
#define EPI_QKV 8

// ---------------- fp32 VALU GEMM (style sk/sv only, 50 rows) ----------------
template<int EPI>
__global__ __launch_bounds__(256) void gemm_nt(
    const float* __restrict__ A, const float* __restrict__ W,
    const float* __restrict__ bias,
    float* __restrict__ Y, int N, int K, int O)
{
  __shared__ float As[16][68];
  __shared__ float Bs[16][68];
  int t = threadIdx.x;
  int tx = t & 15, ty = t >> 4;
  int row0 = blockIdx.y << 6, col0 = blockIdx.x << 6;
  int lr = t >> 2, lk = (t & 3) << 2;
  float acc[4][4] = {};
  int ar = row0 + lr;
  bool arok = ar < N;
  const float* Ap = A + (size_t)(arok ? ar : 0) * K + lk;
  const float* Wp = W + (size_t)(col0 + lr) * K + lk;
  for (int k0 = 0; k0 < K; k0 += 16) {
    float4 av;
    if (arok) av = *(const float4*)(Ap + k0);
    else { av.x=0;av.y=0;av.z=0;av.w=0; }
    float4 bv = *(const float4*)(Wp + k0);
    As[lk+0][lr]=av.x; As[lk+1][lr]=av.y; As[lk+2][lr]=av.z; As[lk+3][lr]=av.w;
    Bs[lk+0][lr]=bv.x; Bs[lk+1][lr]=bv.y; Bs[lk+2][lr]=bv.z; Bs[lk+3][lr]=bv.w;
    __syncthreads();
    #pragma unroll
    for (int k=0;k<16;k++){
      float4 af = *(const float4*)&As[k][ty<<2];
      float4 bf = *(const float4*)&Bs[k][tx<<2];
      float a4[4]={af.x,af.y,af.z,af.w};
      float b4[4]={bf.x,bf.y,bf.z,bf.w};
      #pragma unroll
      for (int i=0;i<4;i++)
        #pragma unroll
        for (int j=0;j<4;j++)
          acc[i][j] += a4[i]*b4[j];
    }
    __syncthreads();
  }
  #pragma unroll
  for (int i=0;i<4;i++){
    int row = row0 + (ty<<2) + i;
    if (row >= N) break;
    int colb = col0 + (tx<<2);
    float vv_[4];
    #pragma unroll
    for (int j=0;j<4;j++){
      float v = acc[i][j] + bias[colb+j];
      if constexpr (EPI==EPI_TANH) v = tanhf(v);
      vv_[j]=v;
    }
    float4 ov; ov.x=vv_[0]; ov.y=vv_[1]; ov.z=vv_[2]; ov.w=vv_[3];
    *(float4*)(Y + (size_t)row*O + colb) = ov;
  }
}

// ---------------- pre-split MFMA GEMM, double-buffered LDS -------------------
// Tile 64(M) x NF*32(N) x 32(K). 4 waves 2x2; wave tile 32 x NF*16.
// NF=4: 128-col blocks (O>=1536). NF=2: 64-col blocks (O=512) -> 2+ blocks/CU.
template<int EPI, bool AMASK, int OUT, int NF>
__global__ __launch_bounds__(256) void gemm_ps(
    const unsigned short* __restrict__ Ah, const unsigned short* __restrict__ Al,
    const unsigned short* __restrict__ Wh, const unsigned short* __restrict__ Wl,
    const float* __restrict__ bias, const float* __restrict__ res,
    const float* __restrict__ gamma, const float* __restrict__ rowmask,
    float* __restrict__ Y, unsigned short* __restrict__ Yh,
    unsigned short* __restrict__ Yl, int K, int O, float scale)
{
  __shared__ unsigned short AhS[2][64][40], AlS[2][64][40];
  __shared__ unsigned short BhS[2][NF*32][40], BlS[2][NF*32][40];
  int t = threadIdx.x;
  int row0 = blockIdx.y << 6;
  int col0 = blockIdx.x << (NF==4 ? 7 : 6);
  int lane = t & 63, wid = t >> 6;
  int wr = wid >> 1, wc = wid & 1;

  int sr = t >> 2, sc = (t & 3) << 3;
  const unsigned short* Ahg = Ah + (size_t)(row0 + sr)*K + sc;
  const unsigned short* Alg = Al + (size_t)(row0 + sr)*K + sc;
  const unsigned short* Bhg = Wh + (size_t)(col0 + sr)*K + sc;
  const unsigned short* Blg = Wl + (size_t)(col0 + sr)*K + sc;
  float am = 1.f;
  if (AMASK) am = rowmask[row0 + sr];

  f32x4 acc[2][NF] = {};
  int nsteps = K >> 5;
  short8v ah_, al_, bh0_, bl0_, bh1_, bl1_;
  // preload step 0
  ah_ = *(const short8v*)(Ahg);
  al_ = *(const short8v*)(Alg);
  bh0_ = *(const short8v*)(Bhg);
  bl0_ = *(const short8v*)(Blg);
  if constexpr (NF==4){
    bh1_ = *(const short8v*)(Bhg + (size_t)64*K);
    bl1_ = *(const short8v*)(Blg + (size_t)64*K);
  }
  if (AMASK && am == 0.f){ ah_ ^= ah_; al_ ^= al_; }
  *(short8v*)&AhS[0][sr][sc] = ah_;
  *(short8v*)&AlS[0][sr][sc] = al_;
  *(short8v*)&BhS[0][sr][sc] = bh0_;
  *(short8v*)&BlS[0][sr][sc] = bl0_;
  if constexpr (NF==4){
    *(short8v*)&BhS[0][sr+64][sc] = bh1_;
    *(short8v*)&BlS[0][sr+64][sc] = bl1_;
  }

  int st = 0;
  for (int s = 0; s < nsteps; ++s){
    if (s+1 < nsteps){
      int ko = (s+1) << 5;
      ah_ = *(const short8v*)(Ahg + ko);
      al_ = *(const short8v*)(Alg + ko);
      bh0_ = *(const short8v*)(Bhg + ko);
      bl0_ = *(const short8v*)(Blg + ko);
      if constexpr (NF==4){
        bh1_ = *(const short8v*)(Bhg + (size_t)64*K + ko);
        bl1_ = *(const short8v*)(Blg + (size_t)64*K + ko);
      }
      if (AMASK && am == 0.f){ ah_ ^= ah_; al_ ^= al_; }
    }
    __syncthreads();                 // buf st fully written
    int fr = lane & 15, fc = (lane >> 4) << 3;
    short8v ahf[2], alf[2], bhf[NF], blf[NF];
    #pragma unroll
    for (int mt=0; mt<2; ++mt){
      int r = (wr<<5) + (mt<<4) + fr;
      ahf[mt] = *(const short8v*)&AhS[st][r][fc];
      alf[mt] = *(const short8v*)&AlS[st][r][fc];
    }
    #pragma unroll
    for (int nt=0; nt<NF; ++nt){
      int r = (NF==4 ? (wc<<6) : (wc<<5)) + (nt<<4) + fr;
      bhf[nt] = *(const short8v*)&BhS[st][r][fc];
      blf[nt] = *(const short8v*)&BlS[st][r][fc];
    }
    #pragma unroll
    for (int mt=0; mt<2; ++mt)
      #pragma unroll
      for (int nt=0; nt<NF; ++nt){
        f32x4 c = acc[mt][nt];
        c = __builtin_amdgcn_mfma_f32_16x16x32_bf16(ahf[mt], bhf[nt], c, 0,0,0);
        c = __builtin_amdgcn_mfma_f32_16x16x32_bf16(ahf[mt], blf[nt], c, 0,0,0);
        c = __builtin_amdgcn_mfma_f32_16x16x32_bf16(alf[mt], bhf[nt], c, 0,0,0);
        acc[mt][nt] = c;
      }
    if (s+1 < nsteps){
      int nb = st ^ 1;               // write NEXT buffer; readers use st
      *(short8v*)&AhS[nb][sr][sc] = ah_;
      *(short8v*)&AlS[nb][sr][sc] = al_;
      *(short8v*)&BhS[nb][sr][sc] = bh0_;
      *(short8v*)&BlS[nb][sr][sc] = bl0_;
      if constexpr (NF==4){
        *(short8v*)&BhS[nb][sr+64][sc] = bh1_;
        *(short8v*)&BlS[nb][sr+64][sc] = bl1_;
      }
    }
    st ^= 1;
  }

  int rb = row0 + (wr<<5) + ((lane>>4)<<2);
  int cb = col0 + (NF==4 ? (wc<<6) : (wc<<5)) + (lane & 15);
  float bs[NF], gm[NF];
  #pragma unroll
  for (int nt=0; nt<NF; ++nt){
    int col = cb + (nt<<4);
    if constexpr (EPI==EPI_QKV){
      int which = blockIdx.x >> 2;
      const float* bp = (which==0) ? bias : (which==1) ? res : gamma;
      bs[nt] = bp[col & 511];
    } else {
      bs[nt] = bias[col];
      if constexpr (EPI==EPI_RES_GAMMA_MASK) gm[nt] = gamma[col];
    }
  }
  float qscale = 1.f;
  if constexpr (EPI==EPI_QKV) qscale = ((blockIdx.x>>2)==0) ? scale : 1.f;
  #pragma unroll
  for (int mt=0; mt<2; ++mt)
    #pragma unroll
    for (int j=0; j<4; ++j){
      int row = rb + (mt<<4) + j;
      float rm = 1.f;
      if constexpr (EPI==EPI_RELU_MASK || EPI==EPI_RES_MASK || EPI==EPI_RES_GAMMA_MASK)
        rm = rowmask[row];
      const float* rr = nullptr;
      if constexpr (EPI==EPI_RES || EPI==EPI_RES_MASK || EPI==EPI_RES_GAMMA_MASK)
        rr = res + (size_t)row*O + cb;
      #pragma unroll
      for (int nt=0; nt<NF; ++nt){
        float v = acc[mt][nt][j] + bs[nt];
        if constexpr (EPI==EPI_SCALE) v *= scale;
        else if constexpr (EPI==EPI_QKV) v *= qscale;
        else if constexpr (EPI==EPI_GELU) v = 0.5f*v*(1.f+erff(v*0.7071067811865475f));
        else if constexpr (EPI==EPI_RES) v = rr[nt<<4] + v;
        else if constexpr (EPI==EPI_RELU_MASK) v = fmaxf(v,0.f)*rm;
        else if constexpr (EPI==EPI_RES_MASK) v = rr[nt<<4] + v*rm;
        else if constexpr (EPI==EPI_RES_GAMMA_MASK) v = (rr[nt<<4] + gm[nt]*v)*rm;
        size_t oidx = (size_t)row*O + cb + (nt<<4);
        if constexpr (OUT==0) Y[oidx] = v;
        else { unsigned short h,l; splitc(v,h,l); Yh[oidx]=h; Yl[oidx]=l; }
      }
    }
}

// ---------------- V transpose: planes [N][1536] cols 1024.. -> VT[b][512d][512tok]
__global__ __launch_bounds__(256) void transpose_v_k(
    const unsigned short* __restrict__ Vh, const unsigned short* __restrict__ Vl,
    unsigned short* __restrict__ VTh, unsigned short* __restrict__ VTl){
  __shared__ unsigned short t0[64][72];
  __shared__ unsigned short t1[64][72];
  int dt = blockIdx.x, tb = blockIdx.y, b = blockIdx.z;
  int t = threadIdx.x;
  int r = t >> 3, c = (t & 7) << 3;   // r 0..31
  #pragma unroll
  for (int rep = 0; rep < 2; ++rep){
    int rr = rep*32 + r;
    size_t g = ((size_t)b*512 + tb*64 + rr)*QKVS + 1024 + dt*64 + c;
    *(short8v*)&t0[rr][c] = *(const short8v*)&Vh[g];
    *(short8v*)&t1[rr][c] = *(const short8v*)&Vl[g];
  }
  __syncthreads();
  #pragma unroll
  for (int rep = 0; rep < 2; ++rep){
    int rr = rep*32 + r;   // out row: d-local
    short8v vh_, vl_;
    #pragma unroll
    for (int i = 0; i < 8; ++i){ vh_[i] = (short)t0[c+i][rr]; vl_[i] = (short)t1[c+i][rr]; }
    size_t g = ((size_t)b*512 + dt*64 + rr)*512 + tb*64 + c;
    *(short8v*)&VTh[g] = vh_;
    *(short8v*)&VTl[g] = vl_;
  }
}

// ---------------- MFMA windowed-rel attention (reg-resident scores) ----------
// Block = (16 q-rows, b,h), 4 waves; wave w owns score cols / out dims [w*16,w*16+16).
// Scores stay fp32 in sreg[8] (static idx); P planes written to LDS once for AV.
__global__ __launch_bounds__(256) void attn_mf(
    const unsigned short* __restrict__ Ph_g, const unsigned short* __restrict__ Pl_g,
    const unsigned short* __restrict__ VTh_g, const unsigned short* __restrict__ VTl_g,
    const float* __restrict__ relk, const float* __restrict__ relv,
    const float* __restrict__ mask, unsigned short* __restrict__ Oh,
    unsigned short* __restrict__ Ol)
{
  __shared__ float ms_[512];
  __shared__ float rk[9][64];
  __shared__ float rv[9][64];
  __shared__ unsigned short Qh[16][72], Ql[16][72];
  __shared__ float qrel[16][12];
  __shared__ unsigned short Kh[64][72], Kl[64][72];
  __shared__ unsigned short Sh[16][520], Sl[16][520];
  __shared__ float red1[4][16];   // per-wave max partials
  __shared__ float red2[4][16];   // per-wave sum partials

  int qt = blockIdx.x, bh = blockIdx.y;
  int h = bh & 7, b_ = bh >> 3;
  int t = threadIdx.x;
  int l0 = qt * 16;
  const size_t rowoff = (size_t)b_ * 512;
  int lane = t & 63, w = t >> 6;

  ms_[t] = mask[rowoff + t]; ms_[t+256] = mask[rowoff + t + 256];
  for (int i = t; i < 576; i += 256){ ((float*)rk)[i] = relk[i]; ((float*)rv)[i] = relv[i]; }
  {
    int idx = t & 127; int r = idx >> 3, c = (idx & 7) << 3;
    size_t g = (rowoff + l0 + r)*QKVS + h*64 + c;
    if (t < 128) *(short8v*)&Qh[r][c] = *(const short8v*)&Ph_g[g];
    else         *(short8v*)&Ql[r][c] = *(const short8v*)&Pl_g[g];
  }
  __syncthreads();
  if (t < 144){
    int dlt = t >> 4, q_ = t & 15;
    float s = 0.f;
    for (int d = 0; d < 64; ++d){
      float qf = bf2f(Qh[q_][d]) + bf2f(Ql[q_][d]);
      s += qf * rk[dlt][d];
    }
    qrel[q_][dlt] = s;
  }

  int fr = lane & 15, fc = (lane >> 4) << 3;
  int qbase = (lane>>4) << 2;          // this thread's 4 queries: qbase..qbase+3
  f32x4 sreg[8];
  // ---- QK over 8 tiles of 64 keys; scores stay in registers ----
  #pragma unroll
  for (int tt = 0; tt < 8; ++tt){
    __syncthreads();
    #pragma unroll
    for (int rep = 0; rep < 2; ++rep){
      int idx = rep*256 + t; int r = idx >> 3, c = (idx & 7) << 3;
      size_t g = (rowoff + tt*64 + r)*QKVS + 512 + h*64 + c;
      *(short8v*)&Kh[r][c] = *(const short8v*)&Ph_g[g];
      *(short8v*)&Kl[r][c] = *(const short8v*)&Pl_g[g];
    }
    __syncthreads();
    short8v ah0 = *(const short8v*)&Qh[fr][fc];
    short8v ah1 = *(const short8v*)&Qh[fr][32+fc];
    short8v al0 = *(const short8v*)&Ql[fr][fc];
    short8v al1 = *(const short8v*)&Ql[fr][32+fc];
    int br = w*16 + fr;
    short8v bh0 = *(const short8v*)&Kh[br][fc];
    short8v bh1 = *(const short8v*)&Kh[br][32+fc];
    short8v bl0 = *(const short8v*)&Kl[br][fc];
    short8v bl1 = *(const short8v*)&Kl[br][32+fc];
    f32x4 c4 = {};
    c4 = __builtin_amdgcn_mfma_f32_16x16x32_bf16(ah0,bh0,c4,0,0,0);
    c4 = __builtin_amdgcn_mfma_f32_16x16x32_bf16(ah1,bh1,c4,0,0,0);
    c4 = __builtin_amdgcn_mfma_f32_16x16x32_bf16(ah0,bl0,c4,0,0,0);
    c4 = __builtin_amdgcn_mfma_f32_16x16x32_bf16(ah1,bl1,c4,0,0,0);
    c4 = __builtin_amdgcn_mfma_f32_16x16x32_bf16(al0,bh0,c4,0,0,0);
    c4 = __builtin_amdgcn_mfma_f32_16x16x32_bf16(al1,bh1,c4,0,0,0);
    int m = tt*64 + w*16 + fr;
    float mm_ = ms_[m];
    #pragma unroll
    for (int j = 0; j < 4; ++j){
      int q = qbase + j;
      int l = l0 + q;
      float s = c4[j];
      int dlt = m - l + 4;
      if (dlt >= 0 && dlt <= 8) s += qrel[q][dlt];
      if (ms_[l] * mm_ == 0.f) s = -10000.f;
      c4[j] = s;
    }
    sreg[tt] = c4;
  }

  // ---- softmax: 16-lane shfl + cross-wave LDS partials; all fp32 -----------
  float mx[4], sm[4], inv[4];
  #pragma unroll
  for (int j = 0; j < 4; ++j){
    float v = sreg[0][j];
    #pragma unroll
    for (int tt = 1; tt < 8; ++tt) v = fmaxf(v, sreg[tt][j]);
    #pragma unroll
    for (int o = 8; o >= 1; o >>= 1) v = fmaxf(v, __shfl_xor(v, o));
    mx[j] = v;
  }
  if (fr == 0){
    #pragma unroll
    for (int j = 0; j < 4; ++j) red1[w][qbase + j] = mx[j];
  }
  __syncthreads();
  #pragma unroll
  for (int j = 0; j < 4; ++j){
    int q = qbase + j;
    mx[j] = fmaxf(fmaxf(red1[0][q], red1[1][q]), fmaxf(red1[2][q], red1[3][q]));
  }
  #pragma unroll
  for (int j = 0; j < 4; ++j) sm[j] = 0.f;
  #pragma unroll
  for (int tt = 0; tt < 8; ++tt){
    f32x4 c4 = sreg[tt];
    #pragma unroll
    for (int j = 0; j < 4; ++j){
      float e = expf(c4[j] - mx[j]);
      c4[j] = e;
      sm[j] += e;
    }
    sreg[tt] = c4;
  }
  #pragma unroll
  for (int j = 0; j < 4; ++j){
    float v = sm[j];
    #pragma unroll
    for (int o = 8; o >= 1; o >>= 1) v += __shfl_xor(v, o);
    sm[j] = v;
  }
  if (fr == 0){
    #pragma unroll
    for (int j = 0; j < 4; ++j) red2[w][qbase + j] = sm[j];
  }
  // write P planes (unnormalized) while sums propagate
  #pragma unroll
  for (int tt = 0; tt < 8; ++tt){
    int m = tt*64 + w*16 + fr;
    #pragma unroll
    for (int j = 0; j < 4; ++j){
      unsigned short hh, ll_;
      splitc(sreg[tt][j], hh, ll_);
      Sh[qbase + j][m] = hh; Sl[qbase + j][m] = ll_;
    }
  }
  __syncthreads();
  #pragma unroll
  for (int j = 0; j < 4; ++j){
    int q = qbase + j;
    inv[j] = 1.f / (red2[0][q] + red2[1][q] + red2[2][q] + red2[3][q]);
  }

  // ---- AV over 8 tiles of 64 keys (VT staged: rows = d, cols = token) ----
  f32x4 oacc = {};
  for (int tt = 0; tt < 8; ++tt){
    __syncthreads();
    #pragma unroll
    for (int rep = 0; rep < 2; ++rep){
      int idx = rep*256 + t; int r = idx >> 3, c = (idx & 7) << 3;
      size_t g = ((size_t)b_*512 + h*64 + r)*512 + tt*64 + c;
      *(short8v*)&Kh[r][c] = *(const short8v*)&VTh_g[g];
      *(short8v*)&Kl[r][c] = *(const short8v*)&VTl_g[g];
    }
    __syncthreads();
    #pragma unroll
    for (int ks = 0; ks < 2; ++ks){
      int moff = tt*64 + ks*32 + fc;
      short8v ah = *(const short8v*)&Sh[fr][moff];
      short8v al = *(const short8v*)&Sl[fr][moff];
      int br = w*16 + fr;
      short8v bh = *(const short8v*)&Kh[br][ks*32 + fc];
      short8v bl = *(const short8v*)&Kl[br][ks*32 + fc];
      oacc = __builtin_amdgcn_mfma_f32_16x16x32_bf16(ah,bh,oacc,0,0,0);
      oacc = __builtin_amdgcn_mfma_f32_16x16x32_bf16(ah,bl,oacc,0,0,0);
      oacc = __builtin_amdgcn_mfma_f32_16x16x32_bf16(al,bh,oacc,0,0,0);
    }
  }
  // ---- epilogue: rel_v window + normalize, write output planes ----
  {
    int d = w*16 + fr;
    #pragma unroll
    for (int j = 0; j < 4; ++j){
      int q = qbase + j;
      int l = l0 + q;
      float val = oacc[j];
      #pragma unroll
      for (int dlt = 0; dlt < 9; ++dlt){
        int m = l + dlt - 4;
        if (m >= 0 && m < 512){
          float e = bf2f(Sh[q][m]) + bf2f(Sl[q][m]);
          val += e * rv[dlt][d];
        }
      }
      val *= inv[j];
      unsigned short hh, ll_; splitc(val, hh, ll_);
      size_t oidx = ((rowoff + l) << 9) + h*64 + d;
      Oh[oidx] = hh; Ol[oidx] = ll_;
    }
  }
}

// ---------------- style attention (split out) ----------------
__global__ __launch_bounds__(128) void style_attn_k(const float* __restrict__ Q,
    const float* __restrict__ kk, const float* __restrict__ vv,
    const float* __restrict__ mask, unsigned short* __restrict__ Oh,
    unsigned short* __restrict__ Ol){
  int n = blockIdx.x;
  int h = threadIdx.x >> 6, lane = threadIdx.x & 63;
  __shared__ float qh[512];
  __shared__ float aw[2][64];
  {
    float4 v = ((const float4*)(Q + ((size_t)n<<9)))[threadIdx.x];
    *(float4*)&qh[threadIdx.x*4] = v;
  }
  __syncthreads();
  float sc;
  if (lane < 50){
    float s = 0.f;
    const float* kr = kk + lane*512 + h*256;
    const float* qr = qh + h*256;
    for (int d4 = 0; d4 < 64; ++d4){
      float4 kv = *(const float4*)&kr[d4*4];
      s += qr[d4*4]*kv.x + qr[d4*4+1]*kv.y + qr[d4*4+2]*kv.z + qr[d4*4+3]*kv.w;
    }
    sc = s * 0.044194173824159216f;
  } else sc = -1e30f;
  float mx = wave_max(sc);
  float ex = (lane < 50) ? expf(sc - mx) : 0.f;
  float sm = wave_sum(ex);
  float keep = (mask[n] == 0.f) ? 0.f : 1.f;
  aw[h][lane] = ex / sm * keep;
  __syncthreads();
  float4 acc; acc.x=0; acc.y=0; acc.z=0; acc.w=0;
  const float* vb = vv + h*256 + lane*4;
  for (int s = 0; s < 50; ++s){
    float a = aw[h][s];
    const float4 vvv = *(const float4*)&vb[(size_t)s*512];
    acc.x += a*vvv.x; acc.y += a*vvv.y; acc.z += a*vvv.z; acc.w += a*vvv.w;
  }
  size_t oidx = ((size_t)n<<9) + h*256 + lane*4;
  split4(acc, Oh+oidx, Ol+oidx);
}

// ---------------- final transpose ----------------
__global__ __launch_bounds__(256) void transpose_out_k(const float* __restrict__ xn,
    const float* __restrict__ mask, float* __restrict__ out){
  __shared__ float tile[32][33];
  int b_ = blockIdx.z; int c0 = blockIdx.x*32; int l0 = blockIdx.y*32;
  int tx = threadIdx.x & 31, ty = threadIdx.x >> 5;
  #pragma unroll
  for (int r=0;r<4;r++){
    int l = l0 + ty + r*8;
    tile[ty + r*8][tx] = xn[(((size_t)(b_*512 + l))<<9) + c0 + tx];
  }
  __syncthreads();
  float mm = mask[b_*512 + l0 + tx];
  #pragma unroll
  for (int r=0;r<4;r++){
    int c = c0 + ty + r*8;
    out[(((size_t)(b_*512 + c))<<9) + l0 + tx] = tile[tx][ty + r*8] * mm;
  }
}

extern "C" void kernel_launch(void* const* d_in, const int* in_sizes, int n_in,
                              void* d_out, int out_size, void* d_ws, size_t ws_size,
                              hipStream_t stream) {
  const int*   tokens   = (const int*)  d_in[0];
  const float* style_v  = (const float*)d_in[1];
  const float* mask     = (const float*)d_in[2];
  const float* embed_w  = (const float*)d_in[3];
  const float* cw_dw_w  = (const float*)d_in[4];
  const float* cw_dw_b  = (const float*)d_in[5];
  const float* cw_ln_g  = (const float*)d_in[6];
  const float* cw_ln_b  = (const float*)d_in[7];
  const float* cw_pw1_w = (const float*)d_in[8];
  const float* cw_pw1_b = (const float*)d_in[9];
  const float* cw_pw2_w = (const float*)d_in[10];
  const float* cw_pw2_b = (const float*)d_in[11];
  const float* cw_gamma = (const float*)d_in[12];
  const float* aq_w = (const float*)d_in[13];
  const float* aq_b = (const float*)d_in[14];
  const float* ak_w = (const float*)d_in[15];
  const float* ak_b = (const float*)d_in[16];
  const float* av_w = (const float*)d_in[17];
  const float* av_b = (const float*)d_in[18];
  const float* ao_w = (const float*)d_in[19];
  const float* ao_b = (const float*)d_in[20];
  const float* rel_k = (const float*)d_in[21];
  const float* rel_v = (const float*)d_in[22];
  const float* ln1_g = (const float*)d_in[23];
  const float* ln1_b = (const float*)d_in[24];
  const float* ln2_g = (const float*)d_in[25];
  const float* ln2_b = (const float*)d_in[26];
  const float* ffn_w1 = (const float*)d_in[27];
  const float* ffn_b1 = (const float*)d_in[28];
  const float* ffn_w2 = (const float*)d_in[29];
  const float* ffn_b2 = (const float*)d_in[30];
  const float* style_key = (const float*)d_in[31];
  const float* sq_w = (const float*)d_in[32];
  const float* sq_b = (const float*)d_in[33];
  const float* sk_w = (const float*)d_in[34];
  const float* sk_b = (const float*)d_in[35];
  const float* sv_w = (const float*)d_in[36];
  const float* sv_b = (const float*)d_in[37];
  const float* so_w = (const float*)d_in[38];
  const float* so_b = (const float*)d_in[39];
  const float* sn_g = (const float*)d_in[40];
  const float* sn_b = (const float*)d_in[41];

  const int N = NROWS;
  char* cur = (char*)d_ws;
  auto nextF = [&](size_t n)->float*{ float* p=(float*)cur; cur += n*sizeof(float); return p; };
  auto nextU = [&](size_t n)->unsigned short*{ unsigned short* p=(unsigned short*)cur; cur += n*2; return p; };

  float* X   = nextF((size_t)N*512);
  float* T   = nextF((size_t)N*512);
  float* Qb  = nextF((size_t)N*512);
  float* Vb  = nextF((size_t)N*512);
  float* KK  = nextF(2*50*512);
  float* VV  = nextF(2*50*512);
  unsigned short* Xh = nextU((size_t)N*512);
  unsigned short* Xl = nextU((size_t)N*512);
  unsigned short* Th = nextU((size_t)N*512);
  unsigned short* Tl = nextU((size_t)N*512);
  unsigned short* Hbh = nextU((size_t)N*2048);
  unsigned short* Hbl = nextU((size_t)N*2048);
  unsigned short* QKVh = nextU((size_t)N*QKVS);
  unsigned short* QKVl = nextU((size_t)N*QKVS);
  unsigned short* VTh = nextU((size_t)8*512*512);
  unsigned short* VTl = nextU((size_t)8*512*512);
  // weight planes
  unsigned short* pw1h = nextU(4194304); unsigned short* pw1l = nextU(4194304);
  unsigned short* pw2h = nextU(4194304); unsigned short* pw2l = nextU(4194304);
  unsigned short* qkvh = nextU((size_t)6*QKVS*512); unsigned short* qkvl = nextU((size_t)6*QKVS*512);
  unsigned short* aoh  = nextU(1572864); unsigned short* aol  = nextU(1572864);
  unsigned short* f1h  = nextU(6291456); unsigned short* f1l  = nextU(6291456);
  unsigned short* f2h  = nextU(6291456); unsigned short* f2l  = nextU(6291456);
  unsigned short* sqh  = nextU(524288);  unsigned short* sql  = nextU(524288);
  unsigned short* soh  = nextU(524288);  unsigned short* sol  = nextU(524288);

  // ---- weight prep ----
  split_k<<<1024,256,0,stream>>>(cw_pw1_w, pw1h, pw1l, 4194304/4);
  split_k<<<1024,256,0,stream>>>(cw_pw2_w, pw2h, pw2l, 4194304/4);
  split_qkv_k<<<1024,256,0,stream>>>(aq_w, ak_w, av_w, qkvh, qkvl);
  split_k<<<1024,256,0,stream>>>(ao_w, aoh, aol, 1572864/4);
  split_k<<<1024,256,0,stream>>>(ffn_w1, f1h, f1l, 6291456/4);
  split_k<<<1024,256,0,stream>>>(ffn_w2, f2h, f2l, 6291456/4);
  split_k<<<512,256,0,stream>>>(sq_w, sqh, sql, 524288/4);
  split_k<<<512,256,0,stream>>>(so_w, soh, sol, 524288/4);

  dim3 gm512(8,64), gm2048(16,64), gmqkv(12,64), gS(8,1);

  embed_k<<<4096,128,0,stream>>>(tokens, embed_w, X);

  // ---- ConvNeXt blocks ----
  for (int i=0;i<4;i++){
    maskmul_k<<<2048,256,0,stream>>>(X, mask);
    dwconv_k<<<4096,128,0,stream>>>(X, cw_dw_w + (size_t)i*512*5, cw_dw_b + i*512, mask, T);
    ln_rows<true><<<1024,256,0,stream>>>(T, cw_ln_g+i*512, cw_ln_b+i*512, T, Th, Tl, N);
    gemm_ps<EPI_GELU,false,1,4><<<gm2048,256,0,stream>>>(Th, Tl,
        pw1h + (size_t)i*1048576, pw1l + (size_t)i*1048576,
        cw_pw1_b+i*2048, nullptr, nullptr, nullptr, nullptr, Hbh, Hbl, 512, 2048, 0.f);
    gemm_ps<EPI_RES_GAMMA_MASK,false,0,2><<<gm512,256,0,stream>>>(Hbh, Hbl,
        pw2h + (size_t)i*1048576, pw2l + (size_t)i*1048576,
        cw_pw2_b+i*512, X, cw_gamma+i*512, mask, X, nullptr, nullptr, 2048, 512, 0.f);
  }
  maskmul_split_k<<<2048,256,0,stream>>>(X, mask, Xh, Xl);

  // ---- Attention layers ----
  for (int i=0;i<6;i++){
    gemm_ps<EPI_QKV,false,1,4><<<gmqkv,256,0,stream>>>(Xh, Xl,
        qkvh + (size_t)i*QKVS*512, qkvl + (size_t)i*QKVS*512,
        aq_b+i*512, ak_b+i*512, av_b+i*512, nullptr, nullptr, QKVh, QKVl,
        512, QKVS, 0.125f);
    transpose_v_k<<<dim3(8,8,8),256,0,stream>>>(QKVh, QKVl, VTh, VTl);
    attn_mf<<<dim3(32,64),256,0,stream>>>(QKVh, QKVl, VTh, VTl,
        rel_k + (size_t)i*9*64, rel_v + (size_t)i*9*64, mask, Th, Tl);
    gemm_ps<EPI_RES,false,0,2><<<gm512,256,0,stream>>>(Th, Tl,
        aoh + (size_t)i*262144, aol + (size_t)i*262144,
        ao_b+i*512, X, nullptr, nullptr, Qb, nullptr, nullptr, 512, 512, 0.f);
    ln_rows<true><<<1024,256,0,stream>>>(Qb, ln1_g+i*512, ln1_b+i*512, X, Xh, Xl, N);
    gemm_ps<EPI_RELU_MASK,true,1,4><<<gm2048,256,0,stream>>>(Xh, Xl,
        f1h + (size_t)i*1048576, f1l + (size_t)i*1048576,
        ffn_b1+i*2048, nullptr, nullptr, mask, nullptr, Hbh, Hbl, 512, 2048, 0.f);
    gemm_ps<EPI_RES_MASK,false,0,2><<<gm512,256,0,stream>>>(Hbh, Hbl,
        f2h + (size_t)i*1048576, f2l + (size_t)i*1048576,
        ffn_b2+i*512, X, nullptr, mask, Qb, nullptr, nullptr, 2048, 512, 0.f);
    ln_rows<true><<<1024,256,0,stream>>>(Qb, ln2_g+i*512, ln2_b+i*512, X, Xh, Xl, N);
  }
  maskmul_split_k<<<2048,256,0,stream>>>(X, mask, Xh, Xl);

  // ---- Style attention ----
  gemm_nt<EPI_TANH><<<gS,256,0,stream>>>(style_key, sk_w, sk_b, KK, 50,512,512);
  gemm_nt<EPI_TANH><<<gS,256,0,stream>>>(style_key, sk_w+262144, sk_b+512, KK+25600, 50,512,512);
  gemm_nt<EPI_BIAS><<<gS,256,0,stream>>>(style_v, sv_w, sv_b, VV, 50,512,512);
  gemm_nt<EPI_BIAS><<<gS,256,0,stream>>>(style_v, sv_w+262144, sv_b+512, VV+25600, 50,512,512);

  // layer 0: xin = masked X
  gemm_ps<EPI_BIAS,false,0,2><<<gm512,256,0,stream>>>(Xh, Xl, sqh, sql,
      sq_b, nullptr, nullptr, nullptr, Qb, nullptr, nullptr, 512, 512, 0.f);
  style_attn_k<<<4096,128,0,stream>>>(Qb, KK, VV, mask, Th, Tl);
  gemm_ps<EPI_RES_MASK,false,1,2><<<gm512,256,0,stream>>>(Th, Tl, soh, sol,
      so_b, X, nullptr, mask, nullptr, Hbh, Hbl, 512, 512, 0.f);   // x1 planes
  // layer 1: xin = x1 (planes); residual xt = X
  gemm_ps<EPI_BIAS,false,0,2><<<gm512,256,0,stream>>>(Hbh, Hbl, sqh+262144, sql+262144,
      sq_b+512, nullptr, nullptr, nullptr, Qb, nullptr, nullptr, 512, 512, 0.f);
  style_attn_k<<<4096,128,0,stream>>>(Qb, KK+25600, VV+25600, mask, Th, Tl);
  gemm_ps<EPI_RES_MASK,false,0,2><<<gm512,256,0,stream>>>(Th, Tl, soh+262144, sol+262144,
      so_b+512, X, nullptr, mask, Vb, nullptr, nullptr, 512, 512, 0.f);  // x2

  ln_rows<false><<<1024,256,0,stream>>>(Vb, sn_g, sn_b, Qb, nullptr, nullptr, N);
  transpose_out_k<<<dim3(16,16,8),256,0,stream>>>(Qb, mask, (float*)d_out);
}

// Round 10
// 2146.224 us; speedup vs baseline: 9.1221x; 1.0355x over previous
//
#include <hip/hip_runtime.h>
#include <cstdint>

#define Bb 8
#define Ll 512
#define Cc 512
#define Hh 8
#define HD 64
#define Ff 2048
#define Ss 50
#define NROWS 4096   // B*L
#define QKVS 1536

typedef __attribute__((ext_vector_type(8))) short short8v;  // 8 bf16 (4 VGPR)
typedef __attribute__((ext_vector_type(4))) float f32x4;

__device__ __forceinline__ float wave_sum(float v){
  #pragma unroll
  for (int o=32;o>=1;o>>=1) v += __shfl_xor(v,o);
  return v;
}
__device__ __forceinline__ float wave_max(float v){
  #pragma unroll
  for (int o=32;o>=1;o>>=1) v = fmaxf(v,__shfl_xor(v,o));
  return v;
}
__device__ __forceinline__ float bf2f(unsigned short u){
  return __uint_as_float(((unsigned)u) << 16);
}

// cheap split: hi = trunc-bf16(a); lo = trunc-bf16(a - hi). err ~ 2^-16 |a|
__device__ __forceinline__ void splitc(float a, unsigned short& hi, unsigned short& lo){
  unsigned u = __float_as_uint(a);
  hi = (unsigned short)(u >> 16);
  float l = a - __uint_as_float(u & 0xFFFF0000u);
  lo = (unsigned short)(__float_as_uint(l) >> 16);
}
__device__ __forceinline__ void split4(float4 v, unsigned short* hi, unsigned short* lo){
  unsigned short h0,h1,h2,h3,l0,l1,l2,l3;
  splitc(v.x,h0,l0); splitc(v.y,h1,l1); splitc(v.z,h2,l2); splitc(v.w,h3,l3);
  *(ushort4*)hi = make_ushort4(h0,h1,h2,h3);
  *(ushort4*)lo = make_ushort4(l0,l1,l2,l3);
}

// ---------------- weight split (flat) ----------------
__global__ __launch_bounds__(256) void split_k(const float* __restrict__ src,
    unsigned short* __restrict__ hi, unsigned short* __restrict__ lo, int n4){
  for (int i = blockIdx.x*256 + threadIdx.x; i < n4; i += gridDim.x*256){
    float4 v = ((const float4*)src)[i];
    split4(v, (unsigned short*)((ushort4*)hi + i), (unsigned short*)((ushort4*)lo + i));
  }
}

// qkv interleave split: dst planes laid out [6 layers][1536 rows][512]
__global__ __launch_bounds__(256) void split_qkv_k(const float* __restrict__ q,
    const float* __restrict__ k, const float* __restrict__ v,
    unsigned short* __restrict__ hi, unsigned short* __restrict__ lo){
  const int n4 = 6*QKVS*512/4;
  for (int i = blockIdx.x*256 + threadIdx.x; i < n4; i += gridDim.x*256){
    int e = i << 2;
    int layer = e / 786432;           // 1536*512
    int r = e - layer*786432;
    int which = r >> 18;              // /262144
    int off = r & 262143;
    const float* s = (which==0) ? q : (which==1) ? k : v;
    float4 vv = *(const float4*)(s + (size_t)layer*262144 + off);
    split4(vv, (unsigned short*)((ushort4*)hi + i), (unsigned short*)((ushort4*)lo + i));
  }
}

// ---------------- embed gather (mask fused) ----------------
__global__ __launch_bounds__(128) void embed_k(const int* __restrict__ tok,
    const float* __restrict__ emb, const float* __restrict__ mask,
    float* __restrict__ x){
  int n = blockIdx.x;
  int t = tok[n];
  float m = mask[n];
  float4 v = ((const float4*)(emb + ((size_t)t<<9)))[threadIdx.x];
  v.x*=m; v.y*=m; v.z*=m; v.w*=m;
  ((float4*)(x + ((size_t)n<<9)))[threadIdx.x] = v;
}

// masked + dual split write (X already masked -> idempotent, still splits)
__global__ __launch_bounds__(256) void maskmul_split_k(float* __restrict__ x,
    const float* __restrict__ mask, unsigned short* __restrict__ xh,
    unsigned short* __restrict__ xl){
  int i = blockIdx.x*256 + threadIdx.x;
  float m = mask[i >> 7];
  float4 v = ((float4*)x)[i];
  v.x*=m; v.y*=m; v.z*=m; v.w*=m;
  ((float4*)x)[i]=v;
  split4(v, (unsigned short*)((ushort4*)xh + i), (unsigned short*)((ushort4*)xl + i));
}

// ---------------- depthwise conv K=5, edge pad, +bias, *mask --------
__global__ __launch_bounds__(128) void dwconv_k(const float* __restrict__ x,
    const float* __restrict__ w, const float* __restrict__ bias,
    const float* __restrict__ mask, float* __restrict__ h){
  int n = blockIdx.x; int b_ = n >> 9, l = n & 511;
  int c0 = threadIdx.x * 4;
  float acc0=bias[c0], acc1=bias[c0+1], acc2=bias[c0+2], acc3=bias[c0+3];
  #pragma unroll
  for (int k=0;k<5;k++){
    int ls = l + k - 2; ls = ls < 0 ? 0 : (ls > 511 ? 511 : ls);
    const float4 xv = *(const float4*)&x[((size_t)(b_*512 + ls) << 9) + c0];
    acc0 += w[(c0+0)*5+k]*xv.x;
    acc1 += w[(c0+1)*5+k]*xv.y;
    acc2 += w[(c0+2)*5+k]*xv.z;
    acc3 += w[(c0+3)*5+k]*xv.w;
  }
  float mm = mask[n];
  float4 o; o.x=acc0*mm; o.y=acc1*mm; o.z=acc2*mm; o.w=acc3*mm;
  *(float4*)&h[((size_t)n << 9) + c0] = o;
}

// ---------------- rowwise LayerNorm over C=512 (optional dual split write) ----
template<bool SPLIT>
__global__ __launch_bounds__(256) void ln_rows(const float* __restrict__ x,
    const float* __restrict__ g, const float* __restrict__ bt,
    float* __restrict__ y, unsigned short* __restrict__ yh,
    unsigned short* __restrict__ yl, int nrows){
  int wid = threadIdx.x >> 6, lane = threadIdx.x & 63;
  int row = blockIdx.x*4 + wid;
  if (row >= nrows) return;
  const float4* xr = (const float4*)(x + ((size_t)row<<9));
  float4 a = xr[lane*2], b = xr[lane*2+1];
  float s = a.x+a.y+a.z+a.w+b.x+b.y+b.z+b.w;
  s = wave_sum(s);
  float m = s * (1.f/512.f);
  float d0=a.x-m,d1=a.y-m,d2=a.z-m,d3=a.w-m,d4=b.x-m,d5=b.y-m,d6=b.z-m,d7=b.w-m;
  float sq = d0*d0+d1*d1+d2*d2+d3*d3+d4*d4+d5*d5+d6*d6+d7*d7;
  sq = wave_sum(sq);
  float var = sq * (1.f/512.f);
  float inv = 1.f/sqrtf(var + 1e-6f);
  const float4* gr = (const float4*)g; const float4* br = (const float4*)bt;
  float4 g0=gr[lane*2], g1=gr[lane*2+1], b0=br[lane*2], b1=br[lane*2+1];
  float4 o0, o1;
  o0.x=d0*inv*g0.x+b0.x; o0.y=d1*inv*g0.y+b0.y; o0.z=d2*inv*g0.z+b0.z; o0.w=d3*inv*g0.w+b0.w;
  o1.x=d4*inv*g1.x+b1.x; o1.y=d5*inv*g1.y+b1.y; o1.z=d6*inv*g1.z+b1.z; o1.w=d7*inv*g1.w+b1.w;
  float4* yr = (float4*)(y + ((size_t)row<<9));
  yr[lane*2]=o0; yr[lane*2+1]=o1;
  if constexpr (SPLIT){
    size_t base = ((size_t)row<<9) + lane*8;
    split4(o0, yh+base,   yl+base);
    split4(o1, yh+base+4, yl+base+4);
  }
}

#define EPI_BIAS 0
#define EPI_SCALE 1
#define EPI_GELU 2
#define EPI_RES 3
#define EPI_RELU_MASK 4
#define EPI_RES_MASK 5
#define EPI_RES_GAMMA_MASK 6
#define EPI_TANH 7
#define EPI_QKV 8

// ---------------- fp32 VALU GEMM (style sk/sv only, 50 rows) ----------------
template<int EPI>
__global__ __launch_bounds__(256) void gemm_nt(
    const float* __restrict__ A, const float* __restrict__ W,
    const float* __restrict__ bias,
    float* __restrict__ Y, int N, int K, int O)
{
  __shared__ float As[16][68];
  __shared__ float Bs[16][68];
  int t = threadIdx.x;
  int tx = t & 15, ty = t >> 4;
  int row0 = blockIdx.y << 6, col0 = blockIdx.x << 6;
  int lr = t >> 2, lk = (t & 3) << 2;
  float acc[4][4] = {};
  int ar = row0 + lr;
  bool arok = ar < N;
  const float* Ap = A + (size_t)(arok ? ar : 0) * K + lk;
  const float* Wp = W + (size_t)(col0 + lr) * K + lk;
  for (int k0 = 0; k0 < K; k0 += 16) {
    float4 av;
    if (arok) av = *(const float4*)(Ap + k0);
    else { av.x=0;av.y=0;av.z=0;av.w=0; }
    float4 bv = *(const float4*)(Wp + k0);
    As[lk+0][lr]=av.x; As[lk+1][lr]=av.y; As[lk+2][lr]=av.z; As[lk+3][lr]=av.w;
    Bs[lk+0][lr]=bv.x; Bs[lk+1][lr]=bv.y; Bs[lk+2][lr]=bv.z; Bs[lk+3][lr]=bv.w;
    __syncthreads();
    #pragma unroll
    for (int k=0;k<16;k++){
      float4 af = *(const float4*)&As[k][ty<<2];
      float4 bf = *(const float4*)&Bs[k][tx<<2];
      float a4[4]={af.x,af.y,af.z,af.w};
      float b4[4]={bf.x,bf.y,bf.z,bf.w};
      #pragma unroll
      for (int i=0;i<4;i++)
        #pragma unroll
        for (int j=0;j<4;j++)
          acc[i][j] += a4[i]*b4[j];
    }
    __syncthreads();
  }
  #pragma unroll
  for (int i=0;i<4;i++){
    int row = row0 + (ty<<2) + i;
    if (row >= N) break;
    int colb = col0 + (tx<<2);
    float vv_[4];
    #pragma unroll
    for (int j=0;j<4;j++){
      float v = acc[i][j] + bias[colb+j];
      if constexpr (EPI==EPI_TANH) v = tanhf(v);
      vv_[j]=v;
    }
    float4 ov; ov.x=vv_[0]; ov.y=vv_[1]; ov.z=vv_[2]; ov.w=vv_[3];
    *(float4*)(Y + (size_t)row*O + colb) = ov;
  }
}

// ---------------- pre-split MFMA GEMM, double-buffered LDS -------------------
template<int EPI, bool AMASK, int OUT, int NF>
__global__ __launch_bounds__(256) void gemm_ps(
    const unsigned short* __restrict__ Ah, const unsigned short* __restrict__ Al,
    const unsigned short* __restrict__ Wh, const unsigned short* __restrict__ Wl,
    const float* __restrict__ bias, const float* __restrict__ res,
    const float* __restrict__ gamma, const float* __restrict__ rowmask,
    float* __restrict__ Y, unsigned short* __restrict__ Yh,
    unsigned short* __restrict__ Yl, int K, int O, float scale)
{
  __shared__ unsigned short AhS[2][64][40], AlS[2][64][40];
  __shared__ unsigned short BhS[2][NF*32][40], BlS[2][NF*32][40];
  int t = threadIdx.x;
  int row0 = blockIdx.y << 6;
  int col0 = blockIdx.x << (NF==4 ? 7 : 6);
  int lane = t & 63, wid = t >> 6;
  int wr = wid >> 1, wc = wid & 1;

  int sr = t >> 2, sc = (t & 3) << 3;
  const unsigned short* Ahg = Ah + (size_t)(row0 + sr)*K + sc;
  const unsigned short* Alg = Al + (size_t)(row0 + sr)*K + sc;
  const unsigned short* Bhg = Wh + (size_t)(col0 + sr)*K + sc;
  const unsigned short* Blg = Wl + (size_t)(col0 + sr)*K + sc;
  float am = 1.f;
  if (AMASK) am = rowmask[row0 + sr];

  f32x4 acc[2][NF] = {};
  int nsteps = K >> 5;
  short8v ah_, al_, bh0_, bl0_, bh1_, bl1_;
  ah_ = *(const short8v*)(Ahg);
  al_ = *(const short8v*)(Alg);
  bh0_ = *(const short8v*)(Bhg);
  bl0_ = *(const short8v*)(Blg);
  if constexpr (NF==4){
    bh1_ = *(const short8v*)(Bhg + (size_t)64*K);
    bl1_ = *(const short8v*)(Blg + (size_t)64*K);
  }
  if (AMASK && am == 0.f){ ah_ ^= ah_; al_ ^= al_; }
  *(short8v*)&AhS[0][sr][sc] = ah_;
  *(short8v*)&AlS[0][sr][sc] = al_;
  *(short8v*)&BhS[0][sr][sc] = bh0_;
  *(short8v*)&BlS[0][sr][sc] = bl0_;
  if constexpr (NF==4){
    *(short8v*)&BhS[0][sr+64][sc] = bh1_;
    *(short8v*)&BlS[0][sr+64][sc] = bl1_;
  }

  int st = 0;
  for (int s = 0; s < nsteps; ++s){
    if (s+1 < nsteps){
      int ko = (s+1) << 5;
      ah_ = *(const short8v*)(Ahg + ko);
      al_ = *(const short8v*)(Alg + ko);
      bh0_ = *(const short8v*)(Bhg + ko);
      bl0_ = *(const short8v*)(Blg + ko);
      if constexpr (NF==4){
        bh1_ = *(const short8v*)(Bhg + (size_t)64*K + ko);
        bl1_ = *(const short8v*)(Blg + (size_t)64*K + ko);
      }
      if (AMASK && am == 0.f){ ah_ ^= ah_; al_ ^= al_; }
    }
    __syncthreads();
    int fr = lane & 15, fc = (lane >> 4) << 3;
    short8v ahf[2], alf[2], bhf[NF], blf[NF];
    #pragma unroll
    for (int mt=0; mt<2; ++mt){
      int r = (wr<<5) + (mt<<4) + fr;
      ahf[mt] = *(const short8v*)&AhS[st][r][fc];
      alf[mt] = *(const short8v*)&AlS[st][r][fc];
    }
    #pragma unroll
    for (int nt=0; nt<NF; ++nt){
      int r = (NF==4 ? (wc<<6) : (wc<<5)) + (nt<<4) + fr;
      bhf[nt] = *(const short8v*)&BhS[st][r][fc];
      blf[nt] = *(const short8v*)&BlS[st][r][fc];
    }
    #pragma unroll
    for (int mt=0; mt<2; ++mt)
      #pragma unroll
      for (int nt=0; nt<NF; ++nt){
        f32x4 c = acc[mt][nt];
        c = __builtin_amdgcn_mfma_f32_16x16x32_bf16(ahf[mt], bhf[nt], c, 0,0,0);
        c = __builtin_amdgcn_mfma_f32_16x16x32_bf16(ahf[mt], blf[nt], c, 0,0,0);
        c = __builtin_amdgcn_mfma_f32_16x16x32_bf16(alf[mt], bhf[nt], c, 0,0,0);
        acc[mt][nt] = c;
      }
    if (s+1 < nsteps){
      int nb = st ^ 1;
      *(short8v*)&AhS[nb][sr][sc] = ah_;
      *(short8v*)&AlS[nb][sr][sc] = al_;
      *(short8v*)&BhS[nb][sr][sc] = bh0_;
      *(short8v*)&BlS[nb][sr][sc] = bl0_;
      if constexpr (NF==4){
        *(short8v*)&BhS[nb][sr+64][sc] = bh1_;
        *(short8v*)&BlS[nb][sr+64][sc] = bl1_;
      }
    }
    st ^= 1;
  }

  int rb = row0 + (wr<<5) + ((lane>>4)<<2);
  int cb = col0 + (NF==4 ? (wc<<6) : (wc<<5)) + (lane & 15);
  float bs[NF], gm[NF];
  #pragma unroll
  for (int nt=0; nt<NF; ++nt){
    int col = cb + (nt<<4);
    if constexpr (EPI==EPI_QKV){
      int which = blockIdx.x >> 2;
      const float* bp = (which==0) ? bias : (which==1) ? res : gamma;
      bs[nt] = bp[col & 511];
    } else {
      bs[nt] = bias[col];
      if constexpr (EPI==EPI_RES_GAMMA_MASK) gm[nt] = gamma[col];
    }
  }
  float qscale = 1.f;
  if constexpr (EPI==EPI_QKV) qscale = ((blockIdx.x>>2)==0) ? scale : 1.f;
  #pragma unroll
  for (int mt=0; mt<2; ++mt)
    #pragma unroll
    for (int j=0; j<4; ++j){
      int row = rb + (mt<<4) + j;
      float rm = 1.f;
      if constexpr (EPI==EPI_RELU_MASK || EPI==EPI_RES_MASK || EPI==EPI_RES_GAMMA_MASK)
        rm = rowmask[row];
      const float* rr = nullptr;
      if constexpr (EPI==EPI_RES || EPI==EPI_RES_MASK || EPI==EPI_RES_GAMMA_MASK)
        rr = res + (size_t)row*O + cb;
      #pragma unroll
      for (int nt=0; nt<NF; ++nt){
        float v = acc[mt][nt][j] + bs[nt];
        if constexpr (EPI==EPI_SCALE) v *= scale;
        else if constexpr (EPI==EPI_QKV) v *= qscale;
        else if constexpr (EPI==EPI_GELU) v = 0.5f*v*(1.f+erff(v*0.7071067811865475f));
        else if constexpr (EPI==EPI_RES) v = rr[nt<<4] + v;
        else if constexpr (EPI==EPI_RELU_MASK) v = fmaxf(v,0.f)*rm;
        else if constexpr (EPI==EPI_RES_MASK) v = rr[nt<<4] + v*rm;
        else if constexpr (EPI==EPI_RES_GAMMA_MASK) v = (rr[nt<<4] + gm[nt]*v)*rm;
        size_t oidx = (size_t)row*O + cb + (nt<<4);
        if constexpr (OUT==0) Y[oidx] = v;
        else { unsigned short h,l; splitc(v,h,l); Yh[oidx]=h; Yl[oidx]=l; }
      }
    }
}

// ---------------- V transpose: planes [N][1536] cols 1024.. -> VT[b][512d][512tok]
__global__ __launch_bounds__(256) void transpose_v_k(
    const unsigned short* __restrict__ Vh, const unsigned short* __restrict__ Vl,
    unsigned short* __restrict__ VTh, unsigned short* __restrict__ VTl){
  __shared__ unsigned short t0[64][72];
  __shared__ unsigned short t1[64][72];
  int dt = blockIdx.x, tb = blockIdx.y, b = blockIdx.z;
  int t = threadIdx.x;
  int r = t >> 3, c = (t & 7) << 3;   // r 0..31
  #pragma unroll
  for (int rep = 0; rep < 2; ++rep){
    int rr = rep*32 + r;
    size_t g = ((size_t)b*512 + tb*64 + rr)*QKVS + 1024 + dt*64 + c;
    *(short8v*)&t0[rr][c] = *(const short8v*)&Vh[g];
    *(short8v*)&t1[rr][c] = *(const short8v*)&Vl[g];
  }
  __syncthreads();
  #pragma unroll
  for (int rep = 0; rep < 2; ++rep){
    int rr = rep*32 + r;   // out row: d-local
    short8v vh_, vl_;
    #pragma unroll
    for (int i = 0; i < 8; ++i){ vh_[i] = (short)t0[c+i][rr]; vl_[i] = (short)t1[c+i][rr]; }
    size_t g = ((size_t)b*512 + dt*64 + rr)*512 + tb*64 + c;
    *(short8v*)&VTh[g] = vh_;
    *(short8v*)&VTl[g] = vl_;
  }
}

// ---------------- MFMA windowed-rel attention v3 -----------------------------
// Block = (16 q-rows, b,h), 4 waves. K/V fragments load DIRECTLY global->VGPR
// (16B contiguous per lane) -- no K/V LDS staging, no barriers in QK/AV loops.
// XCD-aware block remap groups the 32 q-tiles of 8 bh per XCD for L2 locality.
__global__ __launch_bounds__(256) void attn_mf(
    const unsigned short* __restrict__ Ph_g, const unsigned short* __restrict__ Pl_g,
    const unsigned short* __restrict__ VTh_g, const unsigned short* __restrict__ VTl_g,
    const float* __restrict__ relk, const float* __restrict__ relv,
    const float* __restrict__ mask, unsigned short* __restrict__ Oh,
    unsigned short* __restrict__ Ol)
{
  __shared__ float ms_[512];
  __shared__ float rk[9][64];
  __shared__ float rv[9][64];
  __shared__ unsigned short Qh[16][72], Ql[16][72];
  __shared__ float qrel[16][12];
  __shared__ unsigned short Sh[16][520], Sl[16][520];
  __shared__ float red1[4][16];
  __shared__ float red2[4][16];

  // bijective XCD remap: XCD x (= id&7 under round-robin) serves bh in [8x,8x+8)
  int id = blockIdx.x;
  int xcd = id & 7, kk = id >> 3;
  int bh = xcd*8 + (kk >> 5);
  int qt = kk & 31;
  int h = bh & 7, b_ = bh >> 3;
  int t = threadIdx.x;
  int l0 = qt * 16;
  const size_t rowoff = (size_t)b_ * 512;
  int lane = t & 63, w = t >> 6;

  ms_[t] = mask[rowoff + t]; ms_[t+256] = mask[rowoff + t + 256];
  for (int i = t; i < 576; i += 256){ ((float*)rk)[i] = relk[i]; ((float*)rv)[i] = relv[i]; }
  {
    int idx = t & 127; int r = idx >> 3, c = (idx & 7) << 3;
    size_t g = (rowoff + l0 + r)*QKVS + h*64 + c;
    if (t < 128) *(short8v*)&Qh[r][c] = *(const short8v*)&Ph_g[g];
    else         *(short8v*)&Ql[r][c] = *(const short8v*)&Pl_g[g];
  }
  __syncthreads();
  if (t < 144){
    int dlt = t >> 4, q_ = t & 15;
    float s = 0.f;
    for (int d = 0; d < 64; ++d){
      float qf = bf2f(Qh[q_][d]) + bf2f(Ql[q_][d]);
      s += qf * rk[dlt][d];
    }
    qrel[q_][dlt] = s;
  }
  __syncthreads();

  int fr = lane & 15, fc = (lane >> 4) << 3;
  int qbase = (lane>>4) << 2;          // this thread's 4 queries
  // Q fragments are tile-invariant: load once
  short8v ah0 = *(const short8v*)&Qh[fr][fc];
  short8v ah1 = *(const short8v*)&Qh[fr][32+fc];
  short8v al0 = *(const short8v*)&Ql[fr][fc];
  short8v al1 = *(const short8v*)&Ql[fr][32+fc];

  f32x4 sreg[8];
  // ---- QK over 8 tiles of 64 keys; B-frags direct from global (L2) ----
  #pragma unroll
  for (int tt = 0; tt < 8; ++tt){
    int br = tt*64 + w*16 + fr;        // key row
    const unsigned short* krh = Ph_g + (rowoff + br)*QKVS + 512 + h*64;
    const unsigned short* krl = Pl_g + (rowoff + br)*QKVS + 512 + h*64;
    short8v bh0 = *(const short8v*)(krh + fc);
    short8v bh1 = *(const short8v*)(krh + 32 + fc);
    short8v bl0 = *(const short8v*)(krl + fc);
    short8v bl1 = *(const short8v*)(krl + 32 + fc);
    f32x4 c4 = {};
    c4 = __builtin_amdgcn_mfma_f32_16x16x32_bf16(ah0,bh0,c4,0,0,0);
    c4 = __builtin_amdgcn_mfma_f32_16x16x32_bf16(ah1,bh1,c4,0,0,0);
    c4 = __builtin_amdgcn_mfma_f32_16x16x32_bf16(ah0,bl0,c4,0,0,0);
    c4 = __builtin_amdgcn_mfma_f32_16x16x32_bf16(ah1,bl1,c4,0,0,0);
    c4 = __builtin_amdgcn_mfma_f32_16x16x32_bf16(al0,bh0,c4,0,0,0);
    c4 = __builtin_amdgcn_mfma_f32_16x16x32_bf16(al1,bh1,c4,0,0,0);
    int m = tt*64 + w*16 + fr;         // C col = lane&15
    float mm_ = ms_[m];
    #pragma unroll
    for (int j = 0; j < 4; ++j){
      int q = qbase + j;
      int l = l0 + q;
      float s = c4[j];
      int dlt = m - l + 4;
      if (dlt >= 0 && dlt <= 8) s += qrel[q][dlt];
      if (ms_[l] * mm_ == 0.f) s = -10000.f;
      c4[j] = s;
    }
    sreg[tt] = c4;
  }

  // ---- softmax: 16-lane shfl + cross-wave LDS partials; fp32 throughout ----
  float mx[4], sm[4], inv[4];
  #pragma unroll
  for (int j = 0; j < 4; ++j){
    float v = sreg[0][j];
    #pragma unroll
    for (int tt = 1; tt < 8; ++tt) v = fmaxf(v, sreg[tt][j]);
    #pragma unroll
    for (int o = 8; o >= 1; o >>= 1) v = fmaxf(v, __shfl_xor(v, o));
    mx[j] = v;
  }
  if (fr == 0){
    #pragma unroll
    for (int j = 0; j < 4; ++j) red1[w][qbase + j] = mx[j];
  }
  __syncthreads();
  #pragma unroll
  for (int j = 0; j < 4; ++j){
    int q = qbase + j;
    mx[j] = fmaxf(fmaxf(red1[0][q], red1[1][q]), fmaxf(red1[2][q], red1[3][q]));
  }
  #pragma unroll
  for (int j = 0; j < 4; ++j) sm[j] = 0.f;
  #pragma unroll
  for (int tt = 0; tt < 8; ++tt){
    f32x4 c4 = sreg[tt];
    #pragma unroll
    for (int j = 0; j < 4; ++j){
      float e = expf(c4[j] - mx[j]);
      c4[j] = e;
      sm[j] += e;
    }
    sreg[tt] = c4;
  }
  #pragma unroll
  for (int j = 0; j < 4; ++j){
    float v = sm[j];
    #pragma unroll
    for (int o = 8; o >= 1; o >>= 1) v += __shfl_xor(v, o);
    sm[j] = v;
  }
  if (fr == 0){
    #pragma unroll
    for (int j = 0; j < 4; ++j) red2[w][qbase + j] = sm[j];
  }
  // write P planes (unnormalized)
  #pragma unroll
  for (int tt = 0; tt < 8; ++tt){
    int m = tt*64 + w*16 + fr;
    #pragma unroll
    for (int j = 0; j < 4; ++j){
      unsigned short hh, ll_;
      splitc(sreg[tt][j], hh, ll_);
      Sh[qbase + j][m] = hh; Sl[qbase + j][m] = ll_;
    }
  }
  __syncthreads();
  #pragma unroll
  for (int j = 0; j < 4; ++j){
    int q = qbase + j;
    inv[j] = 1.f / (red2[0][q] + red2[1][q] + red2[2][q] + red2[3][q]);
  }

  // ---- AV over 8 tiles; V-frags direct from VT global (L2) ----
  f32x4 oacc = {};
  const unsigned short* vrh = VTh_g + ((size_t)b_*512 + h*64 + w*16 + fr)*512;
  const unsigned short* vrl = VTl_g + ((size_t)b_*512 + h*64 + w*16 + fr)*512;
  #pragma unroll
  for (int tt = 0; tt < 8; ++tt){
    #pragma unroll
    for (int ks = 0; ks < 2; ++ks){
      int moff = tt*64 + ks*32 + fc;
      short8v ah = *(const short8v*)&Sh[fr][moff];
      short8v al = *(const short8v*)&Sl[fr][moff];
      short8v bh = *(const short8v*)(vrh + moff);
      short8v bl = *(const short8v*)(vrl + moff);
      oacc = __builtin_amdgcn_mfma_f32_16x16x32_bf16(ah,bh,oacc,0,0,0);
      oacc = __builtin_amdgcn_mfma_f32_16x16x32_bf16(ah,bl,oacc,0,0,0);
      oacc = __builtin_amdgcn_mfma_f32_16x16x32_bf16(al,bh,oacc,0,0,0);
    }
  }
  // ---- epilogue: rel_v window + normalize, write output planes ----
  {
    int d = w*16 + fr;
    #pragma unroll
    for (int j = 0; j < 4; ++j){
      int q = qbase + j;
      int l = l0 + q;
      float val = oacc[j];
      #pragma unroll
      for (int dlt = 0; dlt < 9; ++dlt){
        int m = l + dlt - 4;
        if (m >= 0 && m < 512){
          float e = bf2f(Sh[q][m]) + bf2f(Sl[q][m]);
          val += e * rv[dlt][d];
        }
      }
      val *= inv[j];
      unsigned short hh, ll_; splitc(val, hh, ll_);
      size_t oidx = ((rowoff + l) << 9) + h*64 + d;
      Oh[oidx] = hh; Ol[oidx] = ll_;
    }
  }
}

// ---------------- style attention (split out) ----------------
__global__ __launch_bounds__(128) void style_attn_k(const float* __restrict__ Q,
    const float* __restrict__ kk, const float* __restrict__ vv,
    const float* __restrict__ mask, unsigned short* __restrict__ Oh,
    unsigned short* __restrict__ Ol){
  int n = blockIdx.x;
  int h = threadIdx.x >> 6, lane = threadIdx.x & 63;
  __shared__ float qh[512];
  __shared__ float aw[2][64];
  {
    float4 v = ((const float4*)(Q + ((size_t)n<<9)))[threadIdx.x];
    *(float4*)&qh[threadIdx.x*4] = v;
  }
  __syncthreads();
  float sc;
  if (lane < 50){
    float s = 0.f;
    const float* kr = kk + lane*512 + h*256;
    const float* qr = qh + h*256;
    for (int d4 = 0; d4 < 64; ++d4){
      float4 kv = *(const float4*)&kr[d4*4];
      s += qr[d4*4]*kv.x + qr[d4*4+1]*kv.y + qr[d4*4+2]*kv.z + qr[d4*4+3]*kv.w;
    }
    sc = s * 0.044194173824159216f;
  } else sc = -1e30f;
  float mx = wave_max(sc);
  float ex = (lane < 50) ? expf(sc - mx) : 0.f;
  float sm = wave_sum(ex);
  float keep = (mask[n] == 0.f) ? 0.f : 1.f;
  aw[h][lane] = ex / sm * keep;
  __syncthreads();
  float4 acc; acc.x=0; acc.y=0; acc.z=0; acc.w=0;
  const float* vb = vv + h*256 + lane*4;
  for (int s = 0; s < 50; ++s){
    float a = aw[h][s];
    const float4 vvv = *(const float4*)&vb[(size_t)s*512];
    acc.x += a*vvv.x; acc.y += a*vvv.y; acc.z += a*vvv.z; acc.w += a*vvv.w;
  }
  size_t oidx = ((size_t)n<<9) + h*256 + lane*4;
  split4(acc, Oh+oidx, Ol+oidx);
}

// ---------------- final transpose ----------------
__global__ __launch_bounds__(256) void transpose_out_k(const float* __restrict__ xn,
    const float* __restrict__ mask, float* __restrict__ out){
  __shared__ float tile[32][33];
  int b_ = blockIdx.z; int c0 = blockIdx.x*32; int l0 = blockIdx.y*32;
  int tx = threadIdx.x & 31, ty = threadIdx.x >> 5;
  #pragma unroll
  for (int r=0;r<4;r++){
    int l = l0 + ty + r*8;
    tile[ty + r*8][tx] = xn[(((size_t)(b_*512 + l))<<9) + c0 + tx];
  }
  __syncthreads();
  float mm = mask[b_*512 + l0 + tx];
  #pragma unroll
  for (int r=0;r<4;r++){
    int c = c0 + ty + r*8;
    out[(((size_t)(b_*512 + c))<<9) + l0 + tx] = tile[tx][ty + r*8] * mm;
  }
}

extern "C" void kernel_launch(void* const* d_in, const int* in_sizes, int n_in,
                              void* d_out, int out_size, void* d_ws, size_t ws_size,
                              hipStream_t stream) {
  const int*   tokens   = (const int*)  d_in[0];
  const float* style_v  = (const float*)d_in[1];
  const float* mask     = (const float*)d_in[2];
  const float* embed_w  = (const float*)d_in[3];
  const float* cw_dw_w  = (const float*)d_in[4];
  const float* cw_dw_b  = (const float*)d_in[5];
  const float* cw_ln_g  = (const float*)d_in[6];
  const float* cw_ln_b  = (const float*)d_in[7];
  const float* cw_pw1_w = (const float*)d_in[8];
  const float* cw_pw1_b = (const float*)d_in[9];
  const float* cw_pw2_w = (const float*)d_in[10];
  const float* cw_pw2_b = (const float*)d_in[11];
  const float* cw_gamma = (const float*)d_in[12];
  const float* aq_w = (const float*)d_in[13];
  const float* aq_b = (const float*)d_in[14];
  const float* ak_w = (const float*)d_in[15];
  const float* ak_b = (const float*)d_in[16];
  const float* av_w = (const float*)d_in[17];
  const float* av_b = (const float*)d_in[18];
  const float* ao_w = (const float*)d_in[19];
  const float* ao_b = (const float*)d_in[20];
  const float* rel_k = (const float*)d_in[21];
  const float* rel_v = (const float*)d_in[22];
  const float* ln1_g = (const float*)d_in[23];
  const float* ln1_b = (const float*)d_in[24];
  const float* ln2_g = (const float*)d_in[25];
  const float* ln2_b = (const float*)d_in[26];
  const float* ffn_w1 = (const float*)d_in[27];
  const float* ffn_b1 = (const float*)d_in[28];
  const float* ffn_w2 = (const float*)d_in[29];
  const float* ffn_b2 = (const float*)d_in[30];
  const float* style_key = (const float*)d_in[31];
  const float* sq_w = (const float*)d_in[32];
  const float* sq_b = (const float*)d_in[33];
  const float* sk_w = (const float*)d_in[34];
  const float* sk_b = (const float*)d_in[35];
  const float* sv_w = (const float*)d_in[36];
  const float* sv_b = (const float*)d_in[37];
  const float* so_w = (const float*)d_in[38];
  const float* so_b = (const float*)d_in[39];
  const float* sn_g = (const float*)d_in[40];
  const float* sn_b = (const float*)d_in[41];

  const int N = NROWS;
  char* cur = (char*)d_ws;
  auto nextF = [&](size_t n)->float*{ float* p=(float*)cur; cur += n*sizeof(float); return p; };
  auto nextU = [&](size_t n)->unsigned short*{ unsigned short* p=(unsigned short*)cur; cur += n*2; return p; };

  float* X   = nextF((size_t)N*512);
  float* T   = nextF((size_t)N*512);
  float* Qb  = nextF((size_t)N*512);
  float* Vb  = nextF((size_t)N*512);
  float* KK  = nextF(2*50*512);
  float* VV  = nextF(2*50*512);
  unsigned short* Xh = nextU((size_t)N*512);
  unsigned short* Xl = nextU((size_t)N*512);
  unsigned short* Th = nextU((size_t)N*512);
  unsigned short* Tl = nextU((size_t)N*512);
  unsigned short* Hbh = nextU((size_t)N*2048);
  unsigned short* Hbl = nextU((size_t)N*2048);
  unsigned short* QKVh = nextU((size_t)N*QKVS);
  unsigned short* QKVl = nextU((size_t)N*QKVS);
  unsigned short* VTh = nextU((size_t)8*512*512);
  unsigned short* VTl = nextU((size_t)8*512*512);
  // weight planes
  unsigned short* pw1h = nextU(4194304); unsigned short* pw1l = nextU(4194304);
  unsigned short* pw2h = nextU(4194304); unsigned short* pw2l = nextU(4194304);
  unsigned short* qkvh = nextU((size_t)6*QKVS*512); unsigned short* qkvl = nextU((size_t)6*QKVS*512);
  unsigned short* aoh  = nextU(1572864); unsigned short* aol  = nextU(1572864);
  unsigned short* f1h  = nextU(6291456); unsigned short* f1l  = nextU(6291456);
  unsigned short* f2h  = nextU(6291456); unsigned short* f2l  = nextU(6291456);
  unsigned short* sqh  = nextU(524288);  unsigned short* sql  = nextU(524288);
  unsigned short* soh  = nextU(524288);  unsigned short* sol  = nextU(524288);

  // ---- weight prep ----
  split_k<<<1024,256,0,stream>>>(cw_pw1_w, pw1h, pw1l, 4194304/4);
  split_k<<<1024,256,0,stream>>>(cw_pw2_w, pw2h, pw2l, 4194304/4);
  split_qkv_k<<<1024,256,0,stream>>>(aq_w, ak_w, av_w, qkvh, qkvl);
  split_k<<<1024,256,0,stream>>>(ao_w, aoh, aol, 1572864/4);
  split_k<<<1024,256,0,stream>>>(ffn_w1, f1h, f1l, 6291456/4);
  split_k<<<1024,256,0,stream>>>(ffn_w2, f2h, f2l, 6291456/4);
  split_k<<<512,256,0,stream>>>(sq_w, sqh, sql, 524288/4);
  split_k<<<512,256,0,stream>>>(so_w, soh, sol, 524288/4);

  dim3 gm512(8,64), gm2048(16,64), gmqkv(12,64), gS(8,1);

  embed_k<<<4096,128,0,stream>>>(tokens, embed_w, mask, X);

  // ---- ConvNeXt blocks (X stays masked throughout) ----
  for (int i=0;i<4;i++){
    dwconv_k<<<4096,128,0,stream>>>(X, cw_dw_w + (size_t)i*512*5, cw_dw_b + i*512, mask, T);
    ln_rows<true><<<1024,256,0,stream>>>(T, cw_ln_g+i*512, cw_ln_b+i*512, T, Th, Tl, N);
    gemm_ps<EPI_GELU,false,1,4><<<gm2048,256,0,stream>>>(Th, Tl,
        pw1h + (size_t)i*1048576, pw1l + (size_t)i*1048576,
        cw_pw1_b+i*2048, nullptr, nullptr, nullptr, nullptr, Hbh, Hbl, 512, 2048, 0.f);
    gemm_ps<EPI_RES_GAMMA_MASK,false,0,2><<<gm512,256,0,stream>>>(Hbh, Hbl,
        pw2h + (size_t)i*1048576, pw2l + (size_t)i*1048576,
        cw_pw2_b+i*512, X, cw_gamma+i*512, mask, X, nullptr, nullptr, 2048, 512, 0.f);
  }
  maskmul_split_k<<<2048,256,0,stream>>>(X, mask, Xh, Xl);

  // ---- Attention layers ----
  for (int i=0;i<6;i++){
    gemm_ps<EPI_QKV,false,1,4><<<gmqkv,256,0,stream>>>(Xh, Xl,
        qkvh + (size_t)i*QKVS*512, qkvl + (size_t)i*QKVS*512,
        aq_b+i*512, ak_b+i*512, av_b+i*512, nullptr, nullptr, QKVh, QKVl,
        512, QKVS, 0.125f);
    transpose_v_k<<<dim3(8,8,8),256,0,stream>>>(QKVh, QKVl, VTh, VTl);
    attn_mf<<<2048,256,0,stream>>>(QKVh, QKVl, VTh, VTl,
        rel_k + (size_t)i*9*64, rel_v + (size_t)i*9*64, mask, Th, Tl);
    gemm_ps<EPI_RES,false,0,2><<<gm512,256,0,stream>>>(Th, Tl,
        aoh + (size_t)i*262144, aol + (size_t)i*262144,
        ao_b+i*512, X, nullptr, nullptr, Qb, nullptr, nullptr, 512, 512, 0.f);
    ln_rows<true><<<1024,256,0,stream>>>(Qb, ln1_g+i*512, ln1_b+i*512, X, Xh, Xl, N);
    gemm_ps<EPI_RELU_MASK,true,1,4><<<gm2048,256,0,stream>>>(Xh, Xl,
        f1h + (size_t)i*1048576, f1l + (size_t)i*1048576,
        ffn_b1+i*2048, nullptr, nullptr, mask, nullptr, Hbh, Hbl, 512, 2048, 0.f);
    gemm_ps<EPI_RES_MASK,false,0,2><<<gm512,256,0,stream>>>(Hbh, Hbl,
        f2h + (size_t)i*1048576, f2l + (size_t)i*1048576,
        ffn_b2+i*512, X, nullptr, mask, Qb, nullptr, nullptr, 2048, 512, 0.f);
    ln_rows<true><<<1024,256,0,stream>>>(Qb, ln2_g+i*512, ln2_b+i*512, X, Xh, Xl, N);
  }
  maskmul_split_k<<<2048,256,0,stream>>>(X, mask, Xh, Xl);

  // ---- Style attention ----
  gemm_nt<EPI_TANH><<<gS,256,0,stream>>>(style_key, sk_w, sk_b, KK, 50,512,512);
  gemm_nt<EPI_TANH><<<gS,256,0,stream>>>(style_key, sk_w+262144, sk_b+512, KK+25600, 50,512,512);
  gemm_nt<EPI_BIAS><<<gS,256,0,stream>>>(style_v, sv_w, sv_b, VV, 50,512,512);
  gemm_nt<EPI_BIAS><<<gS,256,0,stream>>>(style_v, sv_w+262144, sv_b+512, VV+25600, 50,512,512);

  // layer 0: xin = masked X
  gemm_ps<EPI_BIAS,false,0,2><<<gm512,256,0,stream>>>(Xh, Xl, sqh, sql,
      sq_b, nullptr, nullptr, nullptr, Qb, nullptr, nullptr, 512, 512, 0.f);
  style_attn_k<<<4096,128,0,stream>>>(Qb, KK, VV, mask, Th, Tl);
  gemm_ps<EPI_RES_MASK,false,1,2><<<gm512,256,0,stream>>>(Th, Tl, soh, sol,
      so_b, X, nullptr, mask, nullptr, Hbh, Hbl, 512, 512, 0.f);   // x1 planes
  // layer 1: xin = x1 (planes); residual xt = X
  gemm_ps<EPI_BIAS,false,0,2><<<gm512,256,0,stream>>>(Hbh, Hbl, sqh+262144, sql+262144,
      sq_b+512, nullptr, nullptr, nullptr, Qb, nullptr, nullptr, 512, 512, 0.f);
  style_attn_k<<<4096,128,0,stream>>>(Qb, KK+25600, VV+25600, mask, Th, Tl);
  gemm_ps<EPI_RES_MASK,false,0,2><<<gm512,256,0,stream>>>(Th, Tl, soh+262144, sol+262144,
      so_b+512, X, nullptr, mask, Vb, nullptr, nullptr, 512, 512, 0.f);  // x2

  ln_rows<false><<<1024,256,0,stream>>>(Vb, sn_g, sn_b, Qb, nullptr, nullptr, N);
  transpose_out_k<<<dim3(16,16,8),256,0,stream>>>(Qb, mask, (float*)d_out);
}